// Round 1
// baseline (8442.976 us; speedup 1.0000x reference)
//
#include <hip/hip_runtime.h>
#include <math.h>

#define N_NODES 50000
#define N_EDGES 500000
// dims
#define ND 128   // NODE_DIM / HID
#define OD 64    // OUT / EDGE_DIM

__device__ inline void atomicMaxF(float* addr, float v) {  // v >= 0 only
    atomicMax((int*)addr, __float_as_int(v));
}
__device__ inline void atomicMinF(float* addr, float v) {  // v >= 0 only
    atomicMin((int*)addr, __float_as_int(v));
}

__global__ void k_fill(float* p, float v, int n) {
    int i = blockIdx.x * blockDim.x + threadIdx.x;
    if (i < n) p[i] = v;
}

// dst[j*kpad + k] = src[k*ldw + j], k<K, j<J
__global__ void k_transpose(const float* __restrict__ src, float* __restrict__ dst,
                            int K, int J, int ldw, int kpad) {
    int i = blockIdx.x * blockDim.x + threadIdx.x;
    if (i >= K * J) return;
    int k = i / J, j = i - k * J;
    dst[j * kpad + k] = src[k * ldw + j];
}

// ---------------- edge encoder: feats(38) -> relu(@w1+b1)(128) -> @w2+b2 (64) ----------
__global__ __launch_bounds__(256) void k_edge_encoder(
    const float* __restrict__ la, const float* __restrict__ tse,
    const int* __restrict__ bp, const int* __restrict__ tt,
    const float* __restrict__ cr, const float* __restrict__ tsp,
    const float* __restrict__ tg, const float* __restrict__ r7,
    const float* __restrict__ r30,
    const float* __restrict__ tx_emb, const float* __restrict__ bank_emb,
    const float* __restrict__ w1t /*[128][40]*/, const float* __restrict__ eb1,
    const float* __restrict__ w2 /*[128][64]*/, const float* __restrict__ eb2,
    float* __restrict__ ea) {
    int e = blockIdx.x * blockDim.x + threadIdx.x;
    if (e >= N_EDGES) return;
    float f[38];
    f[0] = la[e]; f[1] = cr[e]; f[2] = tsp[e]; f[3] = tg[e]; f[4] = r7[e]; f[5] = r30[e];
#pragma unroll
    for (int i = 0; i < 8; i++) f[6 + i] = tse[e * 8 + i];
    int txi = tt[e];
#pragma unroll
    for (int i = 0; i < 8; i++) f[14 + i] = tx_emb[txi * 8 + i];
    int bk0 = bp[e * 2 + 0], bk1 = bp[e * 2 + 1];
#pragma unroll
    for (int i = 0; i < 8; i++) f[22 + i] = bank_emb[bk0 * 8 + i];
#pragma unroll
    for (int i = 0; i < 8; i++) f[30 + i] = bank_emb[bk1 * 8 + i];

    float acc[64];
#pragma unroll
    for (int o = 0; o < 64; o++) acc[o] = eb2[o];
    for (int j = 0; j < 128; j++) {
        float h = eb1[j];
        const float* wr = w1t + j * 40;
#pragma unroll
        for (int k = 0; k < 38; k++) h = fmaf(f[k], wr[k], h);
        h = fmaxf(h, 0.f);
        const float* w2r = w2 + j * 64;
#pragma unroll
        for (int o = 0; o < 64; o++) acc[o] = fmaf(h, w2r[o], acc[o]);
    }
    float* er = ea + (long)e * 64;
#pragma unroll
    for (int o = 0; o < 64; o++) er[o] = acc[o];
}

// ---------------- generic node-level GEMM: out[n, j0:j0+JC] = act(b + in1@W[:K1] + (in2/deg)@W[K1:]) ---
template <int K1, int K2, int JC, bool RELU, bool DIV2>
__global__ __launch_bounds__(256) void k_node_gemm(
    const float* __restrict__ in1, int ld1,
    const float* __restrict__ in2, int ld2,
    const float* __restrict__ deg,
    const float* __restrict__ W, int ldw,
    const float* __restrict__ bias,
    float* __restrict__ out, int ldo, int nrows) {
    int n = blockIdx.x * blockDim.x + threadIdx.x;
    if (n >= nrows) return;
    int j0 = blockIdx.y * JC;
    float acc[JC];
#pragma unroll
    for (int j = 0; j < JC; j++) acc[j] = bias ? bias[j0 + j] : 0.f;
    const float* r1 = in1 + (long)n * ld1;
    for (int k = 0; k < K1; k++) {
        float v = r1[k];
        const float* wr = W + (long)k * ldw + j0;
#pragma unroll
        for (int j = 0; j < JC; j++) acc[j] = fmaf(v, wr[j], acc[j]);
    }
    if constexpr (K2 > 0) {
        float dinv = 1.f;
        if constexpr (DIV2) dinv = 1.f / (deg[n] + 1e-6f);
        const float* r2 = in2 + (long)n * ld2;
        for (int k = 0; k < K2; k++) {
            float v = r2[k] * dinv;
            const float* wr = W + (long)(K1 + k) * ldw + j0;
#pragma unroll
            for (int j = 0; j < JC; j++) acc[j] = fmaf(v, wr[j], acc[j]);
        }
    }
    float* orow = out + (long)n * ldo + j0;
#pragma unroll
    for (int j = 0; j < JC; j++) {
        float v = acc[j];
        if (RELU) v = fmaxf(v, 0.f);
        orow[j] = v;
    }
}

// ---------------- fused message + scatter: s[dst] += relu(P[src] + ea@Wbt + b) ------------
__global__ __launch_bounds__(256) void k_scatter(
    const float* __restrict__ P, const float* __restrict__ ea,
    const float* __restrict__ Wbt /*[128][64]*/, const float* __restrict__ bias,
    const int* __restrict__ src, const int* __restrict__ dst,
    float* __restrict__ s, float* __restrict__ deg, int do_deg) {
    int e = blockIdx.x * blockDim.x + threadIdx.x;
    if (e >= N_EDGES) return;
    int sn = src[e], dn = dst[e];
    float a[64];
    const float4* ar = (const float4*)(ea + (long)e * 64);
#pragma unroll
    for (int i = 0; i < 16; i++) {
        float4 v = ar[i];
        a[4 * i] = v.x; a[4 * i + 1] = v.y; a[4 * i + 2] = v.z; a[4 * i + 3] = v.w;
    }
    if (do_deg) atomicAdd(deg + dn, 1.f);
    const float* Pr = P + (long)sn * 128;
    float* sr = s + (long)dn * 128;
    for (int j = 0; j < 128; j++) {
        float m = bias[j];
        const float* wr = Wbt + j * 64;
#pragma unroll
        for (int k = 0; k < 64; k++) m = fmaf(a[k], wr[k], m);
        m += Pr[j];
        m = fmaxf(m, 0.f);
        atomicAdd(sr + j, m);
    }
}

// ---------------- edge classifier ------------------------------------------------------
__global__ __launch_bounds__(256) void k_edge_cls(
    const float* __restrict__ nS, const float* __restrict__ nD,
    const float* __restrict__ ea, const float* __restrict__ Ct /*[64][64]*/,
    const float* __restrict__ b1, const float* __restrict__ w2, const float* __restrict__ b2,
    const int* __restrict__ src, const int* __restrict__ dst,
    float* __restrict__ logits_out, float* __restrict__ probs) {
    int e = blockIdx.x * blockDim.x + threadIdx.x;
    if (e >= N_EDGES) return;
    int sn = src[e], dn = dst[e];
    float a[64];
    const float4* ar = (const float4*)(ea + (long)e * 64);
#pragma unroll
    for (int i = 0; i < 16; i++) {
        float4 v = ar[i];
        a[4 * i] = v.x; a[4 * i + 1] = v.y; a[4 * i + 2] = v.z; a[4 * i + 3] = v.w;
    }
    const float* Sr = nS + (long)sn * 64;
    const float* Dr = nD + (long)dn * 64;
    float logit = b2[0];
    for (int j = 0; j < 64; j++) {
        float t = b1[j];
        const float* wr = Ct + j * 64;
#pragma unroll
        for (int k = 0; k < 64; k++) t = fmaf(a[k], wr[k], t);
        t += Sr[j] + Dr[j];
        t = fmaxf(t, 0.f);
        logit = fmaf(t, w2[j], logit);
    }
    logits_out[e] = logit;
    probs[e] = 1.f / (1.f + expf(-logit));
}

// ---------------- ts max reduction -----------------------------------------------------
__global__ void k_tsmax(const int* __restrict__ ts, int* __restrict__ out) {
    int i = blockIdx.x * blockDim.x + threadIdx.x;
    int stride = gridDim.x * blockDim.x;
    int m = 0;
    for (int t = i; t < N_EDGES; t += stride) m = max(m, ts[t]);
#pragma unroll
    for (int off = 32; off > 0; off >>= 1) m = max(m, __shfl_down(m, off));
    if ((threadIdx.x & 63) == 0) atomicMax(out, m);
}

// ---------------- per-edge aggregation into node stats ---------------------------------
// stats layout: 0 cnt, 1 sum_p, 2 max_p, 3 sum_high, 4 sum_p*decay, 5 sum_decay,
//               6 sum_high30, 7 max_p30, 8 sum_p30, 9 sum_l30, 10 min_age
__global__ __launch_bounds__(256) void k_edge_agg(
    const float* __restrict__ probs, const int* __restrict__ uts,
    const int* __restrict__ src, const int* __restrict__ dst,
    const int* __restrict__ tsmax, float* __restrict__ stats) {
    int e = blockIdx.x * blockDim.x + threadIdx.x;
    if (e >= N_EDGES) return;
    float p = probs[e];
    float now = (float)(*tsmax);
    float ts = (float)uts[e];
    float age = fmaxf(now - ts, 0.f);
    float decay = expf(-age / 2592000.f);
    bool high = p >= 0.7f;
    bool l30 = age <= 2592000.f;
    float aged = age / 86400.f;
    float* cnt = stats;
    float* sump = stats + N_NODES;
    float* maxp = stats + 2 * N_NODES;
    float* sumh = stats + 3 * N_NODES;
    float* sumpd = stats + 4 * N_NODES;
    float* sumd = stats + 5 * N_NODES;
    float* sumh30 = stats + 6 * N_NODES;
    float* maxp30 = stats + 7 * N_NODES;
    float* sump30 = stats + 8 * N_NODES;
    float* suml30 = stats + 9 * N_NODES;
    float* minage = stats + 10 * N_NODES;
    int nn[2] = {src[e], dst[e]};
#pragma unroll
    for (int i = 0; i < 2; i++) {
        int n = nn[i];
        atomicAdd(cnt + n, 1.f);
        atomicAdd(sump + n, p);
        atomicMaxF(maxp + n, p);
        atomicAdd(sumpd + n, p * decay);
        atomicAdd(sumd + n, decay);
        if (high) atomicAdd(sumh + n, 1.f);
        if (l30) {
            atomicAdd(sump30 + n, p);
            atomicAdd(suml30 + n, 1.f);
            atomicMaxF(maxp30 + n, p);
            if (high) atomicAdd(sumh30 + n, 1.f);
        }
        if (high) atomicMinF(minage + n, aged);
    }
}

// ---------------- node classifier ------------------------------------------------------
__global__ __launch_bounds__(256) void k_node_cls(
    const float* __restrict__ ne, const float* __restrict__ stats,
    const float* __restrict__ w1t /*[64][72]*/, const float* __restrict__ b1,
    const float* __restrict__ gamma, const float* __restrict__ beta,
    const float* __restrict__ mean, const float* __restrict__ var,
    const float* __restrict__ w2, const float* __restrict__ b2,
    float* __restrict__ out) {
    int n = blockIdx.x * blockDim.x + threadIdx.x;
    if (n >= N_NODES) return;
    float in[72];
    const float4* nr = (const float4*)(ne + (long)n * 64);
#pragma unroll
    for (int i = 0; i < 16; i++) {
        float4 v = nr[i];
        in[4 * i] = v.x; in[4 * i + 1] = v.y; in[4 * i + 2] = v.z; in[4 * i + 3] = v.w;
    }
    float c = stats[n];
    in[64] = stats[N_NODES + n] / (c + 1e-6f);
    in[65] = stats[2 * N_NODES + n];
    in[66] = log1pf(stats[3 * N_NODES + n]);
    in[67] = stats[4 * N_NODES + n] / (stats[5 * N_NODES + n] + 1e-6f);
    in[68] = log1pf(stats[6 * N_NODES + n]);
    in[69] = stats[7 * N_NODES + n];
    in[70] = stats[8 * N_NODES + n] / (stats[9 * N_NODES + n] + 1e-6f);
    float ma = fminf(stats[10 * N_NODES + n], 9999.f);
    in[71] = log1pf(fminf(ma, 90.f)) / log1pf(90.f);
    float logit = b2[0];
    for (int j = 0; j < 64; j++) {
        float h = b1[j];
        const float* wr = w1t + j * 72;
#pragma unroll
        for (int k = 0; k < 72; k++) h = fmaf(in[k], wr[k], h);
        h = (h - mean[j]) * rsqrtf(var[j] + 1e-5f) * gamma[j] + beta[j];
        h = fmaxf(h, 0.f);
        logit = fmaf(h, w2[j], logit);
    }
    out[n] = logit;
}

extern "C" void kernel_launch(void* const* d_in, const int* in_sizes, int n_in,
                              void* d_out, int out_size, void* d_ws, size_t ws_size,
                              hipStream_t stream) {
    const float* x = (const float*)d_in[0];
    const int* eidx = (const int*)d_in[1];
    const int* src = eidx;
    const int* dst = eidx + N_EDGES;
    const float* la = (const float*)d_in[2];
    const float* tse = (const float*)d_in[3];
    const int* bp = (const int*)d_in[4];
    const int* tt = (const int*)d_in[5];
    const float* cr = (const float*)d_in[6];
    const float* tsp = (const float*)d_in[7];
    const float* tg = (const float*)d_in[8];
    const float* r7 = (const float*)d_in[9];
    const float* r30 = (const float*)d_in[10];
    const int* uts = (const int*)d_in[11];
    const float* tx_emb = (const float*)d_in[12];
    const float* bank_emb = (const float*)d_in[13];
    const float* ee_w1 = (const float*)d_in[14];
    const float* ee_b1 = (const float*)d_in[15];
    const float* ee_w2 = (const float*)d_in[16];
    const float* ee_b2 = (const float*)d_in[17];
    const float* msg1_w = (const float*)d_in[18];
    const float* msg1_b = (const float*)d_in[19];
    const float* upd1_w = (const float*)d_in[20];
    const float* upd1_b = (const float*)d_in[21];
    const float* msg2_w = (const float*)d_in[22];
    const float* msg2_b = (const float*)d_in[23];
    const float* upd2_w = (const float*)d_in[24];
    const float* upd2_b = (const float*)d_in[25];
    const float* ec_w1 = (const float*)d_in[26];
    const float* ec_b1 = (const float*)d_in[27];
    const float* ec_w2 = (const float*)d_in[28];
    const float* ec_b2 = (const float*)d_in[29];
    const float* nc_w1 = (const float*)d_in[30];
    const float* nc_b1 = (const float*)d_in[31];
    const float* bn_g = (const float*)d_in[32];
    const float* bn_b = (const float*)d_in[33];
    const float* bn_m = (const float*)d_in[34];
    const float* bn_v = (const float*)d_in[35];
    const float* nc_w2 = (const float*)d_in[36];
    const float* nc_b2 = (const float*)d_in[37];

    float* out_node = (float*)d_out;              // [N_NODES]
    float* out_edge = (float*)d_out + N_NODES;    // [N_EDGES]

    // workspace layout (floats)
    float* ws = (float*)d_ws;
    float* ea = ws;                         // E*64  = 32,000,000
    float* P = ea + (long)N_EDGES * 64;     // N*128 =  6,400,000
    float* s = P + (long)N_NODES * 128;     // N*128 =  6,400,000
    float* deg = s + (long)N_NODES * 128;   // N
    float* h1 = deg + N_NODES;              // N*128
    float* ne = h1 + (long)N_NODES * 128;   // N*64
    float* nS = ne + (long)N_NODES * 64;    // N*64
    float* nD = nS + (long)N_NODES * 64;    // N*64
    float* probs = nD + (long)N_NODES * 64; // E
    float* stats = probs + N_EDGES;         // 11*N
    float* w1t = stats + 11 * N_NODES;      // 128*40
    float* Wb1t = w1t + 128 * 40;           // 128*64
    float* Wb2t = Wb1t + 128 * 64;          // 128*64
    float* Ct = Wb2t + 128 * 64;            // 64*64
    float* ncw1t = Ct + 64 * 64;            // 64*72
    int* tsmax = (int*)(ncw1t + 64 * 72);   // 1

    const int EB = (N_EDGES + 255) / 256;   // 1954
    const int NB = (N_NODES + 255) / 256;   // 196

    // ---- init ----
    hipMemsetAsync(s, 0, (size_t)N_NODES * 128 * 4, stream);
    hipMemsetAsync(deg, 0, (size_t)N_NODES * 4, stream);
    hipMemsetAsync(stats, 0, (size_t)10 * N_NODES * 4, stream);
    hipMemsetAsync(tsmax, 0, 4, stream);
    k_fill<<<NB, 256, 0, stream>>>(stats + 10 * N_NODES, 9999.f, N_NODES);

    // ---- weight transposes ----
    k_transpose<<<(38 * 128 + 255) / 256, 256, 0, stream>>>(ee_w1, w1t, 38, 128, 128, 40);
    k_transpose<<<(64 * 128 + 255) / 256, 256, 0, stream>>>(msg1_w + 128 * 128, Wb1t, 64, 128, 128, 64);
    k_transpose<<<(64 * 128 + 255) / 256, 256, 0, stream>>>(msg2_w + 128 * 128, Wb2t, 64, 128, 128, 64);
    k_transpose<<<(64 * 64 + 255) / 256, 256, 0, stream>>>(ec_w1 + 128 * 64, Ct, 64, 64, 64, 64);
    k_transpose<<<(72 * 64 + 255) / 256, 256, 0, stream>>>(nc_w1, ncw1t, 72, 64, 64, 72);

    // ---- edge encoder ----
    k_edge_encoder<<<EB, 256, 0, stream>>>(la, tse, bp, tt, cr, tsp, tg, r7, r30,
                                           tx_emb, bank_emb, w1t, ee_b1, ee_w2, ee_b2, ea);

    // ---- SAGE layer 1 ----
    k_node_gemm<128, 0, 64, false, false><<<dim3(NB, 2), 256, 0, stream>>>(
        x, 128, nullptr, 0, nullptr, msg1_w, 128, nullptr, P, 128, N_NODES);
    k_scatter<<<EB, 256, 0, stream>>>(P, ea, Wb1t, msg1_b, src, dst, s, deg, 1);
    k_node_gemm<128, 128, 64, true, true><<<dim3(NB, 2), 256, 0, stream>>>(
        x, 128, s, 128, deg, upd1_w, 128, upd1_b, h1, 128, N_NODES);

    // ---- SAGE layer 2 ----
    hipMemsetAsync(s, 0, (size_t)N_NODES * 128 * 4, stream);
    k_node_gemm<128, 0, 64, false, false><<<dim3(NB, 2), 256, 0, stream>>>(
        h1, 128, nullptr, 0, nullptr, msg2_w, 128, nullptr, P, 128, N_NODES);
    k_scatter<<<EB, 256, 0, stream>>>(P, ea, Wb2t, msg2_b, src, dst, s, deg, 0);
    k_node_gemm<128, 128, 64, true, true><<<dim3(NB, 1), 256, 0, stream>>>(
        h1, 128, s, 128, deg, upd2_w, 64, upd2_b, ne, 64, N_NODES);

    // ---- edge classifier ----
    k_node_gemm<64, 0, 64, false, false><<<dim3(NB, 1), 256, 0, stream>>>(
        ne, 64, nullptr, 0, nullptr, ec_w1, 64, nullptr, nS, 64, N_NODES);
    k_node_gemm<64, 0, 64, false, false><<<dim3(NB, 1), 256, 0, stream>>>(
        ne, 64, nullptr, 0, nullptr, ec_w1 + 64 * 64, 64, nullptr, nD, 64, N_NODES);
    k_edge_cls<<<EB, 256, 0, stream>>>(nS, nD, ea, Ct, ec_b1, ec_w2, ec_b2,
                                       src, dst, out_edge, probs);

    // ---- edge aggregation ----
    k_tsmax<<<256, 256, 0, stream>>>(uts, tsmax);
    k_edge_agg<<<EB, 256, 0, stream>>>(probs, uts, src, dst, tsmax, stats);

    // ---- node classifier ----
    k_node_cls<<<NB, 256, 0, stream>>>(ne, stats, ncw1t, nc_b1, bn_g, bn_b, bn_m, bn_v,
                                       nc_w2, nc_b2, out_node);
}

// Round 2
// 3267.736 us; speedup vs baseline: 2.5837x; 2.5837x over previous
//
#include <hip/hip_runtime.h>
#include <math.h>

#define N_NODES 50000
#define N_EDGES 500000

__device__ inline void atomicMaxF(float* addr, float v) {  // v >= 0 only
    atomicMax((int*)addr, __float_as_int(v));
}
__device__ inline void atomicMinF(float* addr, float v) {  // v >= 0 only
    atomicMin((int*)addr, __float_as_int(v));
}

__global__ void k_fill(float* p, float v, int n) {
    int i = blockIdx.x * blockDim.x + threadIdx.x;
    if (i < n) p[i] = v;
}

// dst[j*kpad + k] = src[k*ldw + j], k<K, j<J
__global__ void k_transpose(const float* __restrict__ src, float* __restrict__ dst,
                            int K, int J, int ldw, int kpad) {
    int i = blockIdx.x * blockDim.x + threadIdx.x;
    if (i >= K * J) return;
    int k = i / J, j = i - k * J;
    dst[j * kpad + k] = src[k * ldw + j];
}

// =================== CSR build (edges grouped by dst) ====================
__global__ void k_deg_count(const int* __restrict__ dst, int* __restrict__ degi) {
    int e = blockIdx.x * blockDim.x + threadIdx.x;
    if (e < N_EDGES) atomicAdd(degi + dst[e], 1);
}

__global__ void k_block_sums(const int* __restrict__ deg, int* __restrict__ partials, int n) {
    __shared__ int sm[256];
    int i = blockIdx.x * 256 + threadIdx.x;
    sm[threadIdx.x] = (i < n) ? deg[i] : 0;
    __syncthreads();
    for (int s = 128; s > 0; s >>= 1) {
        if (threadIdx.x < s) sm[threadIdx.x] += sm[threadIdx.x + s];
        __syncthreads();
    }
    if (threadIdx.x == 0) partials[blockIdx.x] = sm[0];
}

// single block: in-place exclusive scan of partials[nb], nb<=256
__global__ void k_scan_partials(int* partials, int nb) {
    __shared__ int sm[256];
    int v = (threadIdx.x < nb) ? partials[threadIdx.x] : 0;
    sm[threadIdx.x] = v;
    __syncthreads();
    for (int off = 1; off < 256; off <<= 1) {
        int t = (threadIdx.x >= off) ? sm[threadIdx.x - off] : 0;
        __syncthreads();
        sm[threadIdx.x] += t;
        __syncthreads();
    }
    if (threadIdx.x < nb) partials[threadIdx.x] = sm[threadIdx.x] - v;  // exclusive
}

__global__ void k_scan_final(const int* __restrict__ deg, const int* __restrict__ partials,
                             int* __restrict__ row_start, int n) {
    __shared__ int sm[256];
    int i = blockIdx.x * 256 + threadIdx.x;
    int v = (i < n) ? deg[i] : 0;
    sm[threadIdx.x] = v;
    __syncthreads();
    for (int off = 1; off < 256; off <<= 1) {
        int t = (threadIdx.x >= off) ? sm[threadIdx.x - off] : 0;
        __syncthreads();
        sm[threadIdx.x] += t;
        __syncthreads();
    }
    if (i < n) row_start[i] = partials[blockIdx.x] + sm[threadIdx.x] - v;  // exclusive
    if (i == n - 1) row_start[n] = partials[blockIdx.x] + sm[threadIdx.x]; // total
}

__global__ void k_fill_slots(const int* __restrict__ dst, int* __restrict__ cursor,
                             int* __restrict__ eid) {
    int e = blockIdx.x * blockDim.x + threadIdx.x;
    if (e >= N_EDGES) return;
    int pos = atomicAdd(cursor + dst[e], 1);
    eid[pos] = e;
}

// ---------------- edge encoder: feats(38) -> relu(@w1+b1)(128) -> @w2+b2 (64) ----------
__global__ __launch_bounds__(256) void k_edge_encoder(
    const float* __restrict__ la, const float* __restrict__ tse,
    const int* __restrict__ bp, const int* __restrict__ tt,
    const float* __restrict__ cr, const float* __restrict__ tsp,
    const float* __restrict__ tg, const float* __restrict__ r7,
    const float* __restrict__ r30,
    const float* __restrict__ tx_emb, const float* __restrict__ bank_emb,
    const float* __restrict__ w1t /*[128][40]*/, const float* __restrict__ eb1,
    const float* __restrict__ w2 /*[128][64]*/, const float* __restrict__ eb2,
    float* __restrict__ ea) {
    int e = blockIdx.x * blockDim.x + threadIdx.x;
    if (e >= N_EDGES) return;
    float f[38];
    f[0] = la[e]; f[1] = cr[e]; f[2] = tsp[e]; f[3] = tg[e]; f[4] = r7[e]; f[5] = r30[e];
#pragma unroll
    for (int i = 0; i < 8; i++) f[6 + i] = tse[e * 8 + i];
    int txi = tt[e];
#pragma unroll
    for (int i = 0; i < 8; i++) f[14 + i] = tx_emb[txi * 8 + i];
    int bk0 = bp[e * 2 + 0], bk1 = bp[e * 2 + 1];
#pragma unroll
    for (int i = 0; i < 8; i++) f[22 + i] = bank_emb[bk0 * 8 + i];
#pragma unroll
    for (int i = 0; i < 8; i++) f[30 + i] = bank_emb[bk1 * 8 + i];

    float acc[64];
#pragma unroll
    for (int o = 0; o < 64; o++) acc[o] = eb2[o];
    for (int j = 0; j < 128; j++) {
        float h = eb1[j];
        const float* wr = w1t + j * 40;
#pragma unroll
        for (int k = 0; k < 38; k++) h = fmaf(f[k], wr[k], h);
        h = fmaxf(h, 0.f);
        const float* w2r = w2 + j * 64;
#pragma unroll
        for (int o = 0; o < 64; o++) acc[o] = fmaf(h, w2r[o], acc[o]);
    }
    float* er = ea + (long)e * 64;
#pragma unroll
    for (int o = 0; o < 64; o++) er[o] = acc[o];
}

// ---------------- generic node-level GEMM: out[n, j0:j0+JC] = act(b + in1@W[:K1] + (in2/deg)@W[K1:]) ---
template <int K1, int K2, int JC, bool RELU, bool DIV2>
__global__ __launch_bounds__(256) void k_node_gemm(
    const float* __restrict__ in1, int ld1,
    const float* __restrict__ in2, int ld2,
    const int* __restrict__ degi,
    const float* __restrict__ W, int ldw,
    const float* __restrict__ bias,
    float* __restrict__ out, int ldo, int nrows) {
    int n = blockIdx.x * blockDim.x + threadIdx.x;
    if (n >= nrows) return;
    int j0 = blockIdx.y * JC;
    float acc[JC];
#pragma unroll
    for (int j = 0; j < JC; j++) acc[j] = bias ? bias[j0 + j] : 0.f;
    const float* r1 = in1 + (long)n * ld1;
    for (int k = 0; k < K1; k++) {
        float v = r1[k];
        const float* wr = W + (long)k * ldw + j0;
#pragma unroll
        for (int j = 0; j < JC; j++) acc[j] = fmaf(v, wr[j], acc[j]);
    }
    if constexpr (K2 > 0) {
        float dinv = 1.f;
        if constexpr (DIV2) dinv = 1.f / ((float)degi[n] + 1e-6f);
        const float* r2 = in2 + (long)n * ld2;
        for (int k = 0; k < K2; k++) {
            float v = r2[k] * dinv;
            const float* wr = W + (long)(K1 + k) * ldw + j0;
#pragma unroll
            for (int j = 0; j < JC; j++) acc[j] = fmaf(v, wr[j], acc[j]);
        }
    }
    float* orow = out + (long)n * ldo + j0;
#pragma unroll
    for (int j = 0; j < JC; j++) {
        float v = acc[j];
        if (RELU) v = fmaxf(v, 0.f);
        orow[j] = v;
    }
}

// ---------------- CSR gather: s[n, j0:j0+JC] = sum_e relu(P[src_e] + ea_e @ Wbot + b) --------
// W is the bottom half of msg_w, layout [k][j] with leading dim ldw (=128).
template <int JC>
__global__ __launch_bounds__(256) void k_gather(
    const float* __restrict__ P, const float* __restrict__ ea,
    const float* __restrict__ W, int ldw, const float* __restrict__ bias,
    const int* __restrict__ src, const int* __restrict__ row_start,
    const int* __restrict__ eid, float* __restrict__ s, int ldo) {
    int n = blockIdx.x * blockDim.x + threadIdx.x;
    if (n >= N_NODES) return;
    int j0 = blockIdx.y * JC;
    float acc[JC];
#pragma unroll
    for (int j = 0; j < JC; j++) acc[j] = 0.f;
    int e0 = row_start[n], e1 = row_start[n + 1];
    for (int idx = e0; idx < e1; idx++) {
        int e = eid[idx];
        int sn = src[e];
        float t[JC];
        const float4* Pr = (const float4*)(P + (long)sn * 128 + j0);
#pragma unroll
        for (int i = 0; i < JC / 4; i++) {
            float4 v = Pr[i];
            t[4 * i + 0] = v.x + bias[j0 + 4 * i + 0];
            t[4 * i + 1] = v.y + bias[j0 + 4 * i + 1];
            t[4 * i + 2] = v.z + bias[j0 + 4 * i + 2];
            t[4 * i + 3] = v.w + bias[j0 + 4 * i + 3];
        }
        const float4* ar = (const float4*)(ea + (long)e * 64);
#pragma unroll
        for (int k4 = 0; k4 < 16; k4++) {
            float4 av = ar[k4];
            const float* w0 = W + (long)(4 * k4 + 0) * ldw + j0;
            const float* w1 = W + (long)(4 * k4 + 1) * ldw + j0;
            const float* w2 = W + (long)(4 * k4 + 2) * ldw + j0;
            const float* w3 = W + (long)(4 * k4 + 3) * ldw + j0;
#pragma unroll
            for (int j = 0; j < JC; j++) t[j] = fmaf(av.x, w0[j], t[j]);
#pragma unroll
            for (int j = 0; j < JC; j++) t[j] = fmaf(av.y, w1[j], t[j]);
#pragma unroll
            for (int j = 0; j < JC; j++) t[j] = fmaf(av.z, w2[j], t[j]);
#pragma unroll
            for (int j = 0; j < JC; j++) t[j] = fmaf(av.w, w3[j], t[j]);
        }
#pragma unroll
        for (int j = 0; j < JC; j++) acc[j] += fmaxf(t[j], 0.f);
    }
    float* orow = s + (long)n * ldo + j0;
#pragma unroll
    for (int j = 0; j < JC; j++) orow[j] = acc[j];
}

// ---------------- edge classifier ------------------------------------------------------
__global__ __launch_bounds__(256) void k_edge_cls(
    const float* __restrict__ nS, const float* __restrict__ nD,
    const float* __restrict__ ea, const float* __restrict__ Ct /*[64][64]*/,
    const float* __restrict__ b1, const float* __restrict__ w2, const float* __restrict__ b2,
    const int* __restrict__ src, const int* __restrict__ dst,
    float* __restrict__ logits_out, float* __restrict__ probs) {
    int e = blockIdx.x * blockDim.x + threadIdx.x;
    if (e >= N_EDGES) return;
    int sn = src[e], dn = dst[e];
    float a[64];
    const float4* ar = (const float4*)(ea + (long)e * 64);
#pragma unroll
    for (int i = 0; i < 16; i++) {
        float4 v = ar[i];
        a[4 * i] = v.x; a[4 * i + 1] = v.y; a[4 * i + 2] = v.z; a[4 * i + 3] = v.w;
    }
    const float* Sr = nS + (long)sn * 64;
    const float* Dr = nD + (long)dn * 64;
    float logit = b2[0];
    for (int j = 0; j < 64; j++) {
        float t = b1[j];
        const float* wr = Ct + j * 64;
#pragma unroll
        for (int k = 0; k < 64; k++) t = fmaf(a[k], wr[k], t);
        t += Sr[j] + Dr[j];
        t = fmaxf(t, 0.f);
        logit = fmaf(t, w2[j], logit);
    }
    logits_out[e] = logit;
    probs[e] = 1.f / (1.f + expf(-logit));
}

// ---------------- ts max reduction -----------------------------------------------------
__global__ void k_tsmax(const int* __restrict__ ts, int* __restrict__ out) {
    int i = blockIdx.x * blockDim.x + threadIdx.x;
    int stride = gridDim.x * blockDim.x;
    int m = 0;
    for (int t = i; t < N_EDGES; t += stride) m = max(m, ts[t]);
#pragma unroll
    for (int off = 32; off > 0; off >>= 1) m = max(m, __shfl_down(m, off));
    if ((threadIdx.x & 63) == 0) atomicMax(out, m);
}

// ---------------- per-edge aggregation into node stats ---------------------------------
// stats layout: 0 cnt, 1 sum_p, 2 max_p, 3 sum_high, 4 sum_p*decay, 5 sum_decay,
//               6 sum_high30, 7 max_p30, 8 sum_p30, 9 sum_l30, 10 min_age
__global__ __launch_bounds__(256) void k_edge_agg(
    const float* __restrict__ probs, const int* __restrict__ uts,
    const int* __restrict__ src, const int* __restrict__ dst,
    const int* __restrict__ tsmax, float* __restrict__ stats) {
    int e = blockIdx.x * blockDim.x + threadIdx.x;
    if (e >= N_EDGES) return;
    float p = probs[e];
    float now = (float)(*tsmax);
    float ts = (float)uts[e];
    float age = fmaxf(now - ts, 0.f);
    float decay = expf(-age / 2592000.f);
    bool high = p >= 0.7f;
    bool l30 = age <= 2592000.f;
    float aged = age / 86400.f;
    float* cnt = stats;
    float* sump = stats + N_NODES;
    float* maxp = stats + 2 * N_NODES;
    float* sumh = stats + 3 * N_NODES;
    float* sumpd = stats + 4 * N_NODES;
    float* sumd = stats + 5 * N_NODES;
    float* sumh30 = stats + 6 * N_NODES;
    float* maxp30 = stats + 7 * N_NODES;
    float* sump30 = stats + 8 * N_NODES;
    float* suml30 = stats + 9 * N_NODES;
    float* minage = stats + 10 * N_NODES;
    int nn[2] = {src[e], dst[e]};
#pragma unroll
    for (int i = 0; i < 2; i++) {
        int n = nn[i];
        atomicAdd(cnt + n, 1.f);
        atomicAdd(sump + n, p);
        atomicMaxF(maxp + n, p);
        atomicAdd(sumpd + n, p * decay);
        atomicAdd(sumd + n, decay);
        if (high) atomicAdd(sumh + n, 1.f);
        if (l30) {
            atomicAdd(sump30 + n, p);
            atomicAdd(suml30 + n, 1.f);
            atomicMaxF(maxp30 + n, p);
            if (high) atomicAdd(sumh30 + n, 1.f);
        }
        if (high) atomicMinF(minage + n, aged);
    }
}

// ---------------- node classifier ------------------------------------------------------
__global__ __launch_bounds__(256) void k_node_cls(
    const float* __restrict__ ne, const float* __restrict__ stats,
    const float* __restrict__ w1t /*[64][72]*/, const float* __restrict__ b1,
    const float* __restrict__ gamma, const float* __restrict__ beta,
    const float* __restrict__ mean, const float* __restrict__ var,
    const float* __restrict__ w2, const float* __restrict__ b2,
    float* __restrict__ out) {
    int n = blockIdx.x * blockDim.x + threadIdx.x;
    if (n >= N_NODES) return;
    float in[72];
    const float4* nr = (const float4*)(ne + (long)n * 64);
#pragma unroll
    for (int i = 0; i < 16; i++) {
        float4 v = nr[i];
        in[4 * i] = v.x; in[4 * i + 1] = v.y; in[4 * i + 2] = v.z; in[4 * i + 3] = v.w;
    }
    float c = stats[n];
    in[64] = stats[N_NODES + n] / (c + 1e-6f);
    in[65] = stats[2 * N_NODES + n];
    in[66] = log1pf(stats[3 * N_NODES + n]);
    in[67] = stats[4 * N_NODES + n] / (stats[5 * N_NODES + n] + 1e-6f);
    in[68] = log1pf(stats[6 * N_NODES + n]);
    in[69] = stats[7 * N_NODES + n];
    in[70] = stats[8 * N_NODES + n] / (stats[9 * N_NODES + n] + 1e-6f);
    float ma = fminf(stats[10 * N_NODES + n], 9999.f);
    in[71] = log1pf(fminf(ma, 90.f)) / log1pf(90.f);
    float logit = b2[0];
    for (int j = 0; j < 64; j++) {
        float h = b1[j];
        const float* wr = w1t + j * 72;
#pragma unroll
        for (int k = 0; k < 72; k++) h = fmaf(in[k], wr[k], h);
        h = (h - mean[j]) * rsqrtf(var[j] + 1e-5f) * gamma[j] + beta[j];
        h = fmaxf(h, 0.f);
        logit = fmaf(h, w2[j], logit);
    }
    out[n] = logit;
}

extern "C" void kernel_launch(void* const* d_in, const int* in_sizes, int n_in,
                              void* d_out, int out_size, void* d_ws, size_t ws_size,
                              hipStream_t stream) {
    const float* x = (const float*)d_in[0];
    const int* eidx = (const int*)d_in[1];
    const int* src = eidx;
    const int* dst = eidx + N_EDGES;
    const float* la = (const float*)d_in[2];
    const float* tse = (const float*)d_in[3];
    const int* bp = (const int*)d_in[4];
    const int* tt = (const int*)d_in[5];
    const float* cr = (const float*)d_in[6];
    const float* tsp = (const float*)d_in[7];
    const float* tg = (const float*)d_in[8];
    const float* r7 = (const float*)d_in[9];
    const float* r30 = (const float*)d_in[10];
    const int* uts = (const int*)d_in[11];
    const float* tx_emb = (const float*)d_in[12];
    const float* bank_emb = (const float*)d_in[13];
    const float* ee_w1 = (const float*)d_in[14];
    const float* ee_b1 = (const float*)d_in[15];
    const float* ee_w2 = (const float*)d_in[16];
    const float* ee_b2 = (const float*)d_in[17];
    const float* msg1_w = (const float*)d_in[18];
    const float* msg1_b = (const float*)d_in[19];
    const float* upd1_w = (const float*)d_in[20];
    const float* upd1_b = (const float*)d_in[21];
    const float* msg2_w = (const float*)d_in[22];
    const float* msg2_b = (const float*)d_in[23];
    const float* upd2_w = (const float*)d_in[24];
    const float* upd2_b = (const float*)d_in[25];
    const float* ec_w1 = (const float*)d_in[26];
    const float* ec_b1 = (const float*)d_in[27];
    const float* ec_w2 = (const float*)d_in[28];
    const float* ec_b2 = (const float*)d_in[29];
    const float* nc_w1 = (const float*)d_in[30];
    const float* nc_b1 = (const float*)d_in[31];
    const float* bn_g = (const float*)d_in[32];
    const float* bn_b = (const float*)d_in[33];
    const float* bn_m = (const float*)d_in[34];
    const float* bn_v = (const float*)d_in[35];
    const float* nc_w2 = (const float*)d_in[36];
    const float* nc_b2 = (const float*)d_in[37];

    float* out_node = (float*)d_out;              // [N_NODES]
    float* out_edge = (float*)d_out + N_NODES;    // [N_EDGES]

    // workspace layout (floats)
    float* ws = (float*)d_ws;
    float* ea = ws;                         // E*64
    float* P = ea + (long)N_EDGES * 64;     // N*128
    float* s = P + (long)N_NODES * 128;     // N*128
    float* h1 = s + (long)N_NODES * 128;    // N*128
    float* ne = h1 + (long)N_NODES * 128;   // N*64
    float* nS = ne + (long)N_NODES * 64;    // N*64
    float* nD = nS + (long)N_NODES * 64;    // N*64
    float* probs = nD + (long)N_NODES * 64; // E
    float* stats = probs + N_EDGES;         // 11*N
    float* w1t = stats + 11 * N_NODES;      // 128*40
    float* Ct = w1t + 128 * 40;             // 64*64
    float* ncw1t = Ct + 64 * 64;            // 64*72
    int* tsmax = (int*)(ncw1t + 64 * 72);   // 1
    int* degi = tsmax + 1;                  // N
    int* row_start = degi + N_NODES;        // N+1
    int* cursor = row_start + N_NODES + 1;  // N
    int* eid = cursor + N_NODES;            // E
    int* partials = eid + N_EDGES;          // 256

    const int EB = (N_EDGES + 255) / 256;   // 1954
    const int NB = (N_NODES + 255) / 256;   // 196

    // ---- init ----
    hipMemsetAsync(stats, 0, (size_t)10 * N_NODES * 4, stream);
    hipMemsetAsync(tsmax, 0, 4, stream);
    hipMemsetAsync(degi, 0, (size_t)N_NODES * 4, stream);
    k_fill<<<NB, 256, 0, stream>>>(stats + 10 * N_NODES, 9999.f, N_NODES);

    // ---- CSR build (by dst) ----
    k_deg_count<<<EB, 256, 0, stream>>>(dst, degi);
    k_block_sums<<<NB, 256, 0, stream>>>(degi, partials, N_NODES);
    k_scan_partials<<<1, 256, 0, stream>>>(partials, NB);
    k_scan_final<<<NB, 256, 0, stream>>>(degi, partials, row_start, N_NODES);
    hipMemcpyAsync(cursor, row_start, (size_t)N_NODES * 4, hipMemcpyDeviceToDevice, stream);
    k_fill_slots<<<EB, 256, 0, stream>>>(dst, cursor, eid);

    // ---- weight transposes ----
    k_transpose<<<(38 * 128 + 255) / 256, 256, 0, stream>>>(ee_w1, w1t, 38, 128, 128, 40);
    k_transpose<<<(64 * 64 + 255) / 256, 256, 0, stream>>>(ec_w1 + 128 * 64, Ct, 64, 64, 64, 64);
    k_transpose<<<(72 * 64 + 255) / 256, 256, 0, stream>>>(nc_w1, ncw1t, 72, 64, 64, 72);

    // ---- edge encoder ----
    k_edge_encoder<<<EB, 256, 0, stream>>>(la, tse, bp, tt, cr, tsp, tg, r7, r30,
                                           tx_emb, bank_emb, w1t, ee_b1, ee_w2, ee_b2, ea);

    // ---- SAGE layer 1 ----
    k_node_gemm<128, 0, 64, false, false><<<dim3(NB, 2), 256, 0, stream>>>(
        x, 128, nullptr, 0, nullptr, msg1_w, 128, nullptr, P, 128, N_NODES);
    k_gather<32><<<dim3(NB, 4), 256, 0, stream>>>(
        P, ea, msg1_w + 128 * 128, 128, msg1_b, src, row_start, eid, s, 128);
    k_node_gemm<128, 128, 64, true, true><<<dim3(NB, 2), 256, 0, stream>>>(
        x, 128, s, 128, degi, upd1_w, 128, upd1_b, h1, 128, N_NODES);

    // ---- SAGE layer 2 ----
    k_node_gemm<128, 0, 64, false, false><<<dim3(NB, 2), 256, 0, stream>>>(
        h1, 128, nullptr, 0, nullptr, msg2_w, 128, nullptr, P, 128, N_NODES);
    k_gather<32><<<dim3(NB, 4), 256, 0, stream>>>(
        P, ea, msg2_w + 128 * 128, 128, msg2_b, src, row_start, eid, s, 128);
    k_node_gemm<128, 128, 64, true, true><<<dim3(NB, 1), 256, 0, stream>>>(
        h1, 128, s, 128, degi, upd2_w, 64, upd2_b, ne, 64, N_NODES);

    // ---- edge classifier ----
    k_node_gemm<64, 0, 64, false, false><<<dim3(NB, 1), 256, 0, stream>>>(
        ne, 64, nullptr, 0, nullptr, ec_w1, 64, nullptr, nS, 64, N_NODES);
    k_node_gemm<64, 0, 64, false, false><<<dim3(NB, 1), 256, 0, stream>>>(
        ne, 64, nullptr, 0, nullptr, ec_w1 + 64 * 64, 64, nullptr, nD, 64, N_NODES);
    k_edge_cls<<<EB, 256, 0, stream>>>(nS, nD, ea, Ct, ec_b1, ec_w2, ec_b2,
                                       src, dst, out_edge, probs);

    // ---- edge aggregation ----
    k_tsmax<<<256, 256, 0, stream>>>(uts, tsmax);
    k_edge_agg<<<EB, 256, 0, stream>>>(probs, uts, src, dst, tsmax, stats);

    // ---- node classifier ----
    k_node_cls<<<NB, 256, 0, stream>>>(ne, stats, ncw1t, nc_b1, bn_g, bn_b, bn_m, bn_v,
                                       nc_w2, nc_b2, out_node);
}

// Round 4
// 2172.960 us; speedup vs baseline: 3.8855x; 1.5038x over previous
//
#include <hip/hip_runtime.h>
#include <math.h>

#define N_NODES 50000
#define N_EDGES 500000

__device__ inline void atomicMaxF(float* addr, float v) {  // v >= 0 only
    atomicMax((int*)addr, __float_as_int(v));
}
__device__ inline void atomicMinF(float* addr, float v) {  // v >= 0 only
    atomicMin((int*)addr, __float_as_int(v));
}

__global__ void k_fill(float* p, float v, int n) {
    int i = blockIdx.x * blockDim.x + threadIdx.x;
    if (i < n) p[i] = v;
}

// dst[j*kpad + k] = src[k*ldw + j], k<K, j<J
__global__ void k_transpose(const float* __restrict__ src, float* __restrict__ dst,
                            int K, int J, int ldw, int kpad) {
    int i = blockIdx.x * blockDim.x + threadIdx.x;
    if (i >= K * J) return;
    int k = i / J, j = i - k * J;
    dst[j * kpad + k] = src[k * ldw + j];
}

// =================== CSR build (edges grouped by dst) ====================
__global__ void k_deg_count(const int* __restrict__ dst, int* __restrict__ degi) {
    int e = blockIdx.x * blockDim.x + threadIdx.x;
    if (e < N_EDGES) atomicAdd(degi + dst[e], 1);
}

__global__ void k_block_sums(const int* __restrict__ deg, int* __restrict__ partials, int n) {
    __shared__ int sm[256];
    int i = blockIdx.x * 256 + threadIdx.x;
    sm[threadIdx.x] = (i < n) ? deg[i] : 0;
    __syncthreads();
    for (int s = 128; s > 0; s >>= 1) {
        if (threadIdx.x < s) sm[threadIdx.x] += sm[threadIdx.x + s];
        __syncthreads();
    }
    if (threadIdx.x == 0) partials[blockIdx.x] = sm[0];
}

// single block: in-place exclusive scan of partials[nb], nb<=256
__global__ void k_scan_partials(int* partials, int nb) {
    __shared__ int sm[256];
    int v = (threadIdx.x < nb) ? partials[threadIdx.x] : 0;
    sm[threadIdx.x] = v;
    __syncthreads();
    for (int off = 1; off < 256; off <<= 1) {
        int t = (threadIdx.x >= off) ? sm[threadIdx.x - off] : 0;
        __syncthreads();
        sm[threadIdx.x] += t;
        __syncthreads();
    }
    if (threadIdx.x < nb) partials[threadIdx.x] = sm[threadIdx.x] - v;  // exclusive
}

__global__ void k_scan_final(const int* __restrict__ deg, const int* __restrict__ partials,
                             int* __restrict__ row_start, int n) {
    __shared__ int sm[256];
    int i = blockIdx.x * 256 + threadIdx.x;
    int v = (i < n) ? deg[i] : 0;
    sm[threadIdx.x] = v;
    __syncthreads();
    for (int off = 1; off < 256; off <<= 1) {
        int t = (threadIdx.x >= off) ? sm[threadIdx.x - off] : 0;
        __syncthreads();
        sm[threadIdx.x] += t;
        __syncthreads();
    }
    if (i < n) row_start[i] = partials[blockIdx.x] + sm[threadIdx.x] - v;  // exclusive
    if (i == n - 1) row_start[n] = partials[blockIdx.x] + sm[threadIdx.x]; // total
}

__global__ void k_fill_slots(const int* __restrict__ dst, int* __restrict__ cursor,
                             int* __restrict__ eid) {
    int e = blockIdx.x * blockDim.x + threadIdx.x;
    if (e >= N_EDGES) return;
    int pos = atomicAdd(cursor + dst[e], 1);
    eid[pos] = e;
}

// ---------------- edge encoder: feats(38) -> relu(@w1+b1)(128) -> @w2+b2 (64) ----------
__global__ __launch_bounds__(256) void k_edge_encoder(
    const float* __restrict__ la, const float* __restrict__ tse,
    const int* __restrict__ bp, const int* __restrict__ tt,
    const float* __restrict__ cr, const float* __restrict__ tsp,
    const float* __restrict__ tg, const float* __restrict__ r7,
    const float* __restrict__ r30,
    const float* __restrict__ tx_emb, const float* __restrict__ bank_emb,
    const float* __restrict__ w1t /*[128][40]*/, const float* __restrict__ eb1,
    const float* __restrict__ w2 /*[128][64]*/, const float* __restrict__ eb2,
    float* __restrict__ ea) {
    int e = blockIdx.x * blockDim.x + threadIdx.x;
    if (e >= N_EDGES) return;
    float f[38];
    f[0] = la[e]; f[1] = cr[e]; f[2] = tsp[e]; f[3] = tg[e]; f[4] = r7[e]; f[5] = r30[e];
#pragma unroll
    for (int i = 0; i < 8; i++) f[6 + i] = tse[e * 8 + i];
    int txi = tt[e];
#pragma unroll
    for (int i = 0; i < 8; i++) f[14 + i] = tx_emb[txi * 8 + i];
    int bk0 = bp[e * 2 + 0], bk1 = bp[e * 2 + 1];
#pragma unroll
    for (int i = 0; i < 8; i++) f[22 + i] = bank_emb[bk0 * 8 + i];
#pragma unroll
    for (int i = 0; i < 8; i++) f[30 + i] = bank_emb[bk1 * 8 + i];

    float acc[64];
#pragma unroll
    for (int o = 0; o < 64; o++) acc[o] = eb2[o];
    for (int j = 0; j < 128; j++) {
        float h = eb1[j];
        const float* wr = w1t + j * 40;
#pragma unroll
        for (int k = 0; k < 38; k++) h = fmaf(f[k], wr[k], h);
        h = fmaxf(h, 0.f);
        const float* w2r = w2 + j * 64;
#pragma unroll
        for (int o = 0; o < 64; o++) acc[o] = fmaf(h, w2r[o], acc[o]);
    }
    float* er = ea + (long)e * 64;
#pragma unroll
    for (int o = 0; o < 64; o++) er[o] = acc[o];
}

// ---------------- generic node-level GEMM: out[n, j0:j0+JC] = act(b + in1@W[:K1] + (in2/deg)@W[K1:]) ---
template <int K1, int K2, int JC, bool RELU, bool DIV2>
__global__ __launch_bounds__(256) void k_node_gemm(
    const float* __restrict__ in1, int ld1,
    const float* __restrict__ in2, int ld2,
    const int* __restrict__ degi,
    const float* __restrict__ W, int ldw,
    const float* __restrict__ bias,
    float* __restrict__ out, int ldo, int nrows) {
    int n = blockIdx.x * blockDim.x + threadIdx.x;
    if (n >= nrows) return;
    int j0 = blockIdx.y * JC;
    float acc[JC];
#pragma unroll
    for (int j = 0; j < JC; j++) acc[j] = bias ? bias[j0 + j] : 0.f;
    const float* r1 = in1 + (long)n * ld1;
    for (int k = 0; k < K1; k++) {
        float v = r1[k];
        const float* wr = W + (long)k * ldw + j0;
#pragma unroll
        for (int j = 0; j < JC; j++) acc[j] = fmaf(v, wr[j], acc[j]);
    }
    if constexpr (K2 > 0) {
        float dinv = 1.f;
        if constexpr (DIV2) dinv = 1.f / ((float)degi[n] + 1e-6f);
        const float* r2 = in2 + (long)n * ld2;
        for (int k = 0; k < K2; k++) {
            float v = r2[k] * dinv;
            const float* wr = W + (long)(K1 + k) * ldw + j0;
#pragma unroll
            for (int j = 0; j < JC; j++) acc[j] = fmaf(v, wr[j], acc[j]);
        }
    }
    float* orow = out + (long)n * ldo + j0;
#pragma unroll
    for (int j = 0; j < JC; j++) {
        float v = acc[j];
        if (RELU) v = fmaxf(v, 0.f);
        orow[j] = v;
    }
}

// ---------------- fused msg GEMM + segmented sum over CSR-ordered edges ----------------
// Per block: 64 slots x 128 outputs, K=64.
//   msg_row(slot) = relu( P[src[eid[slot]]] + ea[eid[slot]] @ W + bias )
//   s[n][:] = sum over slots of node n (slots sorted by dst). Interior segments: plain
//   store; segments crossing block boundary: atomicAdd (s pre-zeroed).
__global__ __launch_bounds__(256) void k_msg_seg(
    const float* __restrict__ P, const float* __restrict__ ea,
    const float* __restrict__ W /*[64][128]*/, const float* __restrict__ bias,
    const int* __restrict__ src, const int* __restrict__ dst,
    const int* __restrict__ eid,
    float* __restrict__ s, int n_edges) {
    __shared__ float ea_s[64][64];
    __shared__ float W_s[64][128];   // reused as the msg tile after the k-loop
    __shared__ int sn_s[64];
    __shared__ int es_s[64];
    __shared__ int nid_s[64];
    __shared__ int bound_s[2];       // prev_n, next_n
    int tid = threadIdx.x;
    int t0 = blockIdx.x * 64;

    if (tid < 64) {
        int slot = t0 + tid;
        int e = (slot < n_edges) ? eid[slot] : 0;
        es_s[tid] = e;
        sn_s[tid] = src[e];
        nid_s[tid] = (slot < n_edges) ? dst[e] : -1;
    }
    if (tid == 64) bound_s[0] = (t0 > 0) ? dst[eid[t0 - 1]] : -1;
    if (tid == 65) bound_s[1] = (t0 + 64 < n_edges) ? dst[eid[t0 + 64]] : -1;
    // stage W: 64*128 floats = 2048 float4
#pragma unroll
    for (int i = 0; i < 8; i++) {
        int f = tid + 256 * i;
        ((float4*)W_s)[f] = ((const float4*)W)[f];
    }
    __syncthreads();
    // stage ea tile: 64 rows x 16 float4
#pragma unroll
    for (int i = 0; i < 4; i++) {
        int f = tid + 256 * i;
        int el = f >> 4, c = f & 15;
        float4 v = ((const float4*)(ea + (long)es_s[el] * 64))[c];
        *((float4*)&ea_s[el][c * 4]) = v;
    }
    __syncthreads();

    int jg = tid & 31;   // j0 = jg*4
    int eg = tid >> 5;   // rows eg*8 .. eg*8+7
    int j0 = jg * 4;
    float acc[8][4];
#pragma unroll
    for (int el = 0; el < 8; el++)
#pragma unroll
        for (int jj = 0; jj < 4; jj++) acc[el][jj] = 0.f;

    for (int k4 = 0; k4 < 16; k4++) {
        float4 wv[4];
#pragma unroll
        for (int kk = 0; kk < 4; kk++) wv[kk] = *(const float4*)&W_s[k4 * 4 + kk][j0];
#pragma unroll
        for (int el = 0; el < 8; el++) {
            float4 av = *(const float4*)&ea_s[eg * 8 + el][k4 * 4];
#pragma unroll
            for (int jj = 0; jj < 4; jj++) {
                float a = acc[el][jj];
                a = fmaf(av.x, ((const float*)&wv[0])[jj], a);
                a = fmaf(av.y, ((const float*)&wv[1])[jj], a);
                a = fmaf(av.z, ((const float*)&wv[2])[jj], a);
                a = fmaf(av.w, ((const float*)&wv[3])[jj], a);
                acc[el][jj] = a;
            }
        }
    }
    __syncthreads();   // everyone done reading W_s / ea_s

    // epilogue: msg = relu(acc + P[src] + bias) -> write into W_s as msg tile
    float4 bv = *(const float4*)(bias + j0);
#pragma unroll
    for (int el = 0; el < 8; el++) {
        int row = eg * 8 + el;
        float4 pv = *(const float4*)(P + (long)sn_s[row] * 128 + j0);
        float4 o;
        o.x = fmaxf(acc[el][0] + pv.x + bv.x, 0.f);
        o.y = fmaxf(acc[el][1] + pv.y + bv.y, 0.f);
        o.z = fmaxf(acc[el][2] + pv.z + bv.z, 0.f);
        o.w = fmaxf(acc[el][3] + pv.w + bv.w, 0.f);
        *((float4*)&W_s[row][j0]) = o;
    }
    __syncthreads();

    // segmented reduction: one thread per column walks the 64 rows in slot order.
    // Branches are wave-uniform (nid_s shared by all columns).
    if (tid < 128) {
        int c = tid;
        int rows = min(64, n_edges - t0);
        int prev_n = bound_s[0], next_n = bound_s[1];
        int cur = nid_s[0];
        int seg_start = 0;
        float run = 0.f;
        for (int r = 0; r < rows; r++) {
            int nd = nid_s[r];
            if (nd != cur) {
                if (seg_start == 0 && cur == prev_n) atomicAdd(s + (long)cur * 128 + c, run);
                else s[(long)cur * 128 + c] = run;
                cur = nd; seg_start = r; run = 0.f;
            }
            run += W_s[r][c];
        }
        if ((seg_start == 0 && cur == prev_n) || cur == next_n)
            atomicAdd(s + (long)cur * 128 + c, run);
        else s[(long)cur * 128 + c] = run;
    }
}

// ---------------- edge classifier ------------------------------------------------------
__global__ __launch_bounds__(256) void k_edge_cls(
    const float* __restrict__ nS, const float* __restrict__ nD,
    const float* __restrict__ ea, const float* __restrict__ Ct /*[64][64]*/,
    const float* __restrict__ b1, const float* __restrict__ w2, const float* __restrict__ b2,
    const int* __restrict__ src, const int* __restrict__ dst,
    float* __restrict__ logits_out, float* __restrict__ probs) {
    int e = blockIdx.x * blockDim.x + threadIdx.x;
    if (e >= N_EDGES) return;
    int sn = src[e], dn = dst[e];
    float a[64];
    const float4* ar = (const float4*)(ea + (long)e * 64);
#pragma unroll
    for (int i = 0; i < 16; i++) {
        float4 v = ar[i];
        a[4 * i] = v.x; a[4 * i + 1] = v.y; a[4 * i + 2] = v.z; a[4 * i + 3] = v.w;
    }
    const float* Sr = nS + (long)sn * 64;
    const float* Dr = nD + (long)dn * 64;
    float logit = b2[0];
    for (int j = 0; j < 64; j++) {
        float t = b1[j];
        const float* wr = Ct + j * 64;
#pragma unroll
        for (int k = 0; k < 64; k++) t = fmaf(a[k], wr[k], t);
        t += Sr[j] + Dr[j];
        t = fmaxf(t, 0.f);
        logit = fmaf(t, w2[j], logit);
    }
    logits_out[e] = logit;
    probs[e] = 1.f / (1.f + expf(-logit));
}

// ---------------- ts max reduction -----------------------------------------------------
__global__ void k_tsmax(const int* __restrict__ ts, int* __restrict__ out) {
    int i = blockIdx.x * blockDim.x + threadIdx.x;
    int stride = gridDim.x * blockDim.x;
    int m = 0;
    for (int t = i; t < N_EDGES; t += stride) m = max(m, ts[t]);
#pragma unroll
    for (int off = 32; off > 0; off >>= 1) m = max(m, __shfl_down(m, off));
    if ((threadIdx.x & 63) == 0) atomicMax(out, m);
}

// ---------------- per-edge aggregation into node stats ---------------------------------
// stats layout: 0 cnt, 1 sum_p, 2 max_p, 3 sum_high, 4 sum_p*decay, 5 sum_decay,
//               6 sum_high30, 7 max_p30, 8 sum_p30, 9 sum_l30, 10 min_age
__global__ __launch_bounds__(256) void k_edge_agg(
    const float* __restrict__ probs, const int* __restrict__ uts,
    const int* __restrict__ src, const int* __restrict__ dst,
    const int* __restrict__ tsmax, float* __restrict__ stats) {
    int e = blockIdx.x * blockDim.x + threadIdx.x;
    if (e >= N_EDGES) return;
    float p = probs[e];
    float now = (float)(*tsmax);
    float ts = (float)uts[e];
    float age = fmaxf(now - ts, 0.f);
    float decay = expf(-age / 2592000.f);
    bool high = p >= 0.7f;
    bool l30 = age <= 2592000.f;
    float aged = age / 86400.f;
    float* cnt = stats;
    float* sump = stats + N_NODES;
    float* maxp = stats + 2 * N_NODES;
    float* sumh = stats + 3 * N_NODES;
    float* sumpd = stats + 4 * N_NODES;
    float* sumd = stats + 5 * N_NODES;
    float* sumh30 = stats + 6 * N_NODES;
    float* maxp30 = stats + 7 * N_NODES;
    float* sump30 = stats + 8 * N_NODES;
    float* suml30 = stats + 9 * N_NODES;
    float* minage = stats + 10 * N_NODES;
    int nn[2] = {src[e], dst[e]};
#pragma unroll
    for (int i = 0; i < 2; i++) {
        int n = nn[i];
        atomicAdd(cnt + n, 1.f);
        atomicAdd(sump + n, p);
        atomicMaxF(maxp + n, p);
        atomicAdd(sumpd + n, p * decay);
        atomicAdd(sumd + n, decay);
        if (high) atomicAdd(sumh + n, 1.f);
        if (l30) {
            atomicAdd(sump30 + n, p);
            atomicAdd(suml30 + n, 1.f);
            atomicMaxF(maxp30 + n, p);
            if (high) atomicAdd(sumh30 + n, 1.f);
        }
        if (high) atomicMinF(minage + n, aged);
    }
}

// ---------------- node classifier ------------------------------------------------------
__global__ __launch_bounds__(256) void k_node_cls(
    const float* __restrict__ ne, const float* __restrict__ stats,
    const float* __restrict__ w1t /*[64][72]*/, const float* __restrict__ b1,
    const float* __restrict__ gamma, const float* __restrict__ beta,
    const float* __restrict__ mean, const float* __restrict__ var,
    const float* __restrict__ w2, const float* __restrict__ b2,
    float* __restrict__ out) {
    int n = blockIdx.x * blockDim.x + threadIdx.x;
    if (n >= N_NODES) return;
    float in[72];
    const float4* nr = (const float4*)(ne + (long)n * 64);
#pragma unroll
    for (int i = 0; i < 16; i++) {
        float4 v = nr[i];
        in[4 * i] = v.x; in[4 * i + 1] = v.y; in[4 * i + 2] = v.z; in[4 * i + 3] = v.w;
    }
    float c = stats[n];
    in[64] = stats[N_NODES + n] / (c + 1e-6f);
    in[65] = stats[2 * N_NODES + n];
    in[66] = log1pf(stats[3 * N_NODES + n]);
    in[67] = stats[4 * N_NODES + n] / (stats[5 * N_NODES + n] + 1e-6f);
    in[68] = log1pf(stats[6 * N_NODES + n]);
    in[69] = stats[7 * N_NODES + n];
    in[70] = stats[8 * N_NODES + n] / (stats[9 * N_NODES + n] + 1e-6f);
    float ma = fminf(stats[10 * N_NODES + n], 9999.f);
    in[71] = log1pf(fminf(ma, 90.f)) / log1pf(90.f);
    float logit = b2[0];
    for (int j = 0; j < 64; j++) {
        float h = b1[j];
        const float* wr = w1t + j * 72;
#pragma unroll
        for (int k = 0; k < 72; k++) h = fmaf(in[k], wr[k], h);
        h = (h - mean[j]) * rsqrtf(var[j] + 1e-5f) * gamma[j] + beta[j];
        h = fmaxf(h, 0.f);
        logit = fmaf(h, w2[j], logit);
    }
    out[n] = logit;
}

extern "C" void kernel_launch(void* const* d_in, const int* in_sizes, int n_in,
                              void* d_out, int out_size, void* d_ws, size_t ws_size,
                              hipStream_t stream) {
    const float* x = (const float*)d_in[0];
    const int* eidx = (const int*)d_in[1];
    const int* src = eidx;
    const int* dst = eidx + N_EDGES;
    const float* la = (const float*)d_in[2];
    const float* tse = (const float*)d_in[3];
    const int* bp = (const int*)d_in[4];
    const int* tt = (const int*)d_in[5];
    const float* cr = (const float*)d_in[6];
    const float* tsp = (const float*)d_in[7];
    const float* tg = (const float*)d_in[8];
    const float* r7 = (const float*)d_in[9];
    const float* r30 = (const float*)d_in[10];
    const int* uts = (const int*)d_in[11];
    const float* tx_emb = (const float*)d_in[12];
    const float* bank_emb = (const float*)d_in[13];
    const float* ee_w1 = (const float*)d_in[14];
    const float* ee_b1 = (const float*)d_in[15];
    const float* ee_w2 = (const float*)d_in[16];
    const float* ee_b2 = (const float*)d_in[17];
    const float* msg1_w = (const float*)d_in[18];
    const float* msg1_b = (const float*)d_in[19];
    const float* upd1_w = (const float*)d_in[20];
    const float* upd1_b = (const float*)d_in[21];
    const float* msg2_w = (const float*)d_in[22];
    const float* msg2_b = (const float*)d_in[23];
    const float* upd2_w = (const float*)d_in[24];
    const float* upd2_b = (const float*)d_in[25];
    const float* ec_w1 = (const float*)d_in[26];
    const float* ec_b1 = (const float*)d_in[27];
    const float* ec_w2 = (const float*)d_in[28];
    const float* ec_b2 = (const float*)d_in[29];
    const float* nc_w1 = (const float*)d_in[30];
    const float* nc_b1 = (const float*)d_in[31];
    const float* bn_g = (const float*)d_in[32];
    const float* bn_b = (const float*)d_in[33];
    const float* bn_m = (const float*)d_in[34];
    const float* bn_v = (const float*)d_in[35];
    const float* nc_w2 = (const float*)d_in[36];
    const float* nc_b2 = (const float*)d_in[37];

    float* out_node = (float*)d_out;              // [N_NODES]
    float* out_edge = (float*)d_out + N_NODES;    // [N_EDGES]

    // workspace layout (floats) — total ~250 MB (fits; round-3's +128MB mbuf overflowed)
    float* ws = (float*)d_ws;
    float* ea = ws;                         // E*64
    float* P = ea + (long)N_EDGES * 64;     // N*128
    float* s = P + (long)N_NODES * 128;     // N*128
    float* h1 = s + (long)N_NODES * 128;    // N*128
    float* ne = h1 + (long)N_NODES * 128;   // N*64
    float* nS = ne + (long)N_NODES * 64;    // N*64
    float* nD = nS + (long)N_NODES * 64;    // N*64
    float* probs = nD + (long)N_NODES * 64; // E
    float* stats = probs + N_EDGES;         // 11*N
    float* w1t = stats + 11 * N_NODES;      // 128*40
    float* Ct = w1t + 128 * 40;             // 64*64
    float* ncw1t = Ct + 64 * 64;            // 64*72
    int* tsmax = (int*)(ncw1t + 64 * 72);   // 1
    int* degi = tsmax + 1;                  // N
    int* row_start = degi + N_NODES;        // N+1
    int* cursor = row_start + N_NODES + 1;  // N
    int* eid = cursor + N_NODES;            // E
    int* partials = eid + N_EDGES;          // 256

    const int EB = (N_EDGES + 255) / 256;   // 1954
    const int NB = (N_NODES + 255) / 256;   // 196
    const int MB = (N_EDGES + 63) / 64;     // 7813

    // ---- init ----
    hipMemsetAsync(stats, 0, (size_t)10 * N_NODES * 4, stream);
    hipMemsetAsync(tsmax, 0, 4, stream);
    hipMemsetAsync(degi, 0, (size_t)N_NODES * 4, stream);
    hipMemsetAsync(s, 0, (size_t)N_NODES * 128 * 4, stream);
    k_fill<<<NB, 256, 0, stream>>>(stats + 10 * N_NODES, 9999.f, N_NODES);

    // ---- CSR build (by dst) ----
    k_deg_count<<<EB, 256, 0, stream>>>(dst, degi);
    k_block_sums<<<NB, 256, 0, stream>>>(degi, partials, N_NODES);
    k_scan_partials<<<1, 256, 0, stream>>>(partials, NB);
    k_scan_final<<<NB, 256, 0, stream>>>(degi, partials, row_start, N_NODES);
    hipMemcpyAsync(cursor, row_start, (size_t)N_NODES * 4, hipMemcpyDeviceToDevice, stream);
    k_fill_slots<<<EB, 256, 0, stream>>>(dst, cursor, eid);

    // ---- weight transposes ----
    k_transpose<<<(38 * 128 + 255) / 256, 256, 0, stream>>>(ee_w1, w1t, 38, 128, 128, 40);
    k_transpose<<<(64 * 64 + 255) / 256, 256, 0, stream>>>(ec_w1 + 128 * 64, Ct, 64, 64, 64, 64);
    k_transpose<<<(72 * 64 + 255) / 256, 256, 0, stream>>>(nc_w1, ncw1t, 72, 64, 64, 72);

    // ---- edge encoder ----
    k_edge_encoder<<<EB, 256, 0, stream>>>(la, tse, bp, tt, cr, tsp, tg, r7, r30,
                                           tx_emb, bank_emb, w1t, ee_b1, ee_w2, ee_b2, ea);

    // ---- SAGE layer 1 ----
    k_node_gemm<128, 0, 64, false, false><<<dim3(NB, 2), 256, 0, stream>>>(
        x, 128, nullptr, 0, nullptr, msg1_w, 128, nullptr, P, 128, N_NODES);
    k_msg_seg<<<MB, 256, 0, stream>>>(P, ea, msg1_w + 128 * 128, msg1_b, src, dst, eid, s, N_EDGES);
    k_node_gemm<128, 128, 64, true, true><<<dim3(NB, 2), 256, 0, stream>>>(
        x, 128, s, 128, degi, upd1_w, 128, upd1_b, h1, 128, N_NODES);

    // ---- SAGE layer 2 ----
    k_node_gemm<128, 0, 64, false, false><<<dim3(NB, 2), 256, 0, stream>>>(
        h1, 128, nullptr, 0, nullptr, msg2_w, 128, nullptr, P, 128, N_NODES);
    hipMemsetAsync(s, 0, (size_t)N_NODES * 128 * 4, stream);
    k_msg_seg<<<MB, 256, 0, stream>>>(P, ea, msg2_w + 128 * 128, msg2_b, src, dst, eid, s, N_EDGES);
    k_node_gemm<128, 128, 64, true, true><<<dim3(NB, 1), 256, 0, stream>>>(
        h1, 128, s, 128, degi, upd2_w, 64, upd2_b, ne, 64, N_NODES);

    // ---- edge classifier ----
    k_node_gemm<64, 0, 64, false, false><<<dim3(NB, 1), 256, 0, stream>>>(
        ne, 64, nullptr, 0, nullptr, ec_w1, 64, nullptr, nS, 64, N_NODES);
    k_node_gemm<64, 0, 64, false, false><<<dim3(NB, 1), 256, 0, stream>>>(
        ne, 64, nullptr, 0, nullptr, ec_w1 + 64 * 64, 64, nullptr, nD, 64, N_NODES);
    k_edge_cls<<<EB, 256, 0, stream>>>(nS, nD, ea, Ct, ec_b1, ec_w2, ec_b2,
                                       src, dst, out_edge, probs);

    // ---- edge aggregation ----
    k_tsmax<<<256, 256, 0, stream>>>(uts, tsmax);
    k_edge_agg<<<EB, 256, 0, stream>>>(probs, uts, src, dst, tsmax, stats);

    // ---- node classifier ----
    k_node_cls<<<NB, 256, 0, stream>>>(ne, stats, ncw1t, nc_b1, bn_g, bn_b, bn_m, bn_v,
                                       nc_w2, nc_b2, out_node);
}

// Round 5
// 1735.525 us; speedup vs baseline: 4.8648x; 1.2520x over previous
//
#include <hip/hip_runtime.h>
#include <math.h>

#define N_NODES 50000
#define N_EDGES 500000

__device__ inline void atomicMaxF(float* addr, float v) {  // v >= 0 only
    atomicMax((int*)addr, __float_as_int(v));
}
__device__ inline void atomicMinF(float* addr, float v) {  // v >= 0 only
    atomicMin((int*)addr, __float_as_int(v));
}

__global__ void k_fill(float* p, float v, int n) {
    int i = blockIdx.x * blockDim.x + threadIdx.x;
    if (i < n) p[i] = v;
}

// dst[j*kpad + k] = src[k*ldw + j], k<K, j<J
__global__ void k_transpose(const float* __restrict__ src, float* __restrict__ dst,
                            int K, int J, int ldw, int kpad) {
    int i = blockIdx.x * blockDim.x + threadIdx.x;
    if (i >= K * J) return;
    int k = i / J, j = i - k * J;
    dst[j * kpad + k] = src[k * ldw + j];
}

// =================== CSR build (edges grouped by dst) ====================
__global__ void k_deg_count(const int* __restrict__ dst, int* __restrict__ degi) {
    int e = blockIdx.x * blockDim.x + threadIdx.x;
    if (e < N_EDGES) atomicAdd(degi + dst[e], 1);
}

__global__ void k_block_sums(const int* __restrict__ deg, int* __restrict__ partials, int n) {
    __shared__ int sm[256];
    int i = blockIdx.x * 256 + threadIdx.x;
    sm[threadIdx.x] = (i < n) ? deg[i] : 0;
    __syncthreads();
    for (int s = 128; s > 0; s >>= 1) {
        if (threadIdx.x < s) sm[threadIdx.x] += sm[threadIdx.x + s];
        __syncthreads();
    }
    if (threadIdx.x == 0) partials[blockIdx.x] = sm[0];
}

// single block: in-place exclusive scan of partials[nb], nb<=256
__global__ void k_scan_partials(int* partials, int nb) {
    __shared__ int sm[256];
    int v = (threadIdx.x < nb) ? partials[threadIdx.x] : 0;
    sm[threadIdx.x] = v;
    __syncthreads();
    for (int off = 1; off < 256; off <<= 1) {
        int t = (threadIdx.x >= off) ? sm[threadIdx.x - off] : 0;
        __syncthreads();
        sm[threadIdx.x] += t;
        __syncthreads();
    }
    if (threadIdx.x < nb) partials[threadIdx.x] = sm[threadIdx.x] - v;  // exclusive
}

__global__ void k_scan_final(const int* __restrict__ deg, const int* __restrict__ partials,
                             int* __restrict__ row_start, int n) {
    __shared__ int sm[256];
    int i = blockIdx.x * 256 + threadIdx.x;
    int v = (i < n) ? deg[i] : 0;
    sm[threadIdx.x] = v;
    __syncthreads();
    for (int off = 1; off < 256; off <<= 1) {
        int t = (threadIdx.x >= off) ? sm[threadIdx.x - off] : 0;
        __syncthreads();
        sm[threadIdx.x] += t;
        __syncthreads();
    }
    if (i < n) row_start[i] = partials[blockIdx.x] + sm[threadIdx.x] - v;  // exclusive
    if (i == n - 1) row_start[n] = partials[blockIdx.x] + sm[threadIdx.x]; // total
}

__global__ void k_fill_slots(const int* __restrict__ dst, int* __restrict__ cursor,
                             int* __restrict__ eid) {
    int e = blockIdx.x * blockDim.x + threadIdx.x;
    if (e >= N_EDGES) return;
    int pos = atomicAdd(cursor + dst[e], 1);
    eid[pos] = e;
}

// ---------------- edge encoder: feats(38) -> relu(@w1+b1)(128) -> @w2+b2 (64) ----------
__global__ __launch_bounds__(256) void k_edge_encoder(
    const float* __restrict__ la, const float* __restrict__ tse,
    const int* __restrict__ bp, const int* __restrict__ tt,
    const float* __restrict__ cr, const float* __restrict__ tsp,
    const float* __restrict__ tg, const float* __restrict__ r7,
    const float* __restrict__ r30,
    const float* __restrict__ tx_emb, const float* __restrict__ bank_emb,
    const float* __restrict__ w1t /*[128][40]*/, const float* __restrict__ eb1,
    const float* __restrict__ w2 /*[128][64]*/, const float* __restrict__ eb2,
    float* __restrict__ ea) {
    int e = blockIdx.x * blockDim.x + threadIdx.x;
    if (e >= N_EDGES) return;
    float f[38];
    f[0] = la[e]; f[1] = cr[e]; f[2] = tsp[e]; f[3] = tg[e]; f[4] = r7[e]; f[5] = r30[e];
#pragma unroll
    for (int i = 0; i < 8; i++) f[6 + i] = tse[e * 8 + i];
    int txi = tt[e];
#pragma unroll
    for (int i = 0; i < 8; i++) f[14 + i] = tx_emb[txi * 8 + i];
    int bk0 = bp[e * 2 + 0], bk1 = bp[e * 2 + 1];
#pragma unroll
    for (int i = 0; i < 8; i++) f[22 + i] = bank_emb[bk0 * 8 + i];
#pragma unroll
    for (int i = 0; i < 8; i++) f[30 + i] = bank_emb[bk1 * 8 + i];

    float acc[64];
#pragma unroll
    for (int o = 0; o < 64; o++) acc[o] = eb2[o];
    for (int j = 0; j < 128; j++) {
        float h = eb1[j];
        const float* wr = w1t + j * 40;
#pragma unroll
        for (int k = 0; k < 38; k++) h = fmaf(f[k], wr[k], h);
        h = fmaxf(h, 0.f);
        const float* w2r = w2 + j * 64;
#pragma unroll
        for (int o = 0; o < 64; o++) acc[o] = fmaf(h, w2r[o], acc[o]);
    }
    float* er = ea + (long)e * 64;
#pragma unroll
    for (int o = 0; o < 64; o++) er[o] = acc[o];
}

// ---------------- generic node-level GEMM: out[n, j0:j0+JC] = act(b + in1@W[:K1] + (in2/deg)@W[K1:]) ---
template <int K1, int K2, int JC, bool RELU, bool DIV2>
__global__ __launch_bounds__(256) void k_node_gemm(
    const float* __restrict__ in1, int ld1,
    const float* __restrict__ in2, int ld2,
    const int* __restrict__ degi,
    const float* __restrict__ W, int ldw,
    const float* __restrict__ bias,
    float* __restrict__ out, int ldo, int nrows) {
    int n = blockIdx.x * blockDim.x + threadIdx.x;
    if (n >= nrows) return;
    int j0 = blockIdx.y * JC;
    float acc[JC];
#pragma unroll
    for (int j = 0; j < JC; j++) acc[j] = bias ? bias[j0 + j] : 0.f;
    const float* r1 = in1 + (long)n * ld1;
    for (int k = 0; k < K1; k++) {
        float v = r1[k];
        const float* wr = W + (long)k * ldw + j0;
#pragma unroll
        for (int j = 0; j < JC; j++) acc[j] = fmaf(v, wr[j], acc[j]);
    }
    if constexpr (K2 > 0) {
        float dinv = 1.f;
        if constexpr (DIV2) dinv = 1.f / ((float)degi[n] + 1e-6f);
        const float* r2 = in2 + (long)n * ld2;
        for (int k = 0; k < K2; k++) {
            float v = r2[k] * dinv;
            const float* wr = W + (long)(K1 + k) * ldw + j0;
#pragma unroll
            for (int j = 0; j < JC; j++) acc[j] = fmaf(v, wr[j], acc[j]);
        }
    }
    float* orow = out + (long)n * ldo + j0;
#pragma unroll
    for (int j = 0; j < JC; j++) {
        float v = acc[j];
        if (RELU) v = fmaxf(v, 0.f);
        orow[j] = v;
    }
}

// ---------------- fused msg GEMM + segmented sum over CSR-ordered edges ----------------
// Per block: 64 slots x 128 outputs, K=64.
//   msg_row(slot) = relu( P[src[eid[slot]]] + ea[eid[slot]] @ W + bias )
//   s[n][:] = sum over slots of node n (slots sorted by dst). Interior segments: plain
//   store; segments crossing block boundary: atomicAdd (s pre-zeroed).
__global__ __launch_bounds__(256) void k_msg_seg(
    const float* __restrict__ P, const float* __restrict__ ea,
    const float* __restrict__ W /*[64][128]*/, const float* __restrict__ bias,
    const int* __restrict__ src, const int* __restrict__ dst,
    const int* __restrict__ eid,
    float* __restrict__ s, int n_edges) {
    __shared__ float ea_s[64][64];
    __shared__ float W_s[64][128];   // reused as the msg tile after the k-loop
    __shared__ int sn_s[64];
    __shared__ int es_s[64];
    __shared__ int nid_s[64];
    __shared__ int bound_s[2];       // prev_n, next_n
    int tid = threadIdx.x;
    int t0 = blockIdx.x * 64;

    if (tid < 64) {
        int slot = t0 + tid;
        int e = (slot < n_edges) ? eid[slot] : 0;
        es_s[tid] = e;
        sn_s[tid] = src[e];
        nid_s[tid] = (slot < n_edges) ? dst[e] : -1;
    }
    if (tid == 64) bound_s[0] = (t0 > 0) ? dst[eid[t0 - 1]] : -1;
    if (tid == 65) bound_s[1] = (t0 + 64 < n_edges) ? dst[eid[t0 + 64]] : -1;
    // stage W: 64*128 floats = 2048 float4
#pragma unroll
    for (int i = 0; i < 8; i++) {
        int f = tid + 256 * i;
        ((float4*)W_s)[f] = ((const float4*)W)[f];
    }
    __syncthreads();
    // stage ea tile: 64 rows x 16 float4
#pragma unroll
    for (int i = 0; i < 4; i++) {
        int f = tid + 256 * i;
        int el = f >> 4, c = f & 15;
        float4 v = ((const float4*)(ea + (long)es_s[el] * 64))[c];
        *((float4*)&ea_s[el][c * 4]) = v;
    }
    __syncthreads();

    int jg = tid & 31;   // j0 = jg*4
    int eg = tid >> 5;   // rows eg*8 .. eg*8+7
    int j0 = jg * 4;
    float acc[8][4];
#pragma unroll
    for (int el = 0; el < 8; el++)
#pragma unroll
        for (int jj = 0; jj < 4; jj++) acc[el][jj] = 0.f;

    for (int k4 = 0; k4 < 16; k4++) {
        float4 wv[4];
#pragma unroll
        for (int kk = 0; kk < 4; kk++) wv[kk] = *(const float4*)&W_s[k4 * 4 + kk][j0];
#pragma unroll
        for (int el = 0; el < 8; el++) {
            float4 av = *(const float4*)&ea_s[eg * 8 + el][k4 * 4];
#pragma unroll
            for (int jj = 0; jj < 4; jj++) {
                float a = acc[el][jj];
                a = fmaf(av.x, ((const float*)&wv[0])[jj], a);
                a = fmaf(av.y, ((const float*)&wv[1])[jj], a);
                a = fmaf(av.z, ((const float*)&wv[2])[jj], a);
                a = fmaf(av.w, ((const float*)&wv[3])[jj], a);
                acc[el][jj] = a;
            }
        }
    }
    __syncthreads();   // everyone done reading W_s / ea_s

    // epilogue: msg = relu(acc + P[src] + bias) -> write into W_s as msg tile
    float4 bv = *(const float4*)(bias + j0);
#pragma unroll
    for (int el = 0; el < 8; el++) {
        int row = eg * 8 + el;
        float4 pv = *(const float4*)(P + (long)sn_s[row] * 128 + j0);
        float4 o;
        o.x = fmaxf(acc[el][0] + pv.x + bv.x, 0.f);
        o.y = fmaxf(acc[el][1] + pv.y + bv.y, 0.f);
        o.z = fmaxf(acc[el][2] + pv.z + bv.z, 0.f);
        o.w = fmaxf(acc[el][3] + pv.w + bv.w, 0.f);
        *((float4*)&W_s[row][j0]) = o;
    }
    __syncthreads();

    // segmented reduction: one thread per column walks the 64 rows in slot order.
    // Branches are wave-uniform (nid_s shared by all columns).
    if (tid < 128) {
        int c = tid;
        int rows = min(64, n_edges - t0);
        int prev_n = bound_s[0], next_n = bound_s[1];
        int cur = nid_s[0];
        int seg_start = 0;
        float run = 0.f;
        for (int r = 0; r < rows; r++) {
            int nd = nid_s[r];
            if (nd != cur) {
                if (seg_start == 0 && cur == prev_n) atomicAdd(s + (long)cur * 128 + c, run);
                else s[(long)cur * 128 + c] = run;
                cur = nd; seg_start = r; run = 0.f;
            }
            run += W_s[r][c];
        }
        if ((seg_start == 0 && cur == prev_n) || cur == next_n)
            atomicAdd(s + (long)cur * 128 + c, run);
        else s[(long)cur * 128 + c] = run;
    }
}

// ---------------- edge classifier (register-staged gathers) ----------------------------
__global__ __launch_bounds__(256) void k_edge_cls(
    const float* __restrict__ nS, const float* __restrict__ nD,
    const float* __restrict__ ea, const float* __restrict__ Ct /*[64][64]*/,
    const float* __restrict__ b1, const float* __restrict__ w2, const float* __restrict__ b2,
    const int* __restrict__ src, const int* __restrict__ dst,
    float* __restrict__ logits_out, float* __restrict__ probs) {
    int e = blockIdx.x * blockDim.x + threadIdx.x;
    if (e >= N_EDGES) return;
    int sn = src[e], dn = dst[e];
    // stage S+D rows once: each HBM line touched exactly once per thread
    float base[64];
    const float4* Sr4 = (const float4*)(nS + (long)sn * 64);
    const float4* Dr4 = (const float4*)(nD + (long)dn * 64);
#pragma unroll
    for (int i = 0; i < 16; i++) {
        float4 sv = Sr4[i];
        float4 dv = Dr4[i];
        base[4 * i + 0] = sv.x + dv.x;
        base[4 * i + 1] = sv.y + dv.y;
        base[4 * i + 2] = sv.z + dv.z;
        base[4 * i + 3] = sv.w + dv.w;
    }
    float a[64];
    const float4* ar = (const float4*)(ea + (long)e * 64);
#pragma unroll
    for (int i = 0; i < 16; i++) {
        float4 v = ar[i];
        a[4 * i] = v.x; a[4 * i + 1] = v.y; a[4 * i + 2] = v.z; a[4 * i + 3] = v.w;
    }
    float logit = b2[0];
    for (int j = 0; j < 64; j++) {
        float t = b1[j] + base[j];
        const float* wr = Ct + j * 64;   // wave-uniform -> scalar loads
#pragma unroll
        for (int k = 0; k < 64; k++) t = fmaf(a[k], wr[k], t);
        t = fmaxf(t, 0.f);
        logit = fmaf(t, w2[j], logit);
    }
    logits_out[e] = logit;
    probs[e] = 1.f / (1.f + expf(-logit));
}

// ---------------- ts max reduction -----------------------------------------------------
__global__ void k_tsmax(const int* __restrict__ ts, int* __restrict__ out) {
    int i = blockIdx.x * blockDim.x + threadIdx.x;
    int stride = gridDim.x * blockDim.x;
    int m = 0;
    for (int t = i; t < N_EDGES; t += stride) m = max(m, ts[t]);
#pragma unroll
    for (int off = 32; off > 0; off >>= 1) m = max(m, __shfl_down(m, off));
    if ((threadIdx.x & 63) == 0) atomicMax(out, m);
}

// ---------------- per-edge aggregation into node stats ---------------------------------
// stats layout: 0 cnt, 1 sum_p, 2 max_p, 3 sum_high, 4 sum_p*decay, 5 sum_decay,
//               6 sum_high30, 7 max_p30, 8 sum_p30, 9 sum_l30, 10 min_age
__global__ __launch_bounds__(256) void k_edge_agg(
    const float* __restrict__ probs, const int* __restrict__ uts,
    const int* __restrict__ src, const int* __restrict__ dst,
    const int* __restrict__ tsmax, float* __restrict__ stats) {
    int e = blockIdx.x * blockDim.x + threadIdx.x;
    if (e >= N_EDGES) return;
    float p = probs[e];
    float now = (float)(*tsmax);
    float ts = (float)uts[e];
    float age = fmaxf(now - ts, 0.f);
    float decay = expf(-age / 2592000.f);
    bool high = p >= 0.7f;
    bool l30 = age <= 2592000.f;
    float aged = age / 86400.f;
    float* cnt = stats;
    float* sump = stats + N_NODES;
    float* maxp = stats + 2 * N_NODES;
    float* sumh = stats + 3 * N_NODES;
    float* sumpd = stats + 4 * N_NODES;
    float* sumd = stats + 5 * N_NODES;
    float* sumh30 = stats + 6 * N_NODES;
    float* maxp30 = stats + 7 * N_NODES;
    float* sump30 = stats + 8 * N_NODES;
    float* suml30 = stats + 9 * N_NODES;
    float* minage = stats + 10 * N_NODES;
    int nn[2] = {src[e], dst[e]};
#pragma unroll
    for (int i = 0; i < 2; i++) {
        int n = nn[i];
        atomicAdd(cnt + n, 1.f);
        atomicAdd(sump + n, p);
        atomicMaxF(maxp + n, p);
        atomicAdd(sumpd + n, p * decay);
        atomicAdd(sumd + n, decay);
        if (high) atomicAdd(sumh + n, 1.f);
        if (l30) {
            atomicAdd(sump30 + n, p);
            atomicAdd(suml30 + n, 1.f);
            atomicMaxF(maxp30 + n, p);
            if (high) atomicAdd(sumh30 + n, 1.f);
        }
        if (high) atomicMinF(minage + n, aged);
    }
}

// ---------------- node classifier ------------------------------------------------------
__global__ __launch_bounds__(256) void k_node_cls(
    const float* __restrict__ ne, const float* __restrict__ stats,
    const float* __restrict__ w1t /*[64][72]*/, const float* __restrict__ b1,
    const float* __restrict__ gamma, const float* __restrict__ beta,
    const float* __restrict__ mean, const float* __restrict__ var,
    const float* __restrict__ w2, const float* __restrict__ b2,
    float* __restrict__ out) {
    int n = blockIdx.x * blockDim.x + threadIdx.x;
    if (n >= N_NODES) return;
    float in[72];
    const float4* nr = (const float4*)(ne + (long)n * 64);
#pragma unroll
    for (int i = 0; i < 16; i++) {
        float4 v = nr[i];
        in[4 * i] = v.x; in[4 * i + 1] = v.y; in[4 * i + 2] = v.z; in[4 * i + 3] = v.w;
    }
    float c = stats[n];
    in[64] = stats[N_NODES + n] / (c + 1e-6f);
    in[65] = stats[2 * N_NODES + n];
    in[66] = log1pf(stats[3 * N_NODES + n]);
    in[67] = stats[4 * N_NODES + n] / (stats[5 * N_NODES + n] + 1e-6f);
    in[68] = log1pf(stats[6 * N_NODES + n]);
    in[69] = stats[7 * N_NODES + n];
    in[70] = stats[8 * N_NODES + n] / (stats[9 * N_NODES + n] + 1e-6f);
    float ma = fminf(stats[10 * N_NODES + n], 9999.f);
    in[71] = log1pf(fminf(ma, 90.f)) / log1pf(90.f);
    float logit = b2[0];
    for (int j = 0; j < 64; j++) {
        float h = b1[j];
        const float* wr = w1t + j * 72;
#pragma unroll
        for (int k = 0; k < 72; k++) h = fmaf(in[k], wr[k], h);
        h = (h - mean[j]) * rsqrtf(var[j] + 1e-5f) * gamma[j] + beta[j];
        h = fmaxf(h, 0.f);
        logit = fmaf(h, w2[j], logit);
    }
    out[n] = logit;
}

extern "C" void kernel_launch(void* const* d_in, const int* in_sizes, int n_in,
                              void* d_out, int out_size, void* d_ws, size_t ws_size,
                              hipStream_t stream) {
    const float* x = (const float*)d_in[0];
    const int* eidx = (const int*)d_in[1];
    const int* src = eidx;
    const int* dst = eidx + N_EDGES;
    const float* la = (const float*)d_in[2];
    const float* tse = (const float*)d_in[3];
    const int* bp = (const int*)d_in[4];
    const int* tt = (const int*)d_in[5];
    const float* cr = (const float*)d_in[6];
    const float* tsp = (const float*)d_in[7];
    const float* tg = (const float*)d_in[8];
    const float* r7 = (const float*)d_in[9];
    const float* r30 = (const float*)d_in[10];
    const int* uts = (const int*)d_in[11];
    const float* tx_emb = (const float*)d_in[12];
    const float* bank_emb = (const float*)d_in[13];
    const float* ee_w1 = (const float*)d_in[14];
    const float* ee_b1 = (const float*)d_in[15];
    const float* ee_w2 = (const float*)d_in[16];
    const float* ee_b2 = (const float*)d_in[17];
    const float* msg1_w = (const float*)d_in[18];
    const float* msg1_b = (const float*)d_in[19];
    const float* upd1_w = (const float*)d_in[20];
    const float* upd1_b = (const float*)d_in[21];
    const float* msg2_w = (const float*)d_in[22];
    const float* msg2_b = (const float*)d_in[23];
    const float* upd2_w = (const float*)d_in[24];
    const float* upd2_b = (const float*)d_in[25];
    const float* ec_w1 = (const float*)d_in[26];
    const float* ec_b1 = (const float*)d_in[27];
    const float* ec_w2 = (const float*)d_in[28];
    const float* ec_b2 = (const float*)d_in[29];
    const float* nc_w1 = (const float*)d_in[30];
    const float* nc_b1 = (const float*)d_in[31];
    const float* bn_g = (const float*)d_in[32];
    const float* bn_b = (const float*)d_in[33];
    const float* bn_m = (const float*)d_in[34];
    const float* bn_v = (const float*)d_in[35];
    const float* nc_w2 = (const float*)d_in[36];
    const float* nc_b2 = (const float*)d_in[37];

    float* out_node = (float*)d_out;              // [N_NODES]
    float* out_edge = (float*)d_out + N_NODES;    // [N_EDGES]

    // workspace layout (floats) — total ~250 MB
    float* ws = (float*)d_ws;
    float* ea = ws;                         // E*64
    float* P = ea + (long)N_EDGES * 64;     // N*128
    float* s = P + (long)N_NODES * 128;     // N*128
    float* h1 = s + (long)N_NODES * 128;    // N*128
    float* ne = h1 + (long)N_NODES * 128;   // N*64
    float* nS = ne + (long)N_NODES * 64;    // N*64
    float* nD = nS + (long)N_NODES * 64;    // N*64
    float* probs = nD + (long)N_NODES * 64; // E
    float* stats = probs + N_EDGES;         // 11*N
    float* w1t = stats + 11 * N_NODES;      // 128*40
    float* Ct = w1t + 128 * 40;             // 64*64
    float* ncw1t = Ct + 64 * 64;            // 64*72
    int* tsmax = (int*)(ncw1t + 64 * 72);   // 1
    int* degi = tsmax + 1;                  // N
    int* row_start = degi + N_NODES;        // N+1
    int* cursor = row_start + N_NODES + 1;  // N
    int* eid = cursor + N_NODES;            // E
    int* partials = eid + N_EDGES;          // 256

    const int EB = (N_EDGES + 255) / 256;   // 1954
    const int NB = (N_NODES + 255) / 256;   // 196
    const int MB = (N_EDGES + 63) / 64;     // 7813

    // ---- init ----
    hipMemsetAsync(stats, 0, (size_t)10 * N_NODES * 4, stream);
    hipMemsetAsync(tsmax, 0, 4, stream);
    hipMemsetAsync(degi, 0, (size_t)N_NODES * 4, stream);
    hipMemsetAsync(s, 0, (size_t)N_NODES * 128 * 4, stream);
    k_fill<<<NB, 256, 0, stream>>>(stats + 10 * N_NODES, 9999.f, N_NODES);

    // ---- CSR build (by dst) ----
    k_deg_count<<<EB, 256, 0, stream>>>(dst, degi);
    k_block_sums<<<NB, 256, 0, stream>>>(degi, partials, N_NODES);
    k_scan_partials<<<1, 256, 0, stream>>>(partials, NB);
    k_scan_final<<<NB, 256, 0, stream>>>(degi, partials, row_start, N_NODES);
    hipMemcpyAsync(cursor, row_start, (size_t)N_NODES * 4, hipMemcpyDeviceToDevice, stream);
    k_fill_slots<<<EB, 256, 0, stream>>>(dst, cursor, eid);

    // ---- weight transposes ----
    k_transpose<<<(38 * 128 + 255) / 256, 256, 0, stream>>>(ee_w1, w1t, 38, 128, 128, 40);
    k_transpose<<<(64 * 64 + 255) / 256, 256, 0, stream>>>(ec_w1 + 128 * 64, Ct, 64, 64, 64, 64);
    k_transpose<<<(72 * 64 + 255) / 256, 256, 0, stream>>>(nc_w1, ncw1t, 72, 64, 64, 72);

    // ---- edge encoder ----
    k_edge_encoder<<<EB, 256, 0, stream>>>(la, tse, bp, tt, cr, tsp, tg, r7, r30,
                                           tx_emb, bank_emb, w1t, ee_b1, ee_w2, ee_b2, ea);

    // ---- SAGE layer 1 ----
    k_node_gemm<128, 0, 64, false, false><<<dim3(NB, 2), 256, 0, stream>>>(
        x, 128, nullptr, 0, nullptr, msg1_w, 128, nullptr, P, 128, N_NODES);
    k_msg_seg<<<MB, 256, 0, stream>>>(P, ea, msg1_w + 128 * 128, msg1_b, src, dst, eid, s, N_EDGES);
    k_node_gemm<128, 128, 64, true, true><<<dim3(NB, 2), 256, 0, stream>>>(
        x, 128, s, 128, degi, upd1_w, 128, upd1_b, h1, 128, N_NODES);

    // ---- SAGE layer 2 ----
    k_node_gemm<128, 0, 64, false, false><<<dim3(NB, 2), 256, 0, stream>>>(
        h1, 128, nullptr, 0, nullptr, msg2_w, 128, nullptr, P, 128, N_NODES);
    hipMemsetAsync(s, 0, (size_t)N_NODES * 128 * 4, stream);
    k_msg_seg<<<MB, 256, 0, stream>>>(P, ea, msg2_w + 128 * 128, msg2_b, src, dst, eid, s, N_EDGES);
    k_node_gemm<128, 128, 64, true, true><<<dim3(NB, 1), 256, 0, stream>>>(
        h1, 128, s, 128, degi, upd2_w, 64, upd2_b, ne, 64, N_NODES);

    // ---- edge classifier ----
    k_node_gemm<64, 0, 64, false, false><<<dim3(NB, 1), 256, 0, stream>>>(
        ne, 64, nullptr, 0, nullptr, ec_w1, 64, nullptr, nS, 64, N_NODES);
    k_node_gemm<64, 0, 64, false, false><<<dim3(NB, 1), 256, 0, stream>>>(
        ne, 64, nullptr, 0, nullptr, ec_w1 + 64 * 64, 64, nullptr, nD, 64, N_NODES);
    k_edge_cls<<<EB, 256, 0, stream>>>(nS, nD, ea, Ct, ec_b1, ec_w2, ec_b2,
                                       src, dst, out_edge, probs);

    // ---- edge aggregation ----
    k_tsmax<<<256, 256, 0, stream>>>(uts, tsmax);
    k_edge_agg<<<EB, 256, 0, stream>>>(probs, uts, src, dst, tsmax, stats);

    // ---- node classifier ----
    k_node_cls<<<NB, 256, 0, stream>>>(ne, stats, ncw1t, nc_b1, bn_g, bn_b, bn_m, bn_v,
                                       nc_w2, nc_b2, out_node);
}

// Round 6
// 1608.320 us; speedup vs baseline: 5.2496x; 1.0791x over previous
//
#include <hip/hip_runtime.h>
#include <math.h>

#define N_NODES 50000
#define N_EDGES 500000

// =================== CSR build helpers ====================
__global__ void k_deg_count(const int* __restrict__ keys, int* __restrict__ degi, int n) {
    int e = blockIdx.x * blockDim.x + threadIdx.x;
    if (e < n) atomicAdd(degi + keys[e], 1);
}

__global__ void k_block_sums(const int* __restrict__ deg, int* __restrict__ partials, int n) {
    __shared__ int sm[256];
    int i = blockIdx.x * 256 + threadIdx.x;
    sm[threadIdx.x] = (i < n) ? deg[i] : 0;
    __syncthreads();
    for (int s = 128; s > 0; s >>= 1) {
        if (threadIdx.x < s) sm[threadIdx.x] += sm[threadIdx.x + s];
        __syncthreads();
    }
    if (threadIdx.x == 0) partials[blockIdx.x] = sm[0];
}

// single block: in-place exclusive scan of partials[nb], nb<=256
__global__ void k_scan_partials(int* partials, int nb) {
    __shared__ int sm[256];
    int v = (threadIdx.x < nb) ? partials[threadIdx.x] : 0;
    sm[threadIdx.x] = v;
    __syncthreads();
    for (int off = 1; off < 256; off <<= 1) {
        int t = (threadIdx.x >= off) ? sm[threadIdx.x - off] : 0;
        __syncthreads();
        sm[threadIdx.x] += t;
        __syncthreads();
    }
    if (threadIdx.x < nb) partials[threadIdx.x] = sm[threadIdx.x] - v;  // exclusive
}

__global__ void k_scan_final(const int* __restrict__ deg, const int* __restrict__ partials,
                             int* __restrict__ row_start, int n) {
    __shared__ int sm[256];
    int i = blockIdx.x * 256 + threadIdx.x;
    int v = (i < n) ? deg[i] : 0;
    sm[threadIdx.x] = v;
    __syncthreads();
    for (int off = 1; off < 256; off <<= 1) {
        int t = (threadIdx.x >= off) ? sm[threadIdx.x - off] : 0;
        __syncthreads();
        sm[threadIdx.x] += t;
        __syncthreads();
    }
    if (i < n) row_start[i] = partials[blockIdx.x] + sm[threadIdx.x] - v;  // exclusive
    if (i == n - 1) row_start[n] = partials[blockIdx.x] + sm[threadIdx.x]; // total
}

__global__ void k_fill_slots(const int* __restrict__ dst, int* __restrict__ cursor,
                             int* __restrict__ eid) {
    int e = blockIdx.x * blockDim.x + threadIdx.x;
    if (e >= N_EDGES) return;
    int pos = atomicAdd(cursor + dst[e], 1);
    eid[pos] = e;
}

// incidence fill over 2E entries: entry i -> node eidx[i], edge (i % E)
__global__ void k_fill_slots2(const int* __restrict__ eidx, int* __restrict__ cursor,
                              int* __restrict__ eid2) {
    int i = blockIdx.x * blockDim.x + threadIdx.x;
    if (i >= 2 * N_EDGES) return;
    int pos = atomicAdd(cursor + eidx[i], 1);
    eid2[pos] = (i < N_EDGES) ? i : (i - N_EDGES);
}

// ---------------- edge encoder: feats(38) -> relu(@w1+b1)(128) -> @w2+b2 (64) ----------
__global__ __launch_bounds__(256) void k_edge_encoder(
    const float* __restrict__ la, const float* __restrict__ tse,
    const int* __restrict__ bp, const int* __restrict__ tt,
    const float* __restrict__ cr, const float* __restrict__ tsp,
    const float* __restrict__ tg, const float* __restrict__ r7,
    const float* __restrict__ r30,
    const float* __restrict__ tx_emb, const float* __restrict__ bank_emb,
    const float* __restrict__ w1t /*[128][40]*/, const float* __restrict__ eb1,
    const float* __restrict__ w2 /*[128][64]*/, const float* __restrict__ eb2,
    float* __restrict__ ea) {
    int e = blockIdx.x * blockDim.x + threadIdx.x;
    if (e >= N_EDGES) return;
    float f[38];
    f[0] = la[e]; f[1] = cr[e]; f[2] = tsp[e]; f[3] = tg[e]; f[4] = r7[e]; f[5] = r30[e];
#pragma unroll
    for (int i = 0; i < 8; i++) f[6 + i] = tse[e * 8 + i];
    int txi = tt[e];
#pragma unroll
    for (int i = 0; i < 8; i++) f[14 + i] = tx_emb[txi * 8 + i];
    int bk0 = bp[e * 2 + 0], bk1 = bp[e * 2 + 1];
#pragma unroll
    for (int i = 0; i < 8; i++) f[22 + i] = bank_emb[bk0 * 8 + i];
#pragma unroll
    for (int i = 0; i < 8; i++) f[30 + i] = bank_emb[bk1 * 8 + i];

    float acc[64];
#pragma unroll
    for (int o = 0; o < 64; o++) acc[o] = eb2[o];
    for (int j = 0; j < 128; j++) {
        float h = eb1[j];
        const float* wr = w1t + j * 40;
#pragma unroll
        for (int k = 0; k < 38; k++) h = fmaf(f[k], wr[k], h);
        h = fmaxf(h, 0.f);
        const float* w2r = w2 + j * 64;
#pragma unroll
        for (int o = 0; o < 64; o++) acc[o] = fmaf(h, w2r[o], acc[o]);
    }
    float* er = ea + (long)e * 64;
#pragma unroll
    for (int o = 0; o < 64; o++) er[o] = acc[o];
}

// ---------------- generic node-level GEMM: out[n, j0:j0+JC] = act(b + in1@W[:K1] + (in2/deg)@W[K1:]) ---
template <int K1, int K2, int JC, bool RELU, bool DIV2>
__global__ __launch_bounds__(256) void k_node_gemm(
    const float* __restrict__ in1, int ld1,
    const float* __restrict__ in2, int ld2,
    const int* __restrict__ degi,
    const float* __restrict__ W, int ldw,
    const float* __restrict__ bias,
    float* __restrict__ out, int ldo, int nrows) {
    int n = blockIdx.x * blockDim.x + threadIdx.x;
    if (n >= nrows) return;
    int j0 = blockIdx.y * JC;
    float acc[JC];
#pragma unroll
    for (int j = 0; j < JC; j++) acc[j] = bias ? bias[j0 + j] : 0.f;
    const float* r1 = in1 + (long)n * ld1;
    for (int k = 0; k < K1; k++) {
        float v = r1[k];
        const float* wr = W + (long)k * ldw + j0;
#pragma unroll
        for (int j = 0; j < JC; j++) acc[j] = fmaf(v, wr[j], acc[j]);
    }
    if constexpr (K2 > 0) {
        float dinv = 1.f;
        if constexpr (DIV2) dinv = 1.f / ((float)degi[n] + 1e-6f);
        const float* r2 = in2 + (long)n * ld2;
        for (int k = 0; k < K2; k++) {
            float v = r2[k] * dinv;
            const float* wr = W + (long)(K1 + k) * ldw + j0;
#pragma unroll
            for (int j = 0; j < JC; j++) acc[j] = fmaf(v, wr[j], acc[j]);
        }
    }
    float* orow = out + (long)n * ldo + j0;
#pragma unroll
    for (int j = 0; j < JC; j++) {
        float v = acc[j];
        if (RELU) v = fmaxf(v, 0.f);
        orow[j] = v;
    }
}

// ---------------- fused msg GEMM + segmented sum over CSR-ordered edges ----------------
__global__ __launch_bounds__(256) void k_msg_seg(
    const float* __restrict__ P, const float* __restrict__ ea,
    const float* __restrict__ W /*[64][128]*/, const float* __restrict__ bias,
    const int* __restrict__ src, const int* __restrict__ dst,
    const int* __restrict__ eid,
    float* __restrict__ s, int n_edges) {
    __shared__ float ea_s[64][64];
    __shared__ float W_s[64][128];   // reused as the msg tile after the k-loop
    __shared__ int sn_s[64];
    __shared__ int es_s[64];
    __shared__ int nid_s[64];
    __shared__ int bound_s[2];       // prev_n, next_n
    int tid = threadIdx.x;
    int t0 = blockIdx.x * 64;

    if (tid < 64) {
        int slot = t0 + tid;
        int e = (slot < n_edges) ? eid[slot] : 0;
        es_s[tid] = e;
        sn_s[tid] = src[e];
        nid_s[tid] = (slot < n_edges) ? dst[e] : -1;
    }
    if (tid == 64) bound_s[0] = (t0 > 0) ? dst[eid[t0 - 1]] : -1;
    if (tid == 65) bound_s[1] = (t0 + 64 < n_edges) ? dst[eid[t0 + 64]] : -1;
#pragma unroll
    for (int i = 0; i < 8; i++) {
        int f = tid + 256 * i;
        ((float4*)W_s)[f] = ((const float4*)W)[f];
    }
    __syncthreads();
#pragma unroll
    for (int i = 0; i < 4; i++) {
        int f = tid + 256 * i;
        int el = f >> 4, c = f & 15;
        float4 v = ((const float4*)(ea + (long)es_s[el] * 64))[c];
        *((float4*)&ea_s[el][c * 4]) = v;
    }
    __syncthreads();

    int jg = tid & 31;   // j0 = jg*4
    int eg = tid >> 5;   // rows eg*8 .. eg*8+7
    int j0 = jg * 4;
    float acc[8][4];
#pragma unroll
    for (int el = 0; el < 8; el++)
#pragma unroll
        for (int jj = 0; jj < 4; jj++) acc[el][jj] = 0.f;

    for (int k4 = 0; k4 < 16; k4++) {
        float4 wv[4];
#pragma unroll
        for (int kk = 0; kk < 4; kk++) wv[kk] = *(const float4*)&W_s[k4 * 4 + kk][j0];
#pragma unroll
        for (int el = 0; el < 8; el++) {
            float4 av = *(const float4*)&ea_s[eg * 8 + el][k4 * 4];
#pragma unroll
            for (int jj = 0; jj < 4; jj++) {
                float a = acc[el][jj];
                a = fmaf(av.x, ((const float*)&wv[0])[jj], a);
                a = fmaf(av.y, ((const float*)&wv[1])[jj], a);
                a = fmaf(av.z, ((const float*)&wv[2])[jj], a);
                a = fmaf(av.w, ((const float*)&wv[3])[jj], a);
                acc[el][jj] = a;
            }
        }
    }
    __syncthreads();   // everyone done reading W_s / ea_s

    float4 bv = *(const float4*)(bias + j0);
#pragma unroll
    for (int el = 0; el < 8; el++) {
        int row = eg * 8 + el;
        float4 pv = *(const float4*)(P + (long)sn_s[row] * 128 + j0);
        float4 o;
        o.x = fmaxf(acc[el][0] + pv.x + bv.x, 0.f);
        o.y = fmaxf(acc[el][1] + pv.y + bv.y, 0.f);
        o.z = fmaxf(acc[el][2] + pv.z + bv.z, 0.f);
        o.w = fmaxf(acc[el][3] + pv.w + bv.w, 0.f);
        *((float4*)&W_s[row][j0]) = o;
    }
    __syncthreads();

    if (tid < 128) {
        int c = tid;
        int rows = min(64, n_edges - t0);
        int prev_n = bound_s[0], next_n = bound_s[1];
        int cur = nid_s[0];
        int seg_start = 0;
        float run = 0.f;
        for (int r = 0; r < rows; r++) {
            int nd = nid_s[r];
            if (nd != cur) {
                if (seg_start == 0 && cur == prev_n) atomicAdd(s + (long)cur * 128 + c, run);
                else s[(long)cur * 128 + c] = run;
                cur = nd; seg_start = r; run = 0.f;
            }
            run += W_s[r][c];
        }
        if ((seg_start == 0 && cur == prev_n) || cur == next_n)
            atomicAdd(s + (long)cur * 128 + c, run);
        else s[(long)cur * 128 + c] = run;
    }
}

// ---------------- edge classifier (register-staged gathers) + einfo pack ---------------
__global__ __launch_bounds__(256) void k_edge_cls(
    const float* __restrict__ nS, const float* __restrict__ nD,
    const float* __restrict__ ea, const float* __restrict__ Ct /*[64][64]*/,
    const float* __restrict__ b1, const float* __restrict__ w2, const float* __restrict__ b2,
    const int* __restrict__ src, const int* __restrict__ dst,
    const int* __restrict__ uts, const int* __restrict__ tsmax,
    float* __restrict__ logits_out, float4* __restrict__ einfo) {
    int e = blockIdx.x * blockDim.x + threadIdx.x;
    if (e >= N_EDGES) return;
    int sn = src[e], dn = dst[e];
    float base[64];
    const float4* Sr4 = (const float4*)(nS + (long)sn * 64);
    const float4* Dr4 = (const float4*)(nD + (long)dn * 64);
#pragma unroll
    for (int i = 0; i < 16; i++) {
        float4 sv = Sr4[i];
        float4 dv = Dr4[i];
        base[4 * i + 0] = sv.x + dv.x;
        base[4 * i + 1] = sv.y + dv.y;
        base[4 * i + 2] = sv.z + dv.z;
        base[4 * i + 3] = sv.w + dv.w;
    }
    float a[64];
    const float4* ar = (const float4*)(ea + (long)e * 64);
#pragma unroll
    for (int i = 0; i < 16; i++) {
        float4 v = ar[i];
        a[4 * i] = v.x; a[4 * i + 1] = v.y; a[4 * i + 2] = v.z; a[4 * i + 3] = v.w;
    }
    float logit = b2[0];
    for (int j = 0; j < 64; j++) {
        float t = b1[j] + base[j];
        const float* wr = Ct + j * 64;   // wave-uniform -> scalar loads
#pragma unroll
        for (int k = 0; k < 64; k++) t = fmaf(a[k], wr[k], t);
        t = fmaxf(t, 0.f);
        logit = fmaf(t, w2[j], logit);
    }
    logits_out[e] = logit;
    float p = 1.f / (1.f + expf(-logit));
    float now = (float)(*tsmax);
    float age = fmaxf(now - (float)uts[e], 0.f);
    float decay = expf(-age / 2592000.f);
    einfo[e] = make_float4(p, decay, age, 0.f);
}

// ---------------- ts max reduction -----------------------------------------------------
__global__ void k_tsmax(const int* __restrict__ ts, int* __restrict__ out) {
    int i = blockIdx.x * blockDim.x + threadIdx.x;
    int stride = gridDim.x * blockDim.x;
    int m = 0;
    for (int t = i; t < N_EDGES; t += stride) m = max(m, ts[t]);
#pragma unroll
    for (int off = 32; off > 0; off >>= 1) m = max(m, __shfl_down(m, off));
    if ((threadIdx.x & 63) == 0) atomicMax(out, m);
}

// ---------------- per-node aggregation over incidence CSR (no atomics) -----------------
// feat8[n][0..7] = {mean_prob, max_prob, count_high, decay_weighted,
//                   susp_cnt_30d, max_risk_30d, avg_risk_30d, t_since_susp}
__global__ __launch_bounds__(256) void k_node_agg(
    const float4* __restrict__ einfo, const int* __restrict__ row2,
    const int* __restrict__ eid2, float* __restrict__ feat8) {
    int n = blockIdx.x * blockDim.x + threadIdx.x;
    if (n >= N_NODES) return;
    int e0 = row2[n], e1 = row2[n + 1];
    float cnt = (float)(e1 - e0);
    float sump = 0.f, maxp = 0.f, sumh = 0.f, sumpd = 0.f, sumd = 0.f;
    float sumh30 = 0.f, maxp30 = 0.f, sump30 = 0.f, suml30 = 0.f, minage = 9999.f;
    for (int idx = e0; idx < e1; idx++) {
        float4 v = einfo[eid2[idx]];
        float p = v.x, decay = v.y, age = v.z;
        float aged = age / 86400.f;
        bool high = p >= 0.7f;
        bool l30 = age <= 2592000.f;
        sump += p;
        maxp = fmaxf(maxp, p);
        sumpd += p * decay;
        sumd += decay;
        if (high) {
            sumh += 1.f;
            minage = fminf(minage, aged);
        }
        if (l30) {
            sump30 += p;
            suml30 += 1.f;
            maxp30 = fmaxf(maxp30, p);
            if (high) sumh30 += 1.f;
        }
    }
    float* f = feat8 + (long)n * 8;
    f[0] = sump / (cnt + 1e-6f);
    f[1] = maxp;
    f[2] = log1pf(sumh);
    f[3] = sumpd / (sumd + 1e-6f);
    f[4] = log1pf(sumh30);
    f[5] = maxp30;
    f[6] = sump30 / (suml30 + 1e-6f);
    f[7] = log1pf(fminf(fminf(minage, 9999.f), 90.f)) / log1pf(90.f);
}

// ---------------- node classifier ------------------------------------------------------
__global__ __launch_bounds__(256) void k_node_cls(
    const float* __restrict__ ne, const float* __restrict__ feat8,
    const float* __restrict__ w1t /*[64][72]*/, const float* __restrict__ b1,
    const float* __restrict__ gamma, const float* __restrict__ beta,
    const float* __restrict__ mean, const float* __restrict__ var,
    const float* __restrict__ w2, const float* __restrict__ b2,
    float* __restrict__ out) {
    int n = blockIdx.x * blockDim.x + threadIdx.x;
    if (n >= N_NODES) return;
    float in[72];
    const float4* nr = (const float4*)(ne + (long)n * 64);
#pragma unroll
    for (int i = 0; i < 16; i++) {
        float4 v = nr[i];
        in[4 * i] = v.x; in[4 * i + 1] = v.y; in[4 * i + 2] = v.z; in[4 * i + 3] = v.w;
    }
    const float4* fr = (const float4*)(feat8 + (long)n * 8);
    float4 f0 = fr[0], f1 = fr[1];
    in[64] = f0.x; in[65] = f0.y; in[66] = f0.z; in[67] = f0.w;
    in[68] = f1.x; in[69] = f1.y; in[70] = f1.z; in[71] = f1.w;
    float logit = b2[0];
    for (int j = 0; j < 64; j++) {
        float h = b1[j];
        const float* wr = w1t + j * 72;
#pragma unroll
        for (int k = 0; k < 72; k++) h = fmaf(in[k], wr[k], h);
        h = (h - mean[j]) * rsqrtf(var[j] + 1e-5f) * gamma[j] + beta[j];
        h = fmaxf(h, 0.f);
        logit = fmaf(h, w2[j], logit);
    }
    out[n] = logit;
}

// weight transpose: dst[j*kpad + k] = src[k*ldw + j]
__global__ void k_transpose(const float* __restrict__ src, float* __restrict__ dst,
                            int K, int J, int ldw, int kpad) {
    int i = blockIdx.x * blockDim.x + threadIdx.x;
    if (i >= K * J) return;
    int k = i / J, j = i - k * J;
    dst[j * kpad + k] = src[k * ldw + j];
}

extern "C" void kernel_launch(void* const* d_in, const int* in_sizes, int n_in,
                              void* d_out, int out_size, void* d_ws, size_t ws_size,
                              hipStream_t stream) {
    const float* x = (const float*)d_in[0];
    const int* eidx = (const int*)d_in[1];
    const int* src = eidx;
    const int* dst = eidx + N_EDGES;
    const float* la = (const float*)d_in[2];
    const float* tse = (const float*)d_in[3];
    const int* bp = (const int*)d_in[4];
    const int* tt = (const int*)d_in[5];
    const float* cr = (const float*)d_in[6];
    const float* tsp = (const float*)d_in[7];
    const float* tg = (const float*)d_in[8];
    const float* r7 = (const float*)d_in[9];
    const float* r30 = (const float*)d_in[10];
    const int* uts = (const int*)d_in[11];
    const float* tx_emb = (const float*)d_in[12];
    const float* bank_emb = (const float*)d_in[13];
    const float* ee_w1 = (const float*)d_in[14];
    const float* ee_b1 = (const float*)d_in[15];
    const float* ee_w2 = (const float*)d_in[16];
    const float* ee_b2 = (const float*)d_in[17];
    const float* msg1_w = (const float*)d_in[18];
    const float* msg1_b = (const float*)d_in[19];
    const float* upd1_w = (const float*)d_in[20];
    const float* upd1_b = (const float*)d_in[21];
    const float* msg2_w = (const float*)d_in[22];
    const float* msg2_b = (const float*)d_in[23];
    const float* upd2_w = (const float*)d_in[24];
    const float* upd2_b = (const float*)d_in[25];
    const float* ec_w1 = (const float*)d_in[26];
    const float* ec_b1 = (const float*)d_in[27];
    const float* ec_w2 = (const float*)d_in[28];
    const float* ec_b2 = (const float*)d_in[29];
    const float* nc_w1 = (const float*)d_in[30];
    const float* nc_b1 = (const float*)d_in[31];
    const float* bn_g = (const float*)d_in[32];
    const float* bn_b = (const float*)d_in[33];
    const float* bn_m = (const float*)d_in[34];
    const float* bn_v = (const float*)d_in[35];
    const float* nc_w2 = (const float*)d_in[36];
    const float* nc_b2 = (const float*)d_in[37];

    float* out_node = (float*)d_out;              // [N_NODES]
    float* out_edge = (float*)d_out + N_NODES;    // [N_EDGES]

    // workspace layout (floats) — total ~249 MB (round-4 proven footprint; einfo aliases
    // dead P, eid2 aliases dead s)
    float* ws = (float*)d_ws;
    float* ea = ws;                         // E*64
    float* P = ea + (long)N_EDGES * 64;     // N*128 (dead after 2nd msg_seg -> einfo)
    float* s = P + (long)N_NODES * 128;     // N*128 (dead after upd2 gemm -> eid2)
    float* h1 = s + (long)N_NODES * 128;    // N*128
    float* ne = h1 + (long)N_NODES * 128;   // N*64
    float* nS = ne + (long)N_NODES * 64;    // N*64
    float* nD = nS + (long)N_NODES * 64;    // N*64
    float* feat8 = nD + (long)N_NODES * 64; // N*8
    float* w1t = feat8 + (long)N_NODES * 8; // 128*40
    float* Ct = w1t + 128 * 40;             // 64*64
    float* ncw1t = Ct + 64 * 64;            // 64*72
    int* tsmax = (int*)(ncw1t + 64 * 72);   // 1
    int* degi = tsmax + 1;                  // N   (CSR1 by dst)
    int* row_start = degi + N_NODES;        // N+1
    int* cursor = row_start + N_NODES + 1;  // N
    int* eid = cursor + N_NODES;            // E
    int* partials = eid + N_EDGES;          // 256
    int* deg2 = partials + 256;             // N   (CSR2 incidence)
    int* row2 = deg2 + N_NODES;             // N+1
    int* cursor2 = row2 + N_NODES + 1;      // N
    // aliased regions:
    float4* einfo = (float4*)P;             // E float4 (8 MB < P's 25.6 MB)
    int* eid2 = (int*)s;                    // 2E ints (4 MB < s's 25.6 MB)

    const int EB = (N_EDGES + 255) / 256;    // 1954
    const int E2B = (2 * N_EDGES + 255) / 256;
    const int NB = (N_NODES + 255) / 256;    // 196
    const int MB = (N_EDGES + 63) / 64;      // 7813

    // ---- init ----
    hipMemsetAsync(tsmax, 0, 4, stream);
    hipMemsetAsync(degi, 0, (size_t)N_NODES * 4, stream);
    hipMemsetAsync(s, 0, (size_t)N_NODES * 128 * 4, stream);

    // ---- CSR1 build (by dst) ----
    k_deg_count<<<EB, 256, 0, stream>>>(dst, degi, N_EDGES);
    k_block_sums<<<NB, 256, 0, stream>>>(degi, partials, N_NODES);
    k_scan_partials<<<1, 256, 0, stream>>>(partials, NB);
    k_scan_final<<<NB, 256, 0, stream>>>(degi, partials, row_start, N_NODES);
    hipMemcpyAsync(cursor, row_start, (size_t)N_NODES * 4, hipMemcpyDeviceToDevice, stream);
    k_fill_slots<<<EB, 256, 0, stream>>>(dst, cursor, eid);

    // ---- weight transposes ----
    k_transpose<<<(38 * 128 + 255) / 256, 256, 0, stream>>>(ee_w1, w1t, 38, 128, 128, 40);
    k_transpose<<<(64 * 64 + 255) / 256, 256, 0, stream>>>(ec_w1 + 128 * 64, Ct, 64, 64, 64, 64);
    k_transpose<<<(72 * 64 + 255) / 256, 256, 0, stream>>>(nc_w1, ncw1t, 72, 64, 64, 72);

    // ---- edge encoder ----
    k_edge_encoder<<<EB, 256, 0, stream>>>(la, tse, bp, tt, cr, tsp, tg, r7, r30,
                                           tx_emb, bank_emb, w1t, ee_b1, ee_w2, ee_b2, ea);

    // ---- SAGE layer 1 ----
    k_node_gemm<128, 0, 64, false, false><<<dim3(NB, 2), 256, 0, stream>>>(
        x, 128, nullptr, 0, nullptr, msg1_w, 128, nullptr, P, 128, N_NODES);
    k_msg_seg<<<MB, 256, 0, stream>>>(P, ea, msg1_w + 128 * 128, msg1_b, src, dst, eid, s, N_EDGES);
    k_node_gemm<128, 128, 64, true, true><<<dim3(NB, 2), 256, 0, stream>>>(
        x, 128, s, 128, degi, upd1_w, 128, upd1_b, h1, 128, N_NODES);

    // ---- SAGE layer 2 ----
    k_node_gemm<128, 0, 64, false, false><<<dim3(NB, 2), 256, 0, stream>>>(
        h1, 128, nullptr, 0, nullptr, msg2_w, 128, nullptr, P, 128, N_NODES);
    hipMemsetAsync(s, 0, (size_t)N_NODES * 128 * 4, stream);
    k_msg_seg<<<MB, 256, 0, stream>>>(P, ea, msg2_w + 128 * 128, msg2_b, src, dst, eid, s, N_EDGES);
    k_node_gemm<128, 128, 64, true, true><<<dim3(NB, 1), 256, 0, stream>>>(
        h1, 128, s, 128, degi, upd2_w, 64, upd2_b, ne, 64, N_NODES);
    // s and P are now dead -> eid2 / einfo aliases safe from here on

    // ---- edge classifier prep ----
    k_node_gemm<64, 0, 64, false, false><<<dim3(NB, 1), 256, 0, stream>>>(
        ne, 64, nullptr, 0, nullptr, ec_w1, 64, nullptr, nS, 64, N_NODES);
    k_node_gemm<64, 0, 64, false, false><<<dim3(NB, 1), 256, 0, stream>>>(
        ne, 64, nullptr, 0, nullptr, ec_w1 + 64 * 64, 64, nullptr, nD, 64, N_NODES);

    // ---- CSR2 build (incidence over both endpoints; keys = flat eidx) ----
    hipMemsetAsync(deg2, 0, (size_t)N_NODES * 4, stream);
    k_deg_count<<<E2B, 256, 0, stream>>>(eidx, deg2, 2 * N_EDGES);
    k_block_sums<<<NB, 256, 0, stream>>>(deg2, partials, N_NODES);
    k_scan_partials<<<1, 256, 0, stream>>>(partials, NB);
    k_scan_final<<<NB, 256, 0, stream>>>(deg2, partials, row2, N_NODES);
    hipMemcpyAsync(cursor2, row2, (size_t)N_NODES * 4, hipMemcpyDeviceToDevice, stream);
    k_fill_slots2<<<E2B, 256, 0, stream>>>(eidx, cursor2, eid2);

    // ---- edge classifier (+ einfo pack) ----
    k_tsmax<<<256, 256, 0, stream>>>(uts, tsmax);
    k_edge_cls<<<EB, 256, 0, stream>>>(nS, nD, ea, Ct, ec_b1, ec_w2, ec_b2,
                                       src, dst, uts, tsmax, out_edge, einfo);

    // ---- node aggregation (gather, no atomics) ----
    k_node_agg<<<NB, 256, 0, stream>>>(einfo, row2, eid2, feat8);

    // ---- node classifier ----
    k_node_cls<<<NB, 256, 0, stream>>>(ne, feat8, ncw1t, nc_b1, bn_g, bn_b, bn_m, bn_v,
                                       nc_w2, nc_b2, out_node);
}

// Round 7
// 1529.952 us; speedup vs baseline: 5.5185x; 1.0512x over previous
//
#include <hip/hip_runtime.h>
#include <math.h>

#define N_NODES 50000
#define N_EDGES 500000

// =================== CSR build helpers ====================
__global__ void k_deg_count(const int* __restrict__ keys, int* __restrict__ degi, int n) {
    int e = blockIdx.x * blockDim.x + threadIdx.x;
    if (e < n) atomicAdd(degi + keys[e], 1);
}

__global__ void k_block_sums(const int* __restrict__ deg, int* __restrict__ partials, int n) {
    __shared__ int sm[256];
    int i = blockIdx.x * 256 + threadIdx.x;
    sm[threadIdx.x] = (i < n) ? deg[i] : 0;
    __syncthreads();
    for (int s = 128; s > 0; s >>= 1) {
        if (threadIdx.x < s) sm[threadIdx.x] += sm[threadIdx.x + s];
        __syncthreads();
    }
    if (threadIdx.x == 0) partials[blockIdx.x] = sm[0];
}

// single block: in-place exclusive scan of partials[nb], nb<=256
__global__ void k_scan_partials(int* partials, int nb) {
    __shared__ int sm[256];
    int v = (threadIdx.x < nb) ? partials[threadIdx.x] : 0;
    sm[threadIdx.x] = v;
    __syncthreads();
    for (int off = 1; off < 256; off <<= 1) {
        int t = (threadIdx.x >= off) ? sm[threadIdx.x - off] : 0;
        __syncthreads();
        sm[threadIdx.x] += t;
        __syncthreads();
    }
    if (threadIdx.x < nb) partials[threadIdx.x] = sm[threadIdx.x] - v;  // exclusive
}

__global__ void k_scan_final(const int* __restrict__ deg, const int* __restrict__ partials,
                             int* __restrict__ row_start, int n) {
    __shared__ int sm[256];
    int i = blockIdx.x * 256 + threadIdx.x;
    int v = (i < n) ? deg[i] : 0;
    sm[threadIdx.x] = v;
    __syncthreads();
    for (int off = 1; off < 256; off <<= 1) {
        int t = (threadIdx.x >= off) ? sm[threadIdx.x - off] : 0;
        __syncthreads();
        sm[threadIdx.x] += t;
        __syncthreads();
    }
    if (i < n) row_start[i] = partials[blockIdx.x] + sm[threadIdx.x] - v;  // exclusive
    if (i == n - 1) row_start[n] = partials[blockIdx.x] + sm[threadIdx.x]; // total
}

__global__ void k_fill_slots(const int* __restrict__ dst, int* __restrict__ cursor,
                             int* __restrict__ eid) {
    int e = blockIdx.x * blockDim.x + threadIdx.x;
    if (e >= N_EDGES) return;
    int pos = atomicAdd(cursor + dst[e], 1);
    eid[pos] = e;
}

// incidence fill over 2E entries: entry i -> node eidx[i], edge (i % E)
__global__ void k_fill_slots2(const int* __restrict__ eidx, int* __restrict__ cursor,
                              int* __restrict__ eid2) {
    int i = blockIdx.x * blockDim.x + threadIdx.x;
    if (i >= 2 * N_EDGES) return;
    int pos = atomicAdd(cursor + eidx[i], 1);
    eid2[pos] = (i < N_EDGES) ? i : (i - N_EDGES);
}

// ---------------- edge encoder, LDS-tiled: 64 edges/block, two GEMM phases -------------
// F_s[64][40] feats (K padded 38->40 with zeros), W_s = w1 [40][128] (rows 38,39 zero),
// H_s[64][132] = relu(F @ w1 + b1), out tile = H @ w2 + b2 -> ea.
__global__ __launch_bounds__(256) void k_edge_enc_tiled(
    const float* __restrict__ la, const float* __restrict__ tse,
    const int* __restrict__ bp, const int* __restrict__ tt,
    const float* __restrict__ cr, const float* __restrict__ tsp,
    const float* __restrict__ tg, const float* __restrict__ r7,
    const float* __restrict__ r30,
    const float* __restrict__ tx_emb, const float* __restrict__ bank_emb,
    const float* __restrict__ w1 /*[38][128]*/, const float* __restrict__ eb1,
    const float* __restrict__ w2 /*[128][64]*/, const float* __restrict__ eb2,
    float* __restrict__ ea, int n_edges) {
    __shared__ float F_s[64][40];    // 10.2 KB
    __shared__ float W_s[40][128];   // 20.5 KB
    __shared__ float H_s[64][132];   // 33.8 KB   (pad 132 kills stride-128 bank alias)
    int tid = threadIdx.x;
    int t0 = blockIdx.x * 64;

    // ---- stage w1 (+2 zero rows): 40*128 floats = 1280 float4 ----
#pragma unroll
    for (int i = 0; i < 5; i++) {
        int f = tid + 256 * i;          // float4 index
        int row = f >> 5;               // 32 float4 per row
        float4 v = make_float4(0.f, 0.f, 0.f, 0.f);
        if (row < 38) v = ((const float4*)w1)[f];
        ((float4*)W_s)[f] = v;
    }
    // ---- build feats tile: thread (el = tid&63, g = tid>>6) ----
    {
        int el = tid & 63, g = tid >> 6;
        int e = t0 + el;
        bool ok = e < n_edges;
        float* Fr = F_s[el];
        if (g == 0) {
            Fr[0] = ok ? la[e] : 0.f;
            Fr[1] = ok ? cr[e] : 0.f;
            Fr[2] = ok ? tsp[e] : 0.f;
            Fr[3] = ok ? tg[e] : 0.f;
            Fr[4] = ok ? r7[e] : 0.f;
            Fr[5] = ok ? r30[e] : 0.f;
            Fr[38] = 0.f; Fr[39] = 0.f;
        } else if (g == 1) {
            float4 a = make_float4(0, 0, 0, 0), b = a;
            if (ok) { a = ((const float4*)(tse + (long)e * 8))[0];
                      b = ((const float4*)(tse + (long)e * 8))[1]; }
            *((float4*)&Fr[6]) = a;
            // Fr[10..13]
            Fr[10] = b.x; Fr[11] = b.y; Fr[12] = b.z; Fr[13] = b.w;
        } else if (g == 2) {
            float4 a = make_float4(0, 0, 0, 0), b = a;
            if (ok) { int txi = tt[e];
                      a = ((const float4*)(tx_emb + (long)txi * 8))[0];
                      b = ((const float4*)(tx_emb + (long)txi * 8))[1]; }
            Fr[14] = a.x; Fr[15] = a.y; Fr[16] = a.z; Fr[17] = a.w;
            Fr[18] = b.x; Fr[19] = b.y; Fr[20] = b.z; Fr[21] = b.w;
        } else {
            float4 a = make_float4(0, 0, 0, 0), b = a, c = a, d = a;
            if (ok) {
                int bk0 = bp[e * 2 + 0], bk1 = bp[e * 2 + 1];
                a = ((const float4*)(bank_emb + (long)bk0 * 8))[0];
                b = ((const float4*)(bank_emb + (long)bk0 * 8))[1];
                c = ((const float4*)(bank_emb + (long)bk1 * 8))[0];
                d = ((const float4*)(bank_emb + (long)bk1 * 8))[1];
            }
            Fr[22] = a.x; Fr[23] = a.y; Fr[24] = a.z; Fr[25] = a.w;
            Fr[26] = b.x; Fr[27] = b.y; Fr[28] = b.z; Fr[29] = b.w;
            Fr[30] = c.x; Fr[31] = c.y; Fr[32] = c.z; Fr[33] = c.w;
            Fr[34] = d.x; Fr[35] = d.y; Fr[36] = d.z; Fr[37] = d.w;
        }
    }
    __syncthreads();

    // ---- GEMM1: h[64][128] = relu(F @ w1 + b1), tile 8 edges x 4 outs / thread ----
    {
        int jg = tid & 31, eg = tid >> 5;
        int j0 = jg * 4;
        float acc[8][4];
#pragma unroll
        for (int el = 0; el < 8; el++)
#pragma unroll
            for (int jj = 0; jj < 4; jj++) acc[el][jj] = 0.f;
        for (int k4 = 0; k4 < 10; k4++) {
            float4 wv[4];
#pragma unroll
            for (int kk = 0; kk < 4; kk++) wv[kk] = *(const float4*)&W_s[k4 * 4 + kk][j0];
#pragma unroll
            for (int el = 0; el < 8; el++) {
                float4 av = *(const float4*)&F_s[eg * 8 + el][k4 * 4];
#pragma unroll
                for (int jj = 0; jj < 4; jj++) {
                    float a = acc[el][jj];
                    a = fmaf(av.x, ((const float*)&wv[0])[jj], a);
                    a = fmaf(av.y, ((const float*)&wv[1])[jj], a);
                    a = fmaf(av.z, ((const float*)&wv[2])[jj], a);
                    a = fmaf(av.w, ((const float*)&wv[3])[jj], a);
                    acc[el][jj] = a;
                }
            }
        }
        float4 bv = *(const float4*)(eb1 + j0);
#pragma unroll
        for (int el = 0; el < 8; el++) {
            int row = eg * 8 + el;
            float4 o;
            o.x = fmaxf(acc[el][0] + bv.x, 0.f);
            o.y = fmaxf(acc[el][1] + bv.y, 0.f);
            o.z = fmaxf(acc[el][2] + bv.z, 0.f);
            o.w = fmaxf(acc[el][3] + bv.w, 0.f);
            *((float4*)&H_s[row][j0]) = o;
        }
    }
    __syncthreads();

    // ---- GEMM2: out[64][64] = H @ w2 + b2, tile 4 edges x 4 outs / thread ----
    {
        int jg = tid & 15, eg = tid >> 4;
        int j0 = jg * 4;
        float acc[4][4];
#pragma unroll
        for (int el = 0; el < 4; el++)
#pragma unroll
            for (int jj = 0; jj < 4; jj++) acc[el][jj] = 0.f;
        for (int k4 = 0; k4 < 32; k4++) {
            float4 wv[4];
#pragma unroll
            for (int kk = 0; kk < 4; kk++)
                wv[kk] = *(const float4*)(w2 + (long)(k4 * 4 + kk) * 64 + j0);
#pragma unroll
            for (int el = 0; el < 4; el++) {
                float4 av = *(const float4*)&H_s[eg * 4 + el][k4 * 4];
#pragma unroll
                for (int jj = 0; jj < 4; jj++) {
                    float a = acc[el][jj];
                    a = fmaf(av.x, ((const float*)&wv[0])[jj], a);
                    a = fmaf(av.y, ((const float*)&wv[1])[jj], a);
                    a = fmaf(av.z, ((const float*)&wv[2])[jj], a);
                    a = fmaf(av.w, ((const float*)&wv[3])[jj], a);
                    acc[el][jj] = a;
                }
            }
        }
        float4 bv = *(const float4*)(eb2 + j0);
#pragma unroll
        for (int el = 0; el < 4; el++) {
            int e = t0 + eg * 4 + el;
            if (e >= n_edges) continue;
            float4 o;
            o.x = acc[el][0] + bv.x;
            o.y = acc[el][1] + bv.y;
            o.z = acc[el][2] + bv.z;
            o.w = acc[el][3] + bv.w;
            *((float4*)(ea + (long)e * 64 + j0)) = o;
        }
    }
}

// ---------------- generic node-level GEMM: out[n, j0:j0+JC] = act(b + in1@W[:K1] + (in2/deg)@W[K1:]) ---
template <int K1, int K2, int JC, bool RELU, bool DIV2>
__global__ __launch_bounds__(256) void k_node_gemm(
    const float* __restrict__ in1, int ld1,
    const float* __restrict__ in2, int ld2,
    const int* __restrict__ degi,
    const float* __restrict__ W, int ldw,
    const float* __restrict__ bias,
    float* __restrict__ out, int ldo, int nrows) {
    int n = blockIdx.x * blockDim.x + threadIdx.x;
    if (n >= nrows) return;
    int j0 = blockIdx.y * JC;
    float acc[JC];
#pragma unroll
    for (int j = 0; j < JC; j++) acc[j] = bias ? bias[j0 + j] : 0.f;
    const float* r1 = in1 + (long)n * ld1;
    for (int k = 0; k < K1; k++) {
        float v = r1[k];
        const float* wr = W + (long)k * ldw + j0;
#pragma unroll
        for (int j = 0; j < JC; j++) acc[j] = fmaf(v, wr[j], acc[j]);
    }
    if constexpr (K2 > 0) {
        float dinv = 1.f;
        if constexpr (DIV2) dinv = 1.f / ((float)degi[n] + 1e-6f);
        const float* r2 = in2 + (long)n * ld2;
        for (int k = 0; k < K2; k++) {
            float v = r2[k] * dinv;
            const float* wr = W + (long)(K1 + k) * ldw + j0;
#pragma unroll
            for (int j = 0; j < JC; j++) acc[j] = fmaf(v, wr[j], acc[j]);
        }
    }
    float* orow = out + (long)n * ldo + j0;
#pragma unroll
    for (int j = 0; j < JC; j++) {
        float v = acc[j];
        if (RELU) v = fmaxf(v, 0.f);
        orow[j] = v;
    }
}

// ---------------- fused msg GEMM + segmented sum over CSR-ordered edges ----------------
__global__ __launch_bounds__(256) void k_msg_seg(
    const float* __restrict__ P, const float* __restrict__ ea,
    const float* __restrict__ W /*[64][128]*/, const float* __restrict__ bias,
    const int* __restrict__ src, const int* __restrict__ dst,
    const int* __restrict__ eid,
    float* __restrict__ s, int n_edges) {
    __shared__ float ea_s[64][64];
    __shared__ float W_s[64][128];   // reused as the msg tile after the k-loop
    __shared__ int sn_s[64];
    __shared__ int es_s[64];
    __shared__ int nid_s[64];
    __shared__ int bound_s[2];       // prev_n, next_n
    int tid = threadIdx.x;
    int t0 = blockIdx.x * 64;

    if (tid < 64) {
        int slot = t0 + tid;
        int e = (slot < n_edges) ? eid[slot] : 0;
        es_s[tid] = e;
        sn_s[tid] = src[e];
        nid_s[tid] = (slot < n_edges) ? dst[e] : -1;
    }
    if (tid == 64) bound_s[0] = (t0 > 0) ? dst[eid[t0 - 1]] : -1;
    if (tid == 65) bound_s[1] = (t0 + 64 < n_edges) ? dst[eid[t0 + 64]] : -1;
#pragma unroll
    for (int i = 0; i < 8; i++) {
        int f = tid + 256 * i;
        ((float4*)W_s)[f] = ((const float4*)W)[f];
    }
    __syncthreads();
#pragma unroll
    for (int i = 0; i < 4; i++) {
        int f = tid + 256 * i;
        int el = f >> 4, c = f & 15;
        float4 v = ((const float4*)(ea + (long)es_s[el] * 64))[c];
        *((float4*)&ea_s[el][c * 4]) = v;
    }
    __syncthreads();

    int jg = tid & 31;   // j0 = jg*4
    int eg = tid >> 5;   // rows eg*8 .. eg*8+7
    int j0 = jg * 4;
    float acc[8][4];
#pragma unroll
    for (int el = 0; el < 8; el++)
#pragma unroll
        for (int jj = 0; jj < 4; jj++) acc[el][jj] = 0.f;

    for (int k4 = 0; k4 < 16; k4++) {
        float4 wv[4];
#pragma unroll
        for (int kk = 0; kk < 4; kk++) wv[kk] = *(const float4*)&W_s[k4 * 4 + kk][j0];
#pragma unroll
        for (int el = 0; el < 8; el++) {
            float4 av = *(const float4*)&ea_s[eg * 8 + el][k4 * 4];
#pragma unroll
            for (int jj = 0; jj < 4; jj++) {
                float a = acc[el][jj];
                a = fmaf(av.x, ((const float*)&wv[0])[jj], a);
                a = fmaf(av.y, ((const float*)&wv[1])[jj], a);
                a = fmaf(av.z, ((const float*)&wv[2])[jj], a);
                a = fmaf(av.w, ((const float*)&wv[3])[jj], a);
                acc[el][jj] = a;
            }
        }
    }
    __syncthreads();   // everyone done reading W_s / ea_s

    float4 bv = *(const float4*)(bias + j0);
#pragma unroll
    for (int el = 0; el < 8; el++) {
        int row = eg * 8 + el;
        float4 pv = *(const float4*)(P + (long)sn_s[row] * 128 + j0);
        float4 o;
        o.x = fmaxf(acc[el][0] + pv.x + bv.x, 0.f);
        o.y = fmaxf(acc[el][1] + pv.y + bv.y, 0.f);
        o.z = fmaxf(acc[el][2] + pv.z + bv.z, 0.f);
        o.w = fmaxf(acc[el][3] + pv.w + bv.w, 0.f);
        *((float4*)&W_s[row][j0]) = o;
    }
    __syncthreads();

    if (tid < 128) {
        int c = tid;
        int rows = min(64, n_edges - t0);
        int prev_n = bound_s[0], next_n = bound_s[1];
        int cur = nid_s[0];
        int seg_start = 0;
        float run = 0.f;
        for (int r = 0; r < rows; r++) {
            int nd = nid_s[r];
            if (nd != cur) {
                if (seg_start == 0 && cur == prev_n) atomicAdd(s + (long)cur * 128 + c, run);
                else s[(long)cur * 128 + c] = run;
                cur = nd; seg_start = r; run = 0.f;
            }
            run += W_s[r][c];
        }
        if ((seg_start == 0 && cur == prev_n) || cur == next_n)
            atomicAdd(s + (long)cur * 128 + c, run);
        else s[(long)cur * 128 + c] = run;
    }
}

// ---------------- edge classifier (register-staged gathers) + einfo pack ---------------
__global__ __launch_bounds__(256) void k_edge_cls(
    const float* __restrict__ nS, const float* __restrict__ nD,
    const float* __restrict__ ea, const float* __restrict__ Ct /*[64][64]*/,
    const float* __restrict__ b1, const float* __restrict__ w2, const float* __restrict__ b2,
    const int* __restrict__ src, const int* __restrict__ dst,
    const int* __restrict__ uts, const int* __restrict__ tsmax,
    float* __restrict__ logits_out, float4* __restrict__ einfo) {
    int e = blockIdx.x * blockDim.x + threadIdx.x;
    if (e >= N_EDGES) return;
    int sn = src[e], dn = dst[e];
    float base[64];
    const float4* Sr4 = (const float4*)(nS + (long)sn * 64);
    const float4* Dr4 = (const float4*)(nD + (long)dn * 64);
#pragma unroll
    for (int i = 0; i < 16; i++) {
        float4 sv = Sr4[i];
        float4 dv = Dr4[i];
        base[4 * i + 0] = sv.x + dv.x;
        base[4 * i + 1] = sv.y + dv.y;
        base[4 * i + 2] = sv.z + dv.z;
        base[4 * i + 3] = sv.w + dv.w;
    }
    float a[64];
    const float4* ar = (const float4*)(ea + (long)e * 64);
#pragma unroll
    for (int i = 0; i < 16; i++) {
        float4 v = ar[i];
        a[4 * i] = v.x; a[4 * i + 1] = v.y; a[4 * i + 2] = v.z; a[4 * i + 3] = v.w;
    }
    float logit = b2[0];
    for (int j = 0; j < 64; j++) {
        float t = b1[j] + base[j];
        const float* wr = Ct + j * 64;   // wave-uniform -> scalar loads
#pragma unroll
        for (int k = 0; k < 64; k++) t = fmaf(a[k], wr[k], t);
        t = fmaxf(t, 0.f);
        logit = fmaf(t, w2[j], logit);
    }
    logits_out[e] = logit;
    float p = 1.f / (1.f + expf(-logit));
    float now = (float)(*tsmax);
    float age = fmaxf(now - (float)uts[e], 0.f);
    float decay = expf(-age / 2592000.f);
    einfo[e] = make_float4(p, decay, age, 0.f);
}

// ---------------- ts max reduction -----------------------------------------------------
__global__ void k_tsmax(const int* __restrict__ ts, int* __restrict__ out) {
    int i = blockIdx.x * blockDim.x + threadIdx.x;
    int stride = gridDim.x * blockDim.x;
    int m = 0;
    for (int t = i; t < N_EDGES; t += stride) m = max(m, ts[t]);
#pragma unroll
    for (int off = 32; off > 0; off >>= 1) m = max(m, __shfl_down(m, off));
    if ((threadIdx.x & 63) == 0) atomicMax(out, m);
}

// ---------------- per-node aggregation over incidence CSR (no atomics) -----------------
__global__ __launch_bounds__(256) void k_node_agg(
    const float4* __restrict__ einfo, const int* __restrict__ row2,
    const int* __restrict__ eid2, float* __restrict__ feat8) {
    int n = blockIdx.x * blockDim.x + threadIdx.x;
    if (n >= N_NODES) return;
    int e0 = row2[n], e1 = row2[n + 1];
    float cnt = (float)(e1 - e0);
    float sump = 0.f, maxp = 0.f, sumh = 0.f, sumpd = 0.f, sumd = 0.f;
    float sumh30 = 0.f, maxp30 = 0.f, sump30 = 0.f, suml30 = 0.f, minage = 9999.f;
    for (int idx = e0; idx < e1; idx++) {
        float4 v = einfo[eid2[idx]];
        float p = v.x, decay = v.y, age = v.z;
        float aged = age / 86400.f;
        bool high = p >= 0.7f;
        bool l30 = age <= 2592000.f;
        sump += p;
        maxp = fmaxf(maxp, p);
        sumpd += p * decay;
        sumd += decay;
        if (high) {
            sumh += 1.f;
            minage = fminf(minage, aged);
        }
        if (l30) {
            sump30 += p;
            suml30 += 1.f;
            maxp30 = fmaxf(maxp30, p);
            if (high) sumh30 += 1.f;
        }
    }
    float* f = feat8 + (long)n * 8;
    f[0] = sump / (cnt + 1e-6f);
    f[1] = maxp;
    f[2] = log1pf(sumh);
    f[3] = sumpd / (sumd + 1e-6f);
    f[4] = log1pf(sumh30);
    f[5] = maxp30;
    f[6] = sump30 / (suml30 + 1e-6f);
    f[7] = log1pf(fminf(fminf(minage, 9999.f), 90.f)) / log1pf(90.f);
}

// ---------------- node classifier ------------------------------------------------------
__global__ __launch_bounds__(256) void k_node_cls(
    const float* __restrict__ ne, const float* __restrict__ feat8,
    const float* __restrict__ w1t /*[64][72]*/, const float* __restrict__ b1,
    const float* __restrict__ gamma, const float* __restrict__ beta,
    const float* __restrict__ mean, const float* __restrict__ var,
    const float* __restrict__ w2, const float* __restrict__ b2,
    float* __restrict__ out) {
    int n = blockIdx.x * blockDim.x + threadIdx.x;
    if (n >= N_NODES) return;
    float in[72];
    const float4* nr = (const float4*)(ne + (long)n * 64);
#pragma unroll
    for (int i = 0; i < 16; i++) {
        float4 v = nr[i];
        in[4 * i] = v.x; in[4 * i + 1] = v.y; in[4 * i + 2] = v.z; in[4 * i + 3] = v.w;
    }
    const float4* fr = (const float4*)(feat8 + (long)n * 8);
    float4 f0 = fr[0], f1 = fr[1];
    in[64] = f0.x; in[65] = f0.y; in[66] = f0.z; in[67] = f0.w;
    in[68] = f1.x; in[69] = f1.y; in[70] = f1.z; in[71] = f1.w;
    float logit = b2[0];
    for (int j = 0; j < 64; j++) {
        float h = b1[j];
        const float* wr = w1t + j * 72;
#pragma unroll
        for (int k = 0; k < 72; k++) h = fmaf(in[k], wr[k], h);
        h = (h - mean[j]) * rsqrtf(var[j] + 1e-5f) * gamma[j] + beta[j];
        h = fmaxf(h, 0.f);
        logit = fmaf(h, w2[j], logit);
    }
    out[n] = logit;
}

// weight transpose: dst[j*kpad + k] = src[k*ldw + j]
__global__ void k_transpose(const float* __restrict__ src, float* __restrict__ dst,
                            int K, int J, int ldw, int kpad) {
    int i = blockIdx.x * blockDim.x + threadIdx.x;
    if (i >= K * J) return;
    int k = i / J, j = i - k * J;
    dst[j * kpad + k] = src[k * ldw + j];
}

extern "C" void kernel_launch(void* const* d_in, const int* in_sizes, int n_in,
                              void* d_out, int out_size, void* d_ws, size_t ws_size,
                              hipStream_t stream) {
    const float* x = (const float*)d_in[0];
    const int* eidx = (const int*)d_in[1];
    const int* src = eidx;
    const int* dst = eidx + N_EDGES;
    const float* la = (const float*)d_in[2];
    const float* tse = (const float*)d_in[3];
    const int* bp = (const int*)d_in[4];
    const int* tt = (const int*)d_in[5];
    const float* cr = (const float*)d_in[6];
    const float* tsp = (const float*)d_in[7];
    const float* tg = (const float*)d_in[8];
    const float* r7 = (const float*)d_in[9];
    const float* r30 = (const float*)d_in[10];
    const int* uts = (const int*)d_in[11];
    const float* tx_emb = (const float*)d_in[12];
    const float* bank_emb = (const float*)d_in[13];
    const float* ee_w1 = (const float*)d_in[14];
    const float* ee_b1 = (const float*)d_in[15];
    const float* ee_w2 = (const float*)d_in[16];
    const float* ee_b2 = (const float*)d_in[17];
    const float* msg1_w = (const float*)d_in[18];
    const float* msg1_b = (const float*)d_in[19];
    const float* upd1_w = (const float*)d_in[20];
    const float* upd1_b = (const float*)d_in[21];
    const float* msg2_w = (const float*)d_in[22];
    const float* msg2_b = (const float*)d_in[23];
    const float* upd2_w = (const float*)d_in[24];
    const float* upd2_b = (const float*)d_in[25];
    const float* ec_w1 = (const float*)d_in[26];
    const float* ec_b1 = (const float*)d_in[27];
    const float* ec_w2 = (const float*)d_in[28];
    const float* ec_b2 = (const float*)d_in[29];
    const float* nc_w1 = (const float*)d_in[30];
    const float* nc_b1 = (const float*)d_in[31];
    const float* bn_g = (const float*)d_in[32];
    const float* bn_b = (const float*)d_in[33];
    const float* bn_m = (const float*)d_in[34];
    const float* bn_v = (const float*)d_in[35];
    const float* nc_w2 = (const float*)d_in[36];
    const float* nc_b2 = (const float*)d_in[37];

    float* out_node = (float*)d_out;              // [N_NODES]
    float* out_edge = (float*)d_out + N_NODES;    // [N_EDGES]

    // workspace layout (floats) — round-6 proven footprint
    float* ws = (float*)d_ws;
    float* ea = ws;                         // E*64
    float* P = ea + (long)N_EDGES * 64;     // N*128 (dead after 2nd msg_seg -> einfo)
    float* s = P + (long)N_NODES * 128;     // N*128 (dead after upd2 gemm -> eid2)
    float* h1 = s + (long)N_NODES * 128;    // N*128
    float* ne = h1 + (long)N_NODES * 128;   // N*64
    float* nS = ne + (long)N_NODES * 64;    // N*64
    float* nD = nS + (long)N_NODES * 64;    // N*64
    float* feat8 = nD + (long)N_NODES * 64; // N*8
    float* w1t = feat8 + (long)N_NODES * 8; // 128*40 (unused now, kept for layout)
    float* Ct = w1t + 128 * 40;             // 64*64
    float* ncw1t = Ct + 64 * 64;            // 64*72
    int* tsmax = (int*)(ncw1t + 64 * 72);   // 1
    int* degi = tsmax + 1;                  // N   (CSR1 by dst)
    int* row_start = degi + N_NODES;        // N+1
    int* cursor = row_start + N_NODES + 1;  // N
    int* eid = cursor + N_NODES;            // E
    int* partials = eid + N_EDGES;          // 256
    int* deg2 = partials + 256;             // N   (CSR2 incidence)
    int* row2 = deg2 + N_NODES;             // N+1
    int* cursor2 = row2 + N_NODES + 1;      // N
    // aliased regions:
    float4* einfo = (float4*)P;             // E float4 (8 MB < P's 25.6 MB)
    int* eid2 = (int*)s;                    // 2E ints (4 MB < s's 25.6 MB)

    const int EB = (N_EDGES + 255) / 256;    // 1954
    const int E2B = (2 * N_EDGES + 255) / 256;
    const int NB = (N_NODES + 255) / 256;    // 196
    const int MB = (N_EDGES + 63) / 64;      // 7813

    // ---- init ----
    hipMemsetAsync(tsmax, 0, 4, stream);
    hipMemsetAsync(degi, 0, (size_t)N_NODES * 4, stream);
    hipMemsetAsync(s, 0, (size_t)N_NODES * 128 * 4, stream);

    // ---- CSR1 build (by dst) ----
    k_deg_count<<<EB, 256, 0, stream>>>(dst, degi, N_EDGES);
    k_block_sums<<<NB, 256, 0, stream>>>(degi, partials, N_NODES);
    k_scan_partials<<<1, 256, 0, stream>>>(partials, NB);
    k_scan_final<<<NB, 256, 0, stream>>>(degi, partials, row_start, N_NODES);
    hipMemcpyAsync(cursor, row_start, (size_t)N_NODES * 4, hipMemcpyDeviceToDevice, stream);
    k_fill_slots<<<EB, 256, 0, stream>>>(dst, cursor, eid);

    // ---- weight transposes ----
    k_transpose<<<(64 * 64 + 255) / 256, 256, 0, stream>>>(ec_w1 + 128 * 64, Ct, 64, 64, 64, 64);
    k_transpose<<<(72 * 64 + 255) / 256, 256, 0, stream>>>(nc_w1, ncw1t, 72, 64, 64, 72);

    // ---- edge encoder (LDS-tiled) ----
    k_edge_enc_tiled<<<MB, 256, 0, stream>>>(la, tse, bp, tt, cr, tsp, tg, r7, r30,
                                             tx_emb, bank_emb, ee_w1, ee_b1, ee_w2, ee_b2,
                                             ea, N_EDGES);

    // ---- SAGE layer 1 ----
    k_node_gemm<128, 0, 64, false, false><<<dim3(NB, 2), 256, 0, stream>>>(
        x, 128, nullptr, 0, nullptr, msg1_w, 128, nullptr, P, 128, N_NODES);
    k_msg_seg<<<MB, 256, 0, stream>>>(P, ea, msg1_w + 128 * 128, msg1_b, src, dst, eid, s, N_EDGES);
    k_node_gemm<128, 128, 64, true, true><<<dim3(NB, 2), 256, 0, stream>>>(
        x, 128, s, 128, degi, upd1_w, 128, upd1_b, h1, 128, N_NODES);

    // ---- SAGE layer 2 ----
    k_node_gemm<128, 0, 64, false, false><<<dim3(NB, 2), 256, 0, stream>>>(
        h1, 128, nullptr, 0, nullptr, msg2_w, 128, nullptr, P, 128, N_NODES);
    hipMemsetAsync(s, 0, (size_t)N_NODES * 128 * 4, stream);
    k_msg_seg<<<MB, 256, 0, stream>>>(P, ea, msg2_w + 128 * 128, msg2_b, src, dst, eid, s, N_EDGES);
    k_node_gemm<128, 128, 64, true, true><<<dim3(NB, 1), 256, 0, stream>>>(
        h1, 128, s, 128, degi, upd2_w, 64, upd2_b, ne, 64, N_NODES);
    // s and P are now dead -> eid2 / einfo aliases safe from here on

    // ---- edge classifier prep ----
    k_node_gemm<64, 0, 64, false, false><<<dim3(NB, 1), 256, 0, stream>>>(
        ne, 64, nullptr, 0, nullptr, ec_w1, 64, nullptr, nS, 64, N_NODES);
    k_node_gemm<64, 0, 64, false, false><<<dim3(NB, 1), 256, 0, stream>>>(
        ne, 64, nullptr, 0, nullptr, ec_w1 + 64 * 64, 64, nullptr, nD, 64, N_NODES);

    // ---- CSR2 build (incidence over both endpoints; keys = flat eidx) ----
    hipMemsetAsync(deg2, 0, (size_t)N_NODES * 4, stream);
    k_deg_count<<<E2B, 256, 0, stream>>>(eidx, deg2, 2 * N_EDGES);
    k_block_sums<<<NB, 256, 0, stream>>>(deg2, partials, N_NODES);
    k_scan_partials<<<1, 256, 0, stream>>>(partials, NB);
    k_scan_final<<<NB, 256, 0, stream>>>(deg2, partials, row2, N_NODES);
    hipMemcpyAsync(cursor2, row2, (size_t)N_NODES * 4, hipMemcpyDeviceToDevice, stream);
    k_fill_slots2<<<E2B, 256, 0, stream>>>(eidx, cursor2, eid2);

    // ---- edge classifier (+ einfo pack) ----
    k_tsmax<<<256, 256, 0, stream>>>(uts, tsmax);
    k_edge_cls<<<EB, 256, 0, stream>>>(nS, nD, ea, Ct, ec_b1, ec_w2, ec_b2,
                                       src, dst, uts, tsmax, out_edge, einfo);

    // ---- node aggregation (gather, no atomics) ----
    k_node_agg<<<NB, 256, 0, stream>>>(einfo, row2, eid2, feat8);

    // ---- node classifier ----
    k_node_cls<<<NB, 256, 0, stream>>>(ne, feat8, ncw1t, nc_b1, bn_g, bn_b, bn_m, bn_v,
                                       nc_w2, nc_b2, out_node);
}

// Round 8
// 1484.074 us; speedup vs baseline: 5.6891x; 1.0309x over previous
//
#include <hip/hip_runtime.h>
#include <math.h>

#define N_NODES 50000
#define N_EDGES 500000

// =================== CSR build helpers ====================
__global__ void k_deg_count(const int* __restrict__ keys, int* __restrict__ degi, int n) {
    int e = blockIdx.x * blockDim.x + threadIdx.x;
    if (e < n) atomicAdd(degi + keys[e], 1);
}

__global__ void k_block_sums(const int* __restrict__ deg, int* __restrict__ partials, int n) {
    __shared__ int sm[256];
    int i = blockIdx.x * 256 + threadIdx.x;
    sm[threadIdx.x] = (i < n) ? deg[i] : 0;
    __syncthreads();
    for (int s = 128; s > 0; s >>= 1) {
        if (threadIdx.x < s) sm[threadIdx.x] += sm[threadIdx.x + s];
        __syncthreads();
    }
    if (threadIdx.x == 0) partials[blockIdx.x] = sm[0];
}

// single block: in-place exclusive scan of partials[nb], nb<=256
__global__ void k_scan_partials(int* partials, int nb) {
    __shared__ int sm[256];
    int v = (threadIdx.x < nb) ? partials[threadIdx.x] : 0;
    sm[threadIdx.x] = v;
    __syncthreads();
    for (int off = 1; off < 256; off <<= 1) {
        int t = (threadIdx.x >= off) ? sm[threadIdx.x - off] : 0;
        __syncthreads();
        sm[threadIdx.x] += t;
        __syncthreads();
    }
    if (threadIdx.x < nb) partials[threadIdx.x] = sm[threadIdx.x] - v;  // exclusive
}

__global__ void k_scan_final(const int* __restrict__ deg, const int* __restrict__ partials,
                             int* __restrict__ row_start, int n) {
    __shared__ int sm[256];
    int i = blockIdx.x * 256 + threadIdx.x;
    int v = (i < n) ? deg[i] : 0;
    sm[threadIdx.x] = v;
    __syncthreads();
    for (int off = 1; off < 256; off <<= 1) {
        int t = (threadIdx.x >= off) ? sm[threadIdx.x - off] : 0;
        __syncthreads();
        sm[threadIdx.x] += t;
        __syncthreads();
    }
    if (i < n) row_start[i] = partials[blockIdx.x] + sm[threadIdx.x] - v;  // exclusive
    if (i == n - 1) row_start[n] = partials[blockIdx.x] + sm[threadIdx.x]; // total
}

__global__ void k_fill_slots(const int* __restrict__ dst, int* __restrict__ cursor,
                             int* __restrict__ eid) {
    int e = blockIdx.x * blockDim.x + threadIdx.x;
    if (e >= N_EDGES) return;
    int pos = atomicAdd(cursor + dst[e], 1);
    eid[pos] = e;
}

// incidence fill over 2E entries: entry i -> node eidx[i], edge (i % E)
__global__ void k_fill_slots2(const int* __restrict__ eidx, int* __restrict__ cursor,
                              int* __restrict__ eid2) {
    int i = blockIdx.x * blockDim.x + threadIdx.x;
    if (i >= 2 * N_EDGES) return;
    int pos = atomicAdd(cursor + eidx[i], 1);
    eid2[pos] = (i < N_EDGES) ? i : (i - N_EDGES);
}

// ---------------- edge encoder, LDS-tiled with buffer union ----------------------------
// Phase A: F_s[64][40] feats + W_s[40][128] w1 staged.   (30.7 KB, overlaid)
// Phase B: GEMM1 into registers; sync; relu+b1 -> H_s[64][132] (33.8 KB, same union).
// Phase C: GEMM2 (w2 from global via L1) -> ea.
// Union = 8448 floats = 33.8 KB -> 4 blocks/CU (was 64.5 KB -> 2 blocks/CU).
__global__ __launch_bounds__(256) void k_edge_enc_tiled(
    const float* __restrict__ la, const float* __restrict__ tse,
    const int* __restrict__ bp, const int* __restrict__ tt,
    const float* __restrict__ cr, const float* __restrict__ tsp,
    const float* __restrict__ tg, const float* __restrict__ r7,
    const float* __restrict__ r30,
    const float* __restrict__ tx_emb, const float* __restrict__ bank_emb,
    const float* __restrict__ w1 /*[38][128]*/, const float* __restrict__ eb1,
    const float* __restrict__ w2 /*[128][64]*/, const float* __restrict__ eb2,
    float* __restrict__ ea, int n_edges) {
    __shared__ float smem[64 * 132];           // 33.8 KB union
    float* F_s = smem;                         // [64][40]  = 2560 floats
    float* W_s = smem + 64 * 40;               // [40][128] = 5120 floats
    float* H_s = smem;                         // [64][132] = 8448 floats (overlays F+W)
    int tid = threadIdx.x;
    int t0 = blockIdx.x * 64;

    // ---- stage w1: 38*128 floats = 1216 float4 (rows 38,39 zeroed) ----
#pragma unroll
    for (int i = 0; i < 5; i++) {
        int f = tid + 256 * i;          // float4 index into [40][128]
        if (f < 1280) {
            float4 v = make_float4(0.f, 0.f, 0.f, 0.f);
            if (f < 1216) v = ((const float4*)w1)[f];
            ((float4*)W_s)[f] = v;
        }
    }
    // ---- build feats tile: thread (el = tid&63, g = tid>>6) ----
    {
        int el = tid & 63, g = tid >> 6;
        int e = t0 + el;
        bool ok = e < n_edges;
        float* Fr = F_s + el * 40;
        if (g == 0) {
            Fr[0] = ok ? la[e] : 0.f;
            Fr[1] = ok ? cr[e] : 0.f;
            Fr[2] = ok ? tsp[e] : 0.f;
            Fr[3] = ok ? tg[e] : 0.f;
            Fr[4] = ok ? r7[e] : 0.f;
            Fr[5] = ok ? r30[e] : 0.f;
            Fr[38] = 0.f; Fr[39] = 0.f;
        } else if (g == 1) {
            float4 a = make_float4(0, 0, 0, 0), b = a;
            if (ok) { a = ((const float4*)(tse + (long)e * 8))[0];
                      b = ((const float4*)(tse + (long)e * 8))[1]; }
            Fr[6] = a.x; Fr[7] = a.y; Fr[8] = a.z; Fr[9] = a.w;
            Fr[10] = b.x; Fr[11] = b.y; Fr[12] = b.z; Fr[13] = b.w;
        } else if (g == 2) {
            float4 a = make_float4(0, 0, 0, 0), b = a;
            if (ok) { int txi = tt[e];
                      a = ((const float4*)(tx_emb + (long)txi * 8))[0];
                      b = ((const float4*)(tx_emb + (long)txi * 8))[1]; }
            Fr[14] = a.x; Fr[15] = a.y; Fr[16] = a.z; Fr[17] = a.w;
            Fr[18] = b.x; Fr[19] = b.y; Fr[20] = b.z; Fr[21] = b.w;
        } else {
            float4 a = make_float4(0, 0, 0, 0), b = a, c = a, d = a;
            if (ok) {
                int bk0 = bp[e * 2 + 0], bk1 = bp[e * 2 + 1];
                a = ((const float4*)(bank_emb + (long)bk0 * 8))[0];
                b = ((const float4*)(bank_emb + (long)bk0 * 8))[1];
                c = ((const float4*)(bank_emb + (long)bk1 * 8))[0];
                d = ((const float4*)(bank_emb + (long)bk1 * 8))[1];
            }
            Fr[22] = a.x; Fr[23] = a.y; Fr[24] = a.z; Fr[25] = a.w;
            Fr[26] = b.x; Fr[27] = b.y; Fr[28] = b.z; Fr[29] = b.w;
            Fr[30] = c.x; Fr[31] = c.y; Fr[32] = c.z; Fr[33] = c.w;
            Fr[34] = d.x; Fr[35] = d.y; Fr[36] = d.z; Fr[37] = d.w;
        }
    }
    __syncthreads();

    // ---- GEMM1 k-loop (accumulators stay in registers) ----
    int jg1 = tid & 31, eg1 = tid >> 5;
    int j1 = jg1 * 4;
    float acc1[8][4];
#pragma unroll
    for (int el = 0; el < 8; el++)
#pragma unroll
        for (int jj = 0; jj < 4; jj++) acc1[el][jj] = 0.f;
    for (int k4 = 0; k4 < 10; k4++) {
        float4 wv[4];
#pragma unroll
        for (int kk = 0; kk < 4; kk++)
            wv[kk] = *(const float4*)&W_s[(k4 * 4 + kk) * 128 + j1];
#pragma unroll
        for (int el = 0; el < 8; el++) {
            float4 av = *(const float4*)&F_s[(eg1 * 8 + el) * 40 + k4 * 4];
#pragma unroll
            for (int jj = 0; jj < 4; jj++) {
                float a = acc1[el][jj];
                a = fmaf(av.x, ((const float*)&wv[0])[jj], a);
                a = fmaf(av.y, ((const float*)&wv[1])[jj], a);
                a = fmaf(av.z, ((const float*)&wv[2])[jj], a);
                a = fmaf(av.w, ((const float*)&wv[3])[jj], a);
                acc1[el][jj] = a;
            }
        }
    }
    __syncthreads();   // all reads of F_s/W_s complete before H_s overlays them

    // ---- write H tile: relu(acc1 + b1) ----
    {
        float4 bv = *(const float4*)(eb1 + j1);
#pragma unroll
        for (int el = 0; el < 8; el++) {
            int row = eg1 * 8 + el;
            float4 o;
            o.x = fmaxf(acc1[el][0] + bv.x, 0.f);
            o.y = fmaxf(acc1[el][1] + bv.y, 0.f);
            o.z = fmaxf(acc1[el][2] + bv.z, 0.f);
            o.w = fmaxf(acc1[el][3] + bv.w, 0.f);
            *((float4*)&H_s[row * 132 + j1]) = o;
        }
    }
    __syncthreads();

    // ---- GEMM2: out[64][64] = H @ w2 + b2, tile 4 edges x 4 outs / thread ----
    {
        int jg = tid & 15, eg = tid >> 4;
        int j0 = jg * 4;
        float acc[4][4];
#pragma unroll
        for (int el = 0; el < 4; el++)
#pragma unroll
            for (int jj = 0; jj < 4; jj++) acc[el][jj] = 0.f;
        for (int k4 = 0; k4 < 32; k4++) {
            float4 wv[4];
#pragma unroll
            for (int kk = 0; kk < 4; kk++)
                wv[kk] = *(const float4*)(w2 + (long)(k4 * 4 + kk) * 64 + j0);
#pragma unroll
            for (int el = 0; el < 4; el++) {
                float4 av = *(const float4*)&H_s[(eg * 4 + el) * 132 + k4 * 4];
#pragma unroll
                for (int jj = 0; jj < 4; jj++) {
                    float a = acc[el][jj];
                    a = fmaf(av.x, ((const float*)&wv[0])[jj], a);
                    a = fmaf(av.y, ((const float*)&wv[1])[jj], a);
                    a = fmaf(av.z, ((const float*)&wv[2])[jj], a);
                    a = fmaf(av.w, ((const float*)&wv[3])[jj], a);
                    acc[el][jj] = a;
                }
            }
        }
        float4 bv = *(const float4*)(eb2 + j0);
#pragma unroll
        for (int el = 0; el < 4; el++) {
            int e = t0 + eg * 4 + el;
            if (e >= n_edges) continue;
            float4 o;
            o.x = acc[el][0] + bv.x;
            o.y = acc[el][1] + bv.y;
            o.z = acc[el][2] + bv.z;
            o.w = acc[el][3] + bv.w;
            *((float4*)(ea + (long)e * 64 + j0)) = o;
        }
    }
}

// ---------------- generic node-level GEMM: out[n, j0:j0+JC] = act(b + in1@W[:K1] + (in2/deg)@W[K1:]) ---
template <int K1, int K2, int JC, bool RELU, bool DIV2>
__global__ __launch_bounds__(256) void k_node_gemm(
    const float* __restrict__ in1, int ld1,
    const float* __restrict__ in2, int ld2,
    const int* __restrict__ degi,
    const float* __restrict__ W, int ldw,
    const float* __restrict__ bias,
    float* __restrict__ out, int ldo, int nrows) {
    int n = blockIdx.x * blockDim.x + threadIdx.x;
    if (n >= nrows) return;
    int j0 = blockIdx.y * JC;
    float acc[JC];
#pragma unroll
    for (int j = 0; j < JC; j++) acc[j] = bias ? bias[j0 + j] : 0.f;
    const float* r1 = in1 + (long)n * ld1;
    for (int k = 0; k < K1; k++) {
        float v = r1[k];
        const float* wr = W + (long)k * ldw + j0;
#pragma unroll
        for (int j = 0; j < JC; j++) acc[j] = fmaf(v, wr[j], acc[j]);
    }
    if constexpr (K2 > 0) {
        float dinv = 1.f;
        if constexpr (DIV2) dinv = 1.f / ((float)degi[n] + 1e-6f);
        const float* r2 = in2 + (long)n * ld2;
        for (int k = 0; k < K2; k++) {
            float v = r2[k] * dinv;
            const float* wr = W + (long)(K1 + k) * ldw + j0;
#pragma unroll
            for (int j = 0; j < JC; j++) acc[j] = fmaf(v, wr[j], acc[j]);
        }
    }
    float* orow = out + (long)n * ldo + j0;
#pragma unroll
    for (int j = 0; j < JC; j++) {
        float v = acc[j];
        if (RELU) v = fmaxf(v, 0.f);
        orow[j] = v;
    }
}

// ---------------- fused msg GEMM + segmented sum over CSR-ordered edges ----------------
__global__ __launch_bounds__(256) void k_msg_seg(
    const float* __restrict__ P, const float* __restrict__ ea,
    const float* __restrict__ W /*[64][128]*/, const float* __restrict__ bias,
    const int* __restrict__ src, const int* __restrict__ dst,
    const int* __restrict__ eid,
    float* __restrict__ s, int n_edges) {
    __shared__ float ea_s[64][64];
    __shared__ float W_s[64][128];   // reused as the msg tile after the k-loop
    __shared__ int sn_s[64];
    __shared__ int es_s[64];
    __shared__ int nid_s[64];
    __shared__ int bound_s[2];       // prev_n, next_n
    int tid = threadIdx.x;
    int t0 = blockIdx.x * 64;

    if (tid < 64) {
        int slot = t0 + tid;
        int e = (slot < n_edges) ? eid[slot] : 0;
        es_s[tid] = e;
        sn_s[tid] = src[e];
        nid_s[tid] = (slot < n_edges) ? dst[e] : -1;
    }
    if (tid == 64) bound_s[0] = (t0 > 0) ? dst[eid[t0 - 1]] : -1;
    if (tid == 65) bound_s[1] = (t0 + 64 < n_edges) ? dst[eid[t0 + 64]] : -1;
#pragma unroll
    for (int i = 0; i < 8; i++) {
        int f = tid + 256 * i;
        ((float4*)W_s)[f] = ((const float4*)W)[f];
    }
    __syncthreads();
#pragma unroll
    for (int i = 0; i < 4; i++) {
        int f = tid + 256 * i;
        int el = f >> 4, c = f & 15;
        float4 v = ((const float4*)(ea + (long)es_s[el] * 64))[c];
        *((float4*)&ea_s[el][c * 4]) = v;
    }
    __syncthreads();

    int jg = tid & 31;   // j0 = jg*4
    int eg = tid >> 5;   // rows eg*8 .. eg*8+7
    int j0 = jg * 4;
    float acc[8][4];
#pragma unroll
    for (int el = 0; el < 8; el++)
#pragma unroll
        for (int jj = 0; jj < 4; jj++) acc[el][jj] = 0.f;

    for (int k4 = 0; k4 < 16; k4++) {
        float4 wv[4];
#pragma unroll
        for (int kk = 0; kk < 4; kk++) wv[kk] = *(const float4*)&W_s[k4 * 4 + kk][j0];
#pragma unroll
        for (int el = 0; el < 8; el++) {
            float4 av = *(const float4*)&ea_s[eg * 8 + el][k4 * 4];
#pragma unroll
            for (int jj = 0; jj < 4; jj++) {
                float a = acc[el][jj];
                a = fmaf(av.x, ((const float*)&wv[0])[jj], a);
                a = fmaf(av.y, ((const float*)&wv[1])[jj], a);
                a = fmaf(av.z, ((const float*)&wv[2])[jj], a);
                a = fmaf(av.w, ((const float*)&wv[3])[jj], a);
                acc[el][jj] = a;
            }
        }
    }
    __syncthreads();   // everyone done reading W_s / ea_s

    float4 bv = *(const float4*)(bias + j0);
#pragma unroll
    for (int el = 0; el < 8; el++) {
        int row = eg * 8 + el;
        float4 pv = *(const float4*)(P + (long)sn_s[row] * 128 + j0);
        float4 o;
        o.x = fmaxf(acc[el][0] + pv.x + bv.x, 0.f);
        o.y = fmaxf(acc[el][1] + pv.y + bv.y, 0.f);
        o.z = fmaxf(acc[el][2] + pv.z + bv.z, 0.f);
        o.w = fmaxf(acc[el][3] + pv.w + bv.w, 0.f);
        *((float4*)&W_s[row][j0]) = o;
    }
    __syncthreads();

    if (tid < 128) {
        int c = tid;
        int rows = min(64, n_edges - t0);
        int prev_n = bound_s[0], next_n = bound_s[1];
        int cur = nid_s[0];
        int seg_start = 0;
        float run = 0.f;
        for (int r = 0; r < rows; r++) {
            int nd = nid_s[r];
            if (nd != cur) {
                if (seg_start == 0 && cur == prev_n) atomicAdd(s + (long)cur * 128 + c, run);
                else s[(long)cur * 128 + c] = run;
                cur = nd; seg_start = r; run = 0.f;
            }
            run += W_s[r][c];
        }
        if ((seg_start == 0 && cur == prev_n) || cur == next_n)
            atomicAdd(s + (long)cur * 128 + c, run);
        else s[(long)cur * 128 + c] = run;
    }
}

// ---------------- edge classifier (register-staged gathers) + einfo pack ---------------
__global__ __launch_bounds__(256) void k_edge_cls(
    const float* __restrict__ nS, const float* __restrict__ nD,
    const float* __restrict__ ea, const float* __restrict__ Ct /*[64][64]*/,
    const float* __restrict__ b1, const float* __restrict__ w2, const float* __restrict__ b2,
    const int* __restrict__ src, const int* __restrict__ dst,
    const int* __restrict__ uts, const int* __restrict__ tsmax,
    float* __restrict__ logits_out, float4* __restrict__ einfo) {
    int e = blockIdx.x * blockDim.x + threadIdx.x;
    if (e >= N_EDGES) return;
    int sn = src[e], dn = dst[e];
    float base[64];
    const float4* Sr4 = (const float4*)(nS + (long)sn * 64);
    const float4* Dr4 = (const float4*)(nD + (long)dn * 64);
#pragma unroll
    for (int i = 0; i < 16; i++) {
        float4 sv = Sr4[i];
        float4 dv = Dr4[i];
        base[4 * i + 0] = sv.x + dv.x;
        base[4 * i + 1] = sv.y + dv.y;
        base[4 * i + 2] = sv.z + dv.z;
        base[4 * i + 3] = sv.w + dv.w;
    }
    float a[64];
    const float4* ar = (const float4*)(ea + (long)e * 64);
#pragma unroll
    for (int i = 0; i < 16; i++) {
        float4 v = ar[i];
        a[4 * i] = v.x; a[4 * i + 1] = v.y; a[4 * i + 2] = v.z; a[4 * i + 3] = v.w;
    }
    float logit = b2[0];
    for (int j = 0; j < 64; j++) {
        float t = b1[j] + base[j];
        const float* wr = Ct + j * 64;   // wave-uniform -> scalar loads
#pragma unroll
        for (int k = 0; k < 64; k++) t = fmaf(a[k], wr[k], t);
        t = fmaxf(t, 0.f);
        logit = fmaf(t, w2[j], logit);
    }
    logits_out[e] = logit;
    float p = 1.f / (1.f + expf(-logit));
    float now = (float)(*tsmax);
    float age = fmaxf(now - (float)uts[e], 0.f);
    float decay = expf(-age / 2592000.f);
    einfo[e] = make_float4(p, decay, age, 0.f);
}

// ---------------- ts max reduction -----------------------------------------------------
__global__ void k_tsmax(const int* __restrict__ ts, int* __restrict__ out) {
    int i = blockIdx.x * blockDim.x + threadIdx.x;
    int stride = gridDim.x * blockDim.x;
    int m = 0;
    for (int t = i; t < N_EDGES; t += stride) m = max(m, ts[t]);
#pragma unroll
    for (int off = 32; off > 0; off >>= 1) m = max(m, __shfl_down(m, off));
    if ((threadIdx.x & 63) == 0) atomicMax(out, m);
}

// ---------------- per-node aggregation over incidence CSR (no atomics) -----------------
__global__ __launch_bounds__(256) void k_node_agg(
    const float4* __restrict__ einfo, const int* __restrict__ row2,
    const int* __restrict__ eid2, float* __restrict__ feat8) {
    int n = blockIdx.x * blockDim.x + threadIdx.x;
    if (n >= N_NODES) return;
    int e0 = row2[n], e1 = row2[n + 1];
    float cnt = (float)(e1 - e0);
    float sump = 0.f, maxp = 0.f, sumh = 0.f, sumpd = 0.f, sumd = 0.f;
    float sumh30 = 0.f, maxp30 = 0.f, sump30 = 0.f, suml30 = 0.f, minage = 9999.f;
    for (int idx = e0; idx < e1; idx++) {
        float4 v = einfo[eid2[idx]];
        float p = v.x, decay = v.y, age = v.z;
        float aged = age / 86400.f;
        bool high = p >= 0.7f;
        bool l30 = age <= 2592000.f;
        sump += p;
        maxp = fmaxf(maxp, p);
        sumpd += p * decay;
        sumd += decay;
        if (high) {
            sumh += 1.f;
            minage = fminf(minage, aged);
        }
        if (l30) {
            sump30 += p;
            suml30 += 1.f;
            maxp30 = fmaxf(maxp30, p);
            if (high) sumh30 += 1.f;
        }
    }
    float* f = feat8 + (long)n * 8;
    f[0] = sump / (cnt + 1e-6f);
    f[1] = maxp;
    f[2] = log1pf(sumh);
    f[3] = sumpd / (sumd + 1e-6f);
    f[4] = log1pf(sumh30);
    f[5] = maxp30;
    f[6] = sump30 / (suml30 + 1e-6f);
    f[7] = log1pf(fminf(fminf(minage, 9999.f), 90.f)) / log1pf(90.f);
}

// ---------------- node classifier ------------------------------------------------------
__global__ __launch_bounds__(256) void k_node_cls(
    const float* __restrict__ ne, const float* __restrict__ feat8,
    const float* __restrict__ w1t /*[64][72]*/, const float* __restrict__ b1,
    const float* __restrict__ gamma, const float* __restrict__ beta,
    const float* __restrict__ mean, const float* __restrict__ var,
    const float* __restrict__ w2, const float* __restrict__ b2,
    float* __restrict__ out) {
    int n = blockIdx.x * blockDim.x + threadIdx.x;
    if (n >= N_NODES) return;
    float in[72];
    const float4* nr = (const float4*)(ne + (long)n * 64);
#pragma unroll
    for (int i = 0; i < 16; i++) {
        float4 v = nr[i];
        in[4 * i] = v.x; in[4 * i + 1] = v.y; in[4 * i + 2] = v.z; in[4 * i + 3] = v.w;
    }
    const float4* fr = (const float4*)(feat8 + (long)n * 8);
    float4 f0 = fr[0], f1 = fr[1];
    in[64] = f0.x; in[65] = f0.y; in[66] = f0.z; in[67] = f0.w;
    in[68] = f1.x; in[69] = f1.y; in[70] = f1.z; in[71] = f1.w;
    float logit = b2[0];
    for (int j = 0; j < 64; j++) {
        float h = b1[j];
        const float* wr = w1t + j * 72;
#pragma unroll
        for (int k = 0; k < 72; k++) h = fmaf(in[k], wr[k], h);
        h = (h - mean[j]) * rsqrtf(var[j] + 1e-5f) * gamma[j] + beta[j];
        h = fmaxf(h, 0.f);
        logit = fmaf(h, w2[j], logit);
    }
    out[n] = logit;
}

// weight transpose: dst[j*kpad + k] = src[k*ldw + j]
__global__ void k_transpose(const float* __restrict__ src, float* __restrict__ dst,
                            int K, int J, int ldw, int kpad) {
    int i = blockIdx.x * blockDim.x + threadIdx.x;
    if (i >= K * J) return;
    int k = i / J, j = i - k * J;
    dst[j * kpad + k] = src[k * ldw + j];
}

extern "C" void kernel_launch(void* const* d_in, const int* in_sizes, int n_in,
                              void* d_out, int out_size, void* d_ws, size_t ws_size,
                              hipStream_t stream) {
    const float* x = (const float*)d_in[0];
    const int* eidx = (const int*)d_in[1];
    const int* src = eidx;
    const int* dst = eidx + N_EDGES;
    const float* la = (const float*)d_in[2];
    const float* tse = (const float*)d_in[3];
    const int* bp = (const int*)d_in[4];
    const int* tt = (const int*)d_in[5];
    const float* cr = (const float*)d_in[6];
    const float* tsp = (const float*)d_in[7];
    const float* tg = (const float*)d_in[8];
    const float* r7 = (const float*)d_in[9];
    const float* r30 = (const float*)d_in[10];
    const int* uts = (const int*)d_in[11];
    const float* tx_emb = (const float*)d_in[12];
    const float* bank_emb = (const float*)d_in[13];
    const float* ee_w1 = (const float*)d_in[14];
    const float* ee_b1 = (const float*)d_in[15];
    const float* ee_w2 = (const float*)d_in[16];
    const float* ee_b2 = (const float*)d_in[17];
    const float* msg1_w = (const float*)d_in[18];
    const float* msg1_b = (const float*)d_in[19];
    const float* upd1_w = (const float*)d_in[20];
    const float* upd1_b = (const float*)d_in[21];
    const float* msg2_w = (const float*)d_in[22];
    const float* msg2_b = (const float*)d_in[23];
    const float* upd2_w = (const float*)d_in[24];
    const float* upd2_b = (const float*)d_in[25];
    const float* ec_w1 = (const float*)d_in[26];
    const float* ec_b1 = (const float*)d_in[27];
    const float* ec_w2 = (const float*)d_in[28];
    const float* ec_b2 = (const float*)d_in[29];
    const float* nc_w1 = (const float*)d_in[30];
    const float* nc_b1 = (const float*)d_in[31];
    const float* bn_g = (const float*)d_in[32];
    const float* bn_b = (const float*)d_in[33];
    const float* bn_m = (const float*)d_in[34];
    const float* bn_v = (const float*)d_in[35];
    const float* nc_w2 = (const float*)d_in[36];
    const float* nc_b2 = (const float*)d_in[37];

    float* out_node = (float*)d_out;              // [N_NODES]
    float* out_edge = (float*)d_out + N_NODES;    // [N_EDGES]

    // workspace layout (floats) — round-6 proven footprint
    float* ws = (float*)d_ws;
    float* ea = ws;                         // E*64
    float* P = ea + (long)N_EDGES * 64;     // N*128 (dead after 2nd msg_seg -> einfo)
    float* s = P + (long)N_NODES * 128;     // N*128 (dead after upd2 gemm -> eid2)
    float* h1 = s + (long)N_NODES * 128;    // N*128
    float* ne = h1 + (long)N_NODES * 128;   // N*64
    float* nS = ne + (long)N_NODES * 64;    // N*64
    float* nD = nS + (long)N_NODES * 64;    // N*64
    float* feat8 = nD + (long)N_NODES * 64; // N*8
    float* w1t = feat8 + (long)N_NODES * 8; // 128*40 (unused now, kept for layout)
    float* Ct = w1t + 128 * 40;             // 64*64
    float* ncw1t = Ct + 64 * 64;            // 64*72
    int* tsmax = (int*)(ncw1t + 64 * 72);   // 1
    int* degi = tsmax + 1;                  // N   (CSR1 by dst)
    int* row_start = degi + N_NODES;        // N+1
    int* cursor = row_start + N_NODES + 1;  // N
    int* eid = cursor + N_NODES;            // E
    int* partials = eid + N_EDGES;          // 256
    int* deg2 = partials + 256;             // N   (CSR2 incidence)
    int* row2 = deg2 + N_NODES;             // N+1
    int* cursor2 = row2 + N_NODES + 1;      // N
    // aliased regions:
    float4* einfo = (float4*)P;             // E float4 (8 MB < P's 25.6 MB)
    int* eid2 = (int*)s;                    // 2E ints (4 MB < s's 25.6 MB)

    const int EB = (N_EDGES + 255) / 256;    // 1954
    const int E2B = (2 * N_EDGES + 255) / 256;
    const int NB = (N_NODES + 255) / 256;    // 196
    const int MB = (N_EDGES + 63) / 64;      // 7813

    // ---- init ----
    hipMemsetAsync(tsmax, 0, 4, stream);
    hipMemsetAsync(degi, 0, (size_t)N_NODES * 4, stream);
    hipMemsetAsync(s, 0, (size_t)N_NODES * 128 * 4, stream);

    // ---- CSR1 build (by dst) ----
    k_deg_count<<<EB, 256, 0, stream>>>(dst, degi, N_EDGES);
    k_block_sums<<<NB, 256, 0, stream>>>(degi, partials, N_NODES);
    k_scan_partials<<<1, 256, 0, stream>>>(partials, NB);
    k_scan_final<<<NB, 256, 0, stream>>>(degi, partials, row_start, N_NODES);
    hipMemcpyAsync(cursor, row_start, (size_t)N_NODES * 4, hipMemcpyDeviceToDevice, stream);
    k_fill_slots<<<EB, 256, 0, stream>>>(dst, cursor, eid);

    // ---- weight transposes ----
    k_transpose<<<(64 * 64 + 255) / 256, 256, 0, stream>>>(ec_w1 + 128 * 64, Ct, 64, 64, 64, 64);
    k_transpose<<<(72 * 64 + 255) / 256, 256, 0, stream>>>(nc_w1, ncw1t, 72, 64, 64, 72);

    // ---- edge encoder (LDS-tiled, buffer union) ----
    k_edge_enc_tiled<<<MB, 256, 0, stream>>>(la, tse, bp, tt, cr, tsp, tg, r7, r30,
                                             tx_emb, bank_emb, ee_w1, ee_b1, ee_w2, ee_b2,
                                             ea, N_EDGES);

    // ---- SAGE layer 1 ----
    k_node_gemm<128, 0, 64, false, false><<<dim3(NB, 2), 256, 0, stream>>>(
        x, 128, nullptr, 0, nullptr, msg1_w, 128, nullptr, P, 128, N_NODES);
    k_msg_seg<<<MB, 256, 0, stream>>>(P, ea, msg1_w + 128 * 128, msg1_b, src, dst, eid, s, N_EDGES);
    k_node_gemm<128, 128, 64, true, true><<<dim3(NB, 2), 256, 0, stream>>>(
        x, 128, s, 128, degi, upd1_w, 128, upd1_b, h1, 128, N_NODES);

    // ---- SAGE layer 2 ----
    k_node_gemm<128, 0, 64, false, false><<<dim3(NB, 2), 256, 0, stream>>>(
        h1, 128, nullptr, 0, nullptr, msg2_w, 128, nullptr, P, 128, N_NODES);
    hipMemsetAsync(s, 0, (size_t)N_NODES * 128 * 4, stream);
    k_msg_seg<<<MB, 256, 0, stream>>>(P, ea, msg2_w + 128 * 128, msg2_b, src, dst, eid, s, N_EDGES);
    k_node_gemm<128, 128, 64, true, true><<<dim3(NB, 1), 256, 0, stream>>>(
        h1, 128, s, 128, degi, upd2_w, 64, upd2_b, ne, 64, N_NODES);
    // s and P are now dead -> eid2 / einfo aliases safe from here on

    // ---- edge classifier prep ----
    k_node_gemm<64, 0, 64, false, false><<<dim3(NB, 1), 256, 0, stream>>>(
        ne, 64, nullptr, 0, nullptr, ec_w1, 64, nullptr, nS, 64, N_NODES);
    k_node_gemm<64, 0, 64, false, false><<<dim3(NB, 1), 256, 0, stream>>>(
        ne, 64, nullptr, 0, nullptr, ec_w1 + 64 * 64, 64, nullptr, nD, 64, N_NODES);

    // ---- CSR2 build (incidence over both endpoints; keys = flat eidx) ----
    hipMemsetAsync(deg2, 0, (size_t)N_NODES * 4, stream);
    k_deg_count<<<E2B, 256, 0, stream>>>(eidx, deg2, 2 * N_EDGES);
    k_block_sums<<<NB, 256, 0, stream>>>(deg2, partials, N_NODES);
    k_scan_partials<<<1, 256, 0, stream>>>(partials, NB);
    k_scan_final<<<NB, 256, 0, stream>>>(deg2, partials, row2, N_NODES);
    hipMemcpyAsync(cursor2, row2, (size_t)N_NODES * 4, hipMemcpyDeviceToDevice, stream);
    k_fill_slots2<<<E2B, 256, 0, stream>>>(eidx, cursor2, eid2);

    // ---- edge classifier (+ einfo pack) ----
    k_tsmax<<<256, 256, 0, stream>>>(uts, tsmax);
    k_edge_cls<<<EB, 256, 0, stream>>>(nS, nD, ea, Ct, ec_b1, ec_w2, ec_b2,
                                       src, dst, uts, tsmax, out_edge, einfo);

    // ---- node aggregation (gather, no atomics) ----
    k_node_agg<<<NB, 256, 0, stream>>>(einfo, row2, eid2, feat8);

    // ---- node classifier ----
    k_node_cls<<<NB, 256, 0, stream>>>(ne, feat8, ncw1t, nc_b1, bn_g, bn_b, bn_m, bn_v,
                                       nc_w2, nc_b2, out_node);
}

// Round 9
// 1401.157 us; speedup vs baseline: 6.0257x; 1.0592x over previous
//
#include <hip/hip_runtime.h>
#include <math.h>

#define N_NODES 50000
#define N_EDGES 500000

// ---------- f16 pair helpers: pack two fp32 into one float-encoded half2; fdot2 ----------
typedef _Float16 h2_t __attribute__((ext_vector_type(2)));
__device__ inline float pk(float a, float b) {
    h2_t h; h[0] = (_Float16)a; h[1] = (_Float16)b;
    float r; __builtin_memcpy(&r, &h, 4); return r;
}
__device__ inline float dot2f(float pa, float pb, float c) {
    h2_t ha, hb; __builtin_memcpy(&ha, &pa, 4); __builtin_memcpy(&hb, &pb, 4);
    return __builtin_amdgcn_fdot2(ha, hb, c, false);
}

// =================== CSR build helpers ====================
__global__ void k_deg_count(const int* __restrict__ keys, int* __restrict__ degi, int n) {
    int e = blockIdx.x * blockDim.x + threadIdx.x;
    if (e < n) atomicAdd(degi + keys[e], 1);
}

__global__ void k_block_sums(const int* __restrict__ deg, int* __restrict__ partials, int n) {
    __shared__ int sm[256];
    int i = blockIdx.x * 256 + threadIdx.x;
    sm[threadIdx.x] = (i < n) ? deg[i] : 0;
    __syncthreads();
    for (int s = 128; s > 0; s >>= 1) {
        if (threadIdx.x < s) sm[threadIdx.x] += sm[threadIdx.x + s];
        __syncthreads();
    }
    if (threadIdx.x == 0) partials[blockIdx.x] = sm[0];
}

__global__ void k_scan_partials(int* partials, int nb) {
    __shared__ int sm[256];
    int v = (threadIdx.x < nb) ? partials[threadIdx.x] : 0;
    sm[threadIdx.x] = v;
    __syncthreads();
    for (int off = 1; off < 256; off <<= 1) {
        int t = (threadIdx.x >= off) ? sm[threadIdx.x - off] : 0;
        __syncthreads();
        sm[threadIdx.x] += t;
        __syncthreads();
    }
    if (threadIdx.x < nb) partials[threadIdx.x] = sm[threadIdx.x] - v;  // exclusive
}

__global__ void k_scan_final(const int* __restrict__ deg, const int* __restrict__ partials,
                             int* __restrict__ row_start, int n) {
    __shared__ int sm[256];
    int i = blockIdx.x * 256 + threadIdx.x;
    int v = (i < n) ? deg[i] : 0;
    sm[threadIdx.x] = v;
    __syncthreads();
    for (int off = 1; off < 256; off <<= 1) {
        int t = (threadIdx.x >= off) ? sm[threadIdx.x - off] : 0;
        __syncthreads();
        sm[threadIdx.x] += t;
        __syncthreads();
    }
    if (i < n) row_start[i] = partials[blockIdx.x] + sm[threadIdx.x] - v;  // exclusive
    if (i == n - 1) row_start[n] = partials[blockIdx.x] + sm[threadIdx.x]; // total
}

__global__ void k_fill_slots(const int* __restrict__ dst, int* __restrict__ cursor,
                             int* __restrict__ eid) {
    int e = blockIdx.x * blockDim.x + threadIdx.x;
    if (e >= N_EDGES) return;
    int pos = atomicAdd(cursor + dst[e], 1);
    eid[pos] = e;
}

__global__ void k_fill_slots2(const int* __restrict__ eidx, int* __restrict__ cursor,
                              int* __restrict__ eid2) {
    int i = blockIdx.x * blockDim.x + threadIdx.x;
    if (i >= 2 * N_EDGES) return;
    int pos = atomicAdd(cursor + eidx[i], 1);
    eid2[pos] = (i < N_EDGES) ? i : (i - N_EDGES);
}

// pack edge-cls weight: Ctp[j*32+k2] = pk(C[2k2][j], C[2k2+1][j]);  C = [64 k][64 j]
__global__ void k_pack_ct(const float* __restrict__ C, float* __restrict__ Ctp) {
    int i = blockIdx.x * 256 + threadIdx.x;
    if (i >= 64 * 32) return;
    int j = i >> 5, k2 = i & 31;
    Ctp[i] = pk(C[(2 * k2) * 64 + j], C[(2 * k2 + 1) * 64 + j]);
}

// ---------------- edge encoder, LDS-tiled, f16-dot2 math ------------------------------
// smem union (8448 floats = 33.8 KB):
//   [0,4096)        W2p  [64 k2][64 j]  packed w2 (persistent)
//   [4096,5376)     Fp   [64][20]       packed feats         } phase A
//   [5376,7936)     W1p  [20 k2][128 j] packed w1            }
//   [4096,8448)     Hp   [64][68]       packed hidden (overlays Fp+W1p)
__global__ __launch_bounds__(256) void k_edge_enc_tiled(
    const float* __restrict__ la, const float* __restrict__ tse,
    const int* __restrict__ bp, const int* __restrict__ tt,
    const float* __restrict__ cr, const float* __restrict__ tsp,
    const float* __restrict__ tg, const float* __restrict__ r7,
    const float* __restrict__ r30,
    const float* __restrict__ tx_emb, const float* __restrict__ bank_emb,
    const float* __restrict__ w1 /*[38][128]*/, const float* __restrict__ eb1,
    const float* __restrict__ w2 /*[128][64]*/, const float* __restrict__ eb2,
    float* __restrict__ ea, int n_edges) {
    __shared__ float smem[8448];
    float* W2p = smem;
    float* Fp = smem + 4096;
    float* W1p = smem + 5376;
    float* Hp = smem + 4096;
    int tid = threadIdx.x;
    int t0 = blockIdx.x * 64;

    // ---- stage W2p: 4096 entries ----
#pragma unroll
    for (int i = 0; i < 16; i++) {
        int idx = tid + 256 * i;
        int k2 = idx >> 6, j = idx & 63;
        W2p[idx] = pk(w2[(2 * k2) * 64 + j], w2[(2 * k2 + 1) * 64 + j]);
    }
    // ---- stage W1p: 2560 entries (k 38,39 zero) ----
#pragma unroll
    for (int i = 0; i < 10; i++) {
        int idx = tid + 256 * i;
        int k2 = idx >> 7, j = idx & 127;
        float a = (2 * k2 < 38) ? w1[(2 * k2) * 128 + j] : 0.f;
        float b = (2 * k2 + 1 < 38) ? w1[(2 * k2 + 1) * 128 + j] : 0.f;
        W1p[idx] = pk(a, b);
    }
    // ---- build packed feats tile ----
    {
        int el = tid & 63, g = tid >> 6;
        int e = t0 + el;
        bool ok = e < n_edges;
        float* Fr = Fp + el * 20;
        if (g == 0) {
            Fr[0] = ok ? pk(la[e], cr[e]) : 0.f;
            Fr[1] = ok ? pk(tsp[e], tg[e]) : 0.f;
            Fr[2] = ok ? pk(r7[e], r30[e]) : 0.f;
            Fr[19] = 0.f;
        } else if (g == 1) {
            float4 a = make_float4(0, 0, 0, 0), b = a;
            if (ok) { a = ((const float4*)(tse + (long)e * 8))[0];
                      b = ((const float4*)(tse + (long)e * 8))[1]; }
            Fr[3] = pk(a.x, a.y); Fr[4] = pk(a.z, a.w);
            Fr[5] = pk(b.x, b.y); Fr[6] = pk(b.z, b.w);
        } else if (g == 2) {
            float4 a = make_float4(0, 0, 0, 0), b = a;
            if (ok) { int txi = tt[e];
                      a = ((const float4*)(tx_emb + (long)txi * 8))[0];
                      b = ((const float4*)(tx_emb + (long)txi * 8))[1]; }
            Fr[7] = pk(a.x, a.y); Fr[8] = pk(a.z, a.w);
            Fr[9] = pk(b.x, b.y); Fr[10] = pk(b.z, b.w);
        } else {
            float4 a = make_float4(0, 0, 0, 0), b = a, c = a, d = a;
            if (ok) {
                int bk0 = bp[e * 2 + 0], bk1 = bp[e * 2 + 1];
                a = ((const float4*)(bank_emb + (long)bk0 * 8))[0];
                b = ((const float4*)(bank_emb + (long)bk0 * 8))[1];
                c = ((const float4*)(bank_emb + (long)bk1 * 8))[0];
                d = ((const float4*)(bank_emb + (long)bk1 * 8))[1];
            }
            Fr[11] = pk(a.x, a.y); Fr[12] = pk(a.z, a.w);
            Fr[13] = pk(b.x, b.y); Fr[14] = pk(b.z, b.w);
            Fr[15] = pk(c.x, c.y); Fr[16] = pk(c.z, c.w);
            Fr[17] = pk(d.x, d.y); Fr[18] = pk(d.z, d.w);
        }
    }
    __syncthreads();

    // ---- GEMM1 (K2=20): acc in registers ----
    int jg1 = tid & 31, eg1 = tid >> 5;
    int j1 = jg1 * 4;
    float acc1[8][4];
#pragma unroll
    for (int el = 0; el < 8; el++)
#pragma unroll
        for (int jj = 0; jj < 4; jj++) acc1[el][jj] = 0.f;
    for (int kq = 0; kq < 5; kq++) {
        float4 wv[4];
#pragma unroll
        for (int kk = 0; kk < 4; kk++)
            wv[kk] = *(const float4*)&W1p[(kq * 4 + kk) * 128 + j1];
#pragma unroll
        for (int el = 0; el < 8; el++) {
            float4 av = *(const float4*)&Fp[(eg1 * 8 + el) * 20 + kq * 4];
            const float* a = (const float*)&av;
#pragma unroll
            for (int jj = 0; jj < 4; jj++) {
                float t = acc1[el][jj];
                t = dot2f(a[0], ((const float*)&wv[0])[jj], t);
                t = dot2f(a[1], ((const float*)&wv[1])[jj], t);
                t = dot2f(a[2], ((const float*)&wv[2])[jj], t);
                t = dot2f(a[3], ((const float*)&wv[3])[jj], t);
                acc1[el][jj] = t;
            }
        }
    }
    __syncthreads();   // Fp/W1p dead; Hp overlays

    // ---- write packed H tile: relu(acc1 + b1) ----
    {
        float4 bv = *(const float4*)(eb1 + j1);
#pragma unroll
        for (int el = 0; el < 8; el++) {
            int row = eg1 * 8 + el;
            float x0 = fmaxf(acc1[el][0] + bv.x, 0.f);
            float x1 = fmaxf(acc1[el][1] + bv.y, 0.f);
            float x2 = fmaxf(acc1[el][2] + bv.z, 0.f);
            float x3 = fmaxf(acc1[el][3] + bv.w, 0.f);
            int c = (tid & 31) * 2;
            Hp[row * 68 + c] = pk(x0, x1);
            Hp[row * 68 + c + 1] = pk(x2, x3);
        }
    }
    __syncthreads();

    // ---- GEMM2 (K2=64): out[64][64] = H @ w2 + b2, 4 edges x 4 outs / thread ----
    {
        int jg = tid & 15, eg = tid >> 4;
        int j0 = jg * 4;
        float acc[4][4];
#pragma unroll
        for (int el = 0; el < 4; el++)
#pragma unroll
            for (int jj = 0; jj < 4; jj++) acc[el][jj] = 0.f;
        for (int kq = 0; kq < 16; kq++) {
            float4 wv[4];
#pragma unroll
            for (int kk = 0; kk < 4; kk++)
                wv[kk] = *(const float4*)&W2p[(kq * 4 + kk) * 64 + j0];
#pragma unroll
            for (int el = 0; el < 4; el++) {
                float4 av = *(const float4*)&Hp[(eg * 4 + el) * 68 + kq * 4];
                const float* a = (const float*)&av;
#pragma unroll
                for (int jj = 0; jj < 4; jj++) {
                    float t = acc[el][jj];
                    t = dot2f(a[0], ((const float*)&wv[0])[jj], t);
                    t = dot2f(a[1], ((const float*)&wv[1])[jj], t);
                    t = dot2f(a[2], ((const float*)&wv[2])[jj], t);
                    t = dot2f(a[3], ((const float*)&wv[3])[jj], t);
                    acc[el][jj] = t;
                }
            }
        }
        float4 bv = *(const float4*)(eb2 + j0);
#pragma unroll
        for (int el = 0; el < 4; el++) {
            int e = t0 + eg * 4 + el;
            if (e >= n_edges) continue;
            float4 o;
            o.x = acc[el][0] + bv.x;
            o.y = acc[el][1] + bv.y;
            o.z = acc[el][2] + bv.z;
            o.w = acc[el][3] + bv.w;
            *((float4*)(ea + (long)e * 64 + j0)) = o;
        }
    }
}

// ---------------- generic node-level GEMM (fp32, unchanged) ----------------------------
template <int K1, int K2, int JC, bool RELU, bool DIV2>
__global__ __launch_bounds__(256) void k_node_gemm(
    const float* __restrict__ in1, int ld1,
    const float* __restrict__ in2, int ld2,
    const int* __restrict__ degi,
    const float* __restrict__ W, int ldw,
    const float* __restrict__ bias,
    float* __restrict__ out, int ldo, int nrows) {
    int n = blockIdx.x * blockDim.x + threadIdx.x;
    if (n >= nrows) return;
    int j0 = blockIdx.y * JC;
    float acc[JC];
#pragma unroll
    for (int j = 0; j < JC; j++) acc[j] = bias ? bias[j0 + j] : 0.f;
    const float* r1 = in1 + (long)n * ld1;
    for (int k = 0; k < K1; k++) {
        float v = r1[k];
        const float* wr = W + (long)k * ldw + j0;
#pragma unroll
        for (int j = 0; j < JC; j++) acc[j] = fmaf(v, wr[j], acc[j]);
    }
    if constexpr (K2 > 0) {
        float dinv = 1.f;
        if constexpr (DIV2) dinv = 1.f / ((float)degi[n] + 1e-6f);
        const float* r2 = in2 + (long)n * ld2;
        for (int k = 0; k < K2; k++) {
            float v = r2[k] * dinv;
            const float* wr = W + (long)(K1 + k) * ldw + j0;
#pragma unroll
            for (int j = 0; j < JC; j++) acc[j] = fmaf(v, wr[j], acc[j]);
        }
    }
    float* orow = out + (long)n * ldo + j0;
#pragma unroll
    for (int j = 0; j < JC; j++) {
        float v = acc[j];
        if (RELU) v = fmaxf(v, 0.f);
        orow[j] = v;
    }
}

// ---------------- fused msg GEMM (f16-dot2) + segmented sum ----------------------------
// smem union (4096 floats... actually 8192 floats = 32 KB):
//   [0,2048)  eap [64][32] packed ea           } k-loop
//   [2048,6144) Wp [32 k2][128 j] packed W     }
//   [0,8192)  M  [64][128] fp32 msg tile (overlays after k-loop)
__global__ __launch_bounds__(256) void k_msg_seg(
    const float* __restrict__ P, const float* __restrict__ ea,
    const float* __restrict__ W /*[64][128]*/, const float* __restrict__ bias,
    const int* __restrict__ src, const int* __restrict__ dst,
    const int* __restrict__ eid,
    float* __restrict__ s, int n_edges) {
    __shared__ float smem[8192];
    float* eap = smem;            // [64][32]
    float* Wp = smem + 2048;      // [32][128]
    float* M = smem;              // [64][128]
    __shared__ int sn_s[64];
    __shared__ int es_s[64];
    __shared__ int nid_s[64];
    __shared__ int bound_s[2];
    int tid = threadIdx.x;
    int t0 = blockIdx.x * 64;

    if (tid < 64) {
        int slot = t0 + tid;
        int e = (slot < n_edges) ? eid[slot] : 0;
        es_s[tid] = e;
        sn_s[tid] = src[e];
        nid_s[tid] = (slot < n_edges) ? dst[e] : -1;
    }
    if (tid == 64) bound_s[0] = (t0 > 0) ? dst[eid[t0 - 1]] : -1;
    if (tid == 65) bound_s[1] = (t0 + 64 < n_edges) ? dst[eid[t0 + 64]] : -1;
    // stage Wp: 4096 entries
#pragma unroll
    for (int i = 0; i < 16; i++) {
        int idx = tid + 256 * i;
        int k2 = idx >> 7, j = idx & 127;
        Wp[idx] = pk(W[(2 * k2) * 128 + j], W[(2 * k2 + 1) * 128 + j]);
    }
    __syncthreads();
    // stage packed ea tile
#pragma unroll
    for (int i = 0; i < 4; i++) {
        int f = tid + 256 * i;
        int el = f >> 4, c = f & 15;
        float4 v = ((const float4*)(ea + (long)es_s[el] * 64))[c];
        eap[el * 32 + c * 2] = pk(v.x, v.y);
        eap[el * 32 + c * 2 + 1] = pk(v.z, v.w);
    }
    __syncthreads();

    int jg = tid & 31;   // j0 = jg*4
    int eg = tid >> 5;   // rows eg*8 .. eg*8+7
    int j0 = jg * 4;
    float acc[8][4];
#pragma unroll
    for (int el = 0; el < 8; el++)
#pragma unroll
        for (int jj = 0; jj < 4; jj++) acc[el][jj] = 0.f;

    for (int kq = 0; kq < 8; kq++) {
        float4 wv[4];
#pragma unroll
        for (int kk = 0; kk < 4; kk++) wv[kk] = *(const float4*)&Wp[(kq * 4 + kk) * 128 + j0];
#pragma unroll
        for (int el = 0; el < 8; el++) {
            float4 av = *(const float4*)&eap[(eg * 8 + el) * 32 + kq * 4];
            const float* a = (const float*)&av;
#pragma unroll
            for (int jj = 0; jj < 4; jj++) {
                float t = acc[el][jj];
                t = dot2f(a[0], ((const float*)&wv[0])[jj], t);
                t = dot2f(a[1], ((const float*)&wv[1])[jj], t);
                t = dot2f(a[2], ((const float*)&wv[2])[jj], t);
                t = dot2f(a[3], ((const float*)&wv[3])[jj], t);
                acc[el][jj] = t;
            }
        }
    }
    __syncthreads();   // eap/Wp dead; M overlays

    float4 bv = *(const float4*)(bias + j0);
#pragma unroll
    for (int el = 0; el < 8; el++) {
        int row = eg * 8 + el;
        float4 pv = *(const float4*)(P + (long)sn_s[row] * 128 + j0);
        float4 o;
        o.x = fmaxf(acc[el][0] + pv.x + bv.x, 0.f);
        o.y = fmaxf(acc[el][1] + pv.y + bv.y, 0.f);
        o.z = fmaxf(acc[el][2] + pv.z + bv.z, 0.f);
        o.w = fmaxf(acc[el][3] + pv.w + bv.w, 0.f);
        *((float4*)&M[row * 128 + j0]) = o;
    }
    __syncthreads();

    if (tid < 128) {
        int c = tid;
        int rows = min(64, n_edges - t0);
        int prev_n = bound_s[0], next_n = bound_s[1];
        int cur = nid_s[0];
        int seg_start = 0;
        float run = 0.f;
        for (int r = 0; r < rows; r++) {
            int nd = nid_s[r];
            if (nd != cur) {
                if (seg_start == 0 && cur == prev_n) atomicAdd(s + (long)cur * 128 + c, run);
                else s[(long)cur * 128 + c] = run;
                cur = nd; seg_start = r; run = 0.f;
            }
            run += M[r * 128 + c];
        }
        if ((seg_start == 0 && cur == prev_n) || cur == next_n)
            atomicAdd(s + (long)cur * 128 + c, run);
        else s[(long)cur * 128 + c] = run;
    }
}

// ---------------- edge classifier (f16-dot2 math) + einfo pack --------------------------
__global__ __launch_bounds__(256) void k_edge_cls(
    const float* __restrict__ nS, const float* __restrict__ nD,
    const float* __restrict__ ea, const float* __restrict__ Ctp /*[64 j][32 k2] packed*/,
    const float* __restrict__ b1, const float* __restrict__ w2, const float* __restrict__ b2,
    const int* __restrict__ src, const int* __restrict__ dst,
    const int* __restrict__ uts, const int* __restrict__ tsmax,
    float* __restrict__ logits_out, float4* __restrict__ einfo) {
    int e = blockIdx.x * blockDim.x + threadIdx.x;
    if (e >= N_EDGES) return;
    int sn = src[e], dn = dst[e];
    float base[64];
    const float4* Sr4 = (const float4*)(nS + (long)sn * 64);
    const float4* Dr4 = (const float4*)(nD + (long)dn * 64);
#pragma unroll
    for (int i = 0; i < 16; i++) {
        float4 sv = Sr4[i];
        float4 dv = Dr4[i];
        base[4 * i + 0] = sv.x + dv.x;
        base[4 * i + 1] = sv.y + dv.y;
        base[4 * i + 2] = sv.z + dv.z;
        base[4 * i + 3] = sv.w + dv.w;
    }
    float ap[32];
    const float4* ar = (const float4*)(ea + (long)e * 64);
#pragma unroll
    for (int i = 0; i < 16; i++) {
        float4 v = ar[i];
        ap[2 * i] = pk(v.x, v.y);
        ap[2 * i + 1] = pk(v.z, v.w);
    }
    float logit = b2[0];
    for (int j = 0; j < 64; j++) {
        float t = b1[j] + base[j];
        const float* wr = Ctp + j * 32;   // wave-uniform -> scalar loads
#pragma unroll
        for (int k2 = 0; k2 < 32; k2++) t = dot2f(ap[k2], wr[k2], t);
        t = fmaxf(t, 0.f);
        logit = fmaf(t, w2[j], logit);
    }
    logits_out[e] = logit;
    float p = 1.f / (1.f + expf(-logit));
    float now = (float)(*tsmax);
    float age = fmaxf(now - (float)uts[e], 0.f);
    float decay = expf(-age / 2592000.f);
    einfo[e] = make_float4(p, decay, age, 0.f);
}

// ---------------- ts max reduction -----------------------------------------------------
__global__ void k_tsmax(const int* __restrict__ ts, int* __restrict__ out) {
    int i = blockIdx.x * blockDim.x + threadIdx.x;
    int stride = gridDim.x * blockDim.x;
    int m = 0;
    for (int t = i; t < N_EDGES; t += stride) m = max(m, ts[t]);
#pragma unroll
    for (int off = 32; off > 0; off >>= 1) m = max(m, __shfl_down(m, off));
    if ((threadIdx.x & 63) == 0) atomicMax(out, m);
}

// ---------------- per-node aggregation over incidence CSR (no atomics) -----------------
__global__ __launch_bounds__(256) void k_node_agg(
    const float4* __restrict__ einfo, const int* __restrict__ row2,
    const int* __restrict__ eid2, float* __restrict__ feat8) {
    int n = blockIdx.x * blockDim.x + threadIdx.x;
    if (n >= N_NODES) return;
    int e0 = row2[n], e1 = row2[n + 1];
    float cnt = (float)(e1 - e0);
    float sump = 0.f, maxp = 0.f, sumh = 0.f, sumpd = 0.f, sumd = 0.f;
    float sumh30 = 0.f, maxp30 = 0.f, sump30 = 0.f, suml30 = 0.f, minage = 9999.f;
    for (int idx = e0; idx < e1; idx++) {
        float4 v = einfo[eid2[idx]];
        float p = v.x, decay = v.y, age = v.z;
        float aged = age / 86400.f;
        bool high = p >= 0.7f;
        bool l30 = age <= 2592000.f;
        sump += p;
        maxp = fmaxf(maxp, p);
        sumpd += p * decay;
        sumd += decay;
        if (high) {
            sumh += 1.f;
            minage = fminf(minage, aged);
        }
        if (l30) {
            sump30 += p;
            suml30 += 1.f;
            maxp30 = fmaxf(maxp30, p);
            if (high) sumh30 += 1.f;
        }
    }
    float* f = feat8 + (long)n * 8;
    f[0] = sump / (cnt + 1e-6f);
    f[1] = maxp;
    f[2] = log1pf(sumh);
    f[3] = sumpd / (sumd + 1e-6f);
    f[4] = log1pf(sumh30);
    f[5] = maxp30;
    f[6] = sump30 / (suml30 + 1e-6f);
    f[7] = log1pf(fminf(fminf(minage, 9999.f), 90.f)) / log1pf(90.f);
}

// ---------------- node classifier ------------------------------------------------------
__global__ __launch_bounds__(256) void k_node_cls(
    const float* __restrict__ ne, const float* __restrict__ feat8,
    const float* __restrict__ w1t /*[64][72]*/, const float* __restrict__ b1,
    const float* __restrict__ gamma, const float* __restrict__ beta,
    const float* __restrict__ mean, const float* __restrict__ var,
    const float* __restrict__ w2, const float* __restrict__ b2,
    float* __restrict__ out) {
    int n = blockIdx.x * blockDim.x + threadIdx.x;
    if (n >= N_NODES) return;
    float in[72];
    const float4* nr = (const float4*)(ne + (long)n * 64);
#pragma unroll
    for (int i = 0; i < 16; i++) {
        float4 v = nr[i];
        in[4 * i] = v.x; in[4 * i + 1] = v.y; in[4 * i + 2] = v.z; in[4 * i + 3] = v.w;
    }
    const float4* fr = (const float4*)(feat8 + (long)n * 8);
    float4 f0 = fr[0], f1 = fr[1];
    in[64] = f0.x; in[65] = f0.y; in[66] = f0.z; in[67] = f0.w;
    in[68] = f1.x; in[69] = f1.y; in[70] = f1.z; in[71] = f1.w;
    float logit = b2[0];
    for (int j = 0; j < 64; j++) {
        float h = b1[j];
        const float* wr = w1t + j * 72;
#pragma unroll
        for (int k = 0; k < 72; k++) h = fmaf(in[k], wr[k], h);
        h = (h - mean[j]) * rsqrtf(var[j] + 1e-5f) * gamma[j] + beta[j];
        h = fmaxf(h, 0.f);
        logit = fmaf(h, w2[j], logit);
    }
    out[n] = logit;
}

// weight transpose: dst[j*kpad + k] = src[k*ldw + j]
__global__ void k_transpose(const float* __restrict__ src, float* __restrict__ dst,
                            int K, int J, int ldw, int kpad) {
    int i = blockIdx.x * blockDim.x + threadIdx.x;
    if (i >= K * J) return;
    int k = i / J, j = i - k * J;
    dst[j * kpad + k] = src[k * ldw + j];
}

extern "C" void kernel_launch(void* const* d_in, const int* in_sizes, int n_in,
                              void* d_out, int out_size, void* d_ws, size_t ws_size,
                              hipStream_t stream) {
    const float* x = (const float*)d_in[0];
    const int* eidx = (const int*)d_in[1];
    const int* src = eidx;
    const int* dst = eidx + N_EDGES;
    const float* la = (const float*)d_in[2];
    const float* tse = (const float*)d_in[3];
    const int* bp = (const int*)d_in[4];
    const int* tt = (const int*)d_in[5];
    const float* cr = (const float*)d_in[6];
    const float* tsp = (const float*)d_in[7];
    const float* tg = (const float*)d_in[8];
    const float* r7 = (const float*)d_in[9];
    const float* r30 = (const float*)d_in[10];
    const int* uts = (const int*)d_in[11];
    const float* tx_emb = (const float*)d_in[12];
    const float* bank_emb = (const float*)d_in[13];
    const float* ee_w1 = (const float*)d_in[14];
    const float* ee_b1 = (const float*)d_in[15];
    const float* ee_w2 = (const float*)d_in[16];
    const float* ee_b2 = (const float*)d_in[17];
    const float* msg1_w = (const float*)d_in[18];
    const float* msg1_b = (const float*)d_in[19];
    const float* upd1_w = (const float*)d_in[20];
    const float* upd1_b = (const float*)d_in[21];
    const float* msg2_w = (const float*)d_in[22];
    const float* msg2_b = (const float*)d_in[23];
    const float* upd2_w = (const float*)d_in[24];
    const float* upd2_b = (const float*)d_in[25];
    const float* ec_w1 = (const float*)d_in[26];
    const float* ec_b1 = (const float*)d_in[27];
    const float* ec_w2 = (const float*)d_in[28];
    const float* ec_b2 = (const float*)d_in[29];
    const float* nc_w1 = (const float*)d_in[30];
    const float* nc_b1 = (const float*)d_in[31];
    const float* bn_g = (const float*)d_in[32];
    const float* bn_b = (const float*)d_in[33];
    const float* bn_m = (const float*)d_in[34];
    const float* bn_v = (const float*)d_in[35];
    const float* nc_w2 = (const float*)d_in[36];
    const float* nc_b2 = (const float*)d_in[37];

    float* out_node = (float*)d_out;              // [N_NODES]
    float* out_edge = (float*)d_out + N_NODES;    // [N_EDGES]

    // workspace layout (floats) — round-6 proven footprint
    float* ws = (float*)d_ws;
    float* ea = ws;                         // E*64
    float* P = ea + (long)N_EDGES * 64;     // N*128 (dead after 2nd msg_seg -> einfo)
    float* s = P + (long)N_NODES * 128;     // N*128 (dead after upd2 gemm -> eid2)
    float* h1 = s + (long)N_NODES * 128;    // N*128
    float* ne = h1 + (long)N_NODES * 128;   // N*64
    float* nS = ne + (long)N_NODES * 64;    // N*64
    float* nD = nS + (long)N_NODES * 64;    // N*64
    float* feat8 = nD + (long)N_NODES * 64; // N*8
    float* w1t = feat8 + (long)N_NODES * 8; // 128*40 (spare)
    float* Ctp = w1t + 128 * 40;            // 64*32 packed (region holds 64*64)
    float* ncw1t = Ctp + 64 * 64;           // 64*72
    int* tsmax = (int*)(ncw1t + 64 * 72);   // 1
    int* degi = tsmax + 1;                  // N   (CSR1 by dst)
    int* row_start = degi + N_NODES;        // N+1
    int* cursor = row_start + N_NODES + 1;  // N
    int* eid = cursor + N_NODES;            // E
    int* partials = eid + N_EDGES;          // 256
    int* deg2 = partials + 256;             // N   (CSR2 incidence)
    int* row2 = deg2 + N_NODES;             // N+1
    int* cursor2 = row2 + N_NODES + 1;      // N
    // aliased regions:
    float4* einfo = (float4*)P;             // E float4 (8 MB < P's 25.6 MB)
    int* eid2 = (int*)s;                    // 2E ints (4 MB < s's 25.6 MB)

    const int EB = (N_EDGES + 255) / 256;    // 1954
    const int E2B = (2 * N_EDGES + 255) / 256;
    const int NB = (N_NODES + 255) / 256;    // 196
    const int MB = (N_EDGES + 63) / 64;      // 7813

    // ---- init ----
    hipMemsetAsync(tsmax, 0, 4, stream);
    hipMemsetAsync(degi, 0, (size_t)N_NODES * 4, stream);
    hipMemsetAsync(s, 0, (size_t)N_NODES * 128 * 4, stream);

    // ---- CSR1 build (by dst) ----
    k_deg_count<<<EB, 256, 0, stream>>>(dst, degi, N_EDGES);
    k_block_sums<<<NB, 256, 0, stream>>>(degi, partials, N_NODES);
    k_scan_partials<<<1, 256, 0, stream>>>(partials, NB);
    k_scan_final<<<NB, 256, 0, stream>>>(degi, partials, row_start, N_NODES);
    hipMemcpyAsync(cursor, row_start, (size_t)N_NODES * 4, hipMemcpyDeviceToDevice, stream);
    k_fill_slots<<<EB, 256, 0, stream>>>(dst, cursor, eid);

    // ---- weight prep ----
    k_pack_ct<<<8, 256, 0, stream>>>(ec_w1 + 128 * 64, Ctp);
    k_transpose<<<(72 * 64 + 255) / 256, 256, 0, stream>>>(nc_w1, ncw1t, 72, 64, 64, 72);

    // ---- edge encoder (LDS-tiled, f16 dot2) ----
    k_edge_enc_tiled<<<MB, 256, 0, stream>>>(la, tse, bp, tt, cr, tsp, tg, r7, r30,
                                             tx_emb, bank_emb, ee_w1, ee_b1, ee_w2, ee_b2,
                                             ea, N_EDGES);

    // ---- SAGE layer 1 ----
    k_node_gemm<128, 0, 64, false, false><<<dim3(NB, 2), 256, 0, stream>>>(
        x, 128, nullptr, 0, nullptr, msg1_w, 128, nullptr, P, 128, N_NODES);
    k_msg_seg<<<MB, 256, 0, stream>>>(P, ea, msg1_w + 128 * 128, msg1_b, src, dst, eid, s, N_EDGES);
    k_node_gemm<128, 128, 64, true, true><<<dim3(NB, 2), 256, 0, stream>>>(
        x, 128, s, 128, degi, upd1_w, 128, upd1_b, h1, 128, N_NODES);

    // ---- SAGE layer 2 ----
    k_node_gemm<128, 0, 64, false, false><<<dim3(NB, 2), 256, 0, stream>>>(
        h1, 128, nullptr, 0, nullptr, msg2_w, 128, nullptr, P, 128, N_NODES);
    hipMemsetAsync(s, 0, (size_t)N_NODES * 128 * 4, stream);
    k_msg_seg<<<MB, 256, 0, stream>>>(P, ea, msg2_w + 128 * 128, msg2_b, src, dst, eid, s, N_EDGES);
    k_node_gemm<128, 128, 64, true, true><<<dim3(NB, 1), 256, 0, stream>>>(
        h1, 128, s, 128, degi, upd2_w, 64, upd2_b, ne, 64, N_NODES);
    // s and P are now dead -> eid2 / einfo aliases safe from here on

    // ---- edge classifier prep ----
    k_node_gemm<64, 0, 64, false, false><<<dim3(NB, 1), 256, 0, stream>>>(
        ne, 64, nullptr, 0, nullptr, ec_w1, 64, nullptr, nS, 64, N_NODES);
    k_node_gemm<64, 0, 64, false, false><<<dim3(NB, 1), 256, 0, stream>>>(
        ne, 64, nullptr, 0, nullptr, ec_w1 + 64 * 64, 64, nullptr, nD, 64, N_NODES);

    // ---- CSR2 build (incidence over both endpoints; keys = flat eidx) ----
    hipMemsetAsync(deg2, 0, (size_t)N_NODES * 4, stream);
    k_deg_count<<<E2B, 256, 0, stream>>>(eidx, deg2, 2 * N_EDGES);
    k_block_sums<<<NB, 256, 0, stream>>>(deg2, partials, N_NODES);
    k_scan_partials<<<1, 256, 0, stream>>>(partials, NB);
    k_scan_final<<<NB, 256, 0, stream>>>(deg2, partials, row2, N_NODES);
    hipMemcpyAsync(cursor2, row2, (size_t)N_NODES * 4, hipMemcpyDeviceToDevice, stream);
    k_fill_slots2<<<E2B, 256, 0, stream>>>(eidx, cursor2, eid2);

    // ---- edge classifier (+ einfo pack) ----
    k_tsmax<<<256, 256, 0, stream>>>(uts, tsmax);
    k_edge_cls<<<EB, 256, 0, stream>>>(nS, nD, ea, Ctp, ec_b1, ec_w2, ec_b2,
                                       src, dst, uts, tsmax, out_edge, einfo);

    // ---- node aggregation (gather, no atomics) ----
    k_node_agg<<<NB, 256, 0, stream>>>(einfo, row2, eid2, feat8);

    // ---- node classifier ----
    k_node_cls<<<NB, 256, 0, stream>>>(ne, feat8, ncw1t, nc_b1, bn_g, bn_b, bn_m, bn_v,
                                       nc_w2, nc_b2, out_node);
}

// Round 10
// 1337.117 us; speedup vs baseline: 6.3143x; 1.0479x over previous
//
#include <hip/hip_runtime.h>
#include <math.h>

#define N_NODES 50000
#define N_EDGES 500000

// ---------- f16 pair helpers ----------
typedef _Float16 h2_t __attribute__((ext_vector_type(2)));
__device__ inline float pk(float a, float b) {
    h2_t h; h[0] = (_Float16)a; h[1] = (_Float16)b;
    float r; __builtin_memcpy(&r, &h, 4); return r;
}
__device__ inline float2 upk(float p) {
    h2_t h; __builtin_memcpy(&h, &p, 4);
    return make_float2((float)h[0], (float)h[1]);
}
__device__ inline float dot2f(float pa, float pb, float c) {
    h2_t ha, hb; __builtin_memcpy(&ha, &pa, 4); __builtin_memcpy(&hb, &pb, 4);
    return __builtin_amdgcn_fdot2(ha, hb, c, false);
}

// =================== CSR build helpers ====================
__global__ void k_deg_count(const int* __restrict__ keys, int* __restrict__ degi, int n) {
    int e = blockIdx.x * blockDim.x + threadIdx.x;
    if (e < n) atomicAdd(degi + keys[e], 1);
}

__global__ void k_block_sums(const int* __restrict__ deg, int* __restrict__ partials, int n) {
    __shared__ int sm[256];
    int i = blockIdx.x * 256 + threadIdx.x;
    sm[threadIdx.x] = (i < n) ? deg[i] : 0;
    __syncthreads();
    for (int s = 128; s > 0; s >>= 1) {
        if (threadIdx.x < s) sm[threadIdx.x] += sm[threadIdx.x + s];
        __syncthreads();
    }
    if (threadIdx.x == 0) partials[blockIdx.x] = sm[0];
}

__global__ void k_scan_partials(int* partials, int nb) {
    __shared__ int sm[256];
    int v = (threadIdx.x < nb) ? partials[threadIdx.x] : 0;
    sm[threadIdx.x] = v;
    __syncthreads();
    for (int off = 1; off < 256; off <<= 1) {
        int t = (threadIdx.x >= off) ? sm[threadIdx.x - off] : 0;
        __syncthreads();
        sm[threadIdx.x] += t;
        __syncthreads();
    }
    if (threadIdx.x < nb) partials[threadIdx.x] = sm[threadIdx.x] - v;  // exclusive
}

__global__ void k_scan_final(const int* __restrict__ deg, const int* __restrict__ partials,
                             int* __restrict__ row_start, int n) {
    __shared__ int sm[256];
    int i = blockIdx.x * 256 + threadIdx.x;
    int v = (i < n) ? deg[i] : 0;
    sm[threadIdx.x] = v;
    __syncthreads();
    for (int off = 1; off < 256; off <<= 1) {
        int t = (threadIdx.x >= off) ? sm[threadIdx.x - off] : 0;
        __syncthreads();
        sm[threadIdx.x] += t;
        __syncthreads();
    }
    if (i < n) row_start[i] = partials[blockIdx.x] + sm[threadIdx.x] - v;  // exclusive
    if (i == n - 1) row_start[n] = partials[blockIdx.x] + sm[threadIdx.x]; // total
}

__global__ void k_fill_slots(const int* __restrict__ dst, int* __restrict__ cursor,
                             int* __restrict__ eid) {
    int e = blockIdx.x * blockDim.x + threadIdx.x;
    if (e >= N_EDGES) return;
    int pos = atomicAdd(cursor + dst[e], 1);
    eid[pos] = e;
}

__global__ void k_fill_slots2(const int* __restrict__ eidx, int* __restrict__ cursor,
                              int* __restrict__ eid2) {
    int i = blockIdx.x * blockDim.x + threadIdx.x;
    if (i >= 2 * N_EDGES) return;
    int pos = atomicAdd(cursor + eidx[i], 1);
    eid2[pos] = (i < N_EDGES) ? i : (i - N_EDGES);
}

// pack edge-cls weight: Ctp[j*32+k2] = pk(C[2k2][j], C[2k2+1][j]);  C = [64 k][64 j]
__global__ void k_pack_ct(const float* __restrict__ C, float* __restrict__ Ctp) {
    int i = blockIdx.x * 256 + threadIdx.x;
    if (i >= 64 * 32) return;
    int j = i >> 5, k2 = i & 31;
    Ctp[i] = pk(C[(2 * k2) * 64 + j], C[(2 * k2 + 1) * 64 + j]);
}

// ---------------- edge encoder, LDS-tiled, f16-dot2, packed-f16 ea output --------------
__global__ __launch_bounds__(256) void k_edge_enc_tiled(
    const float* __restrict__ la, const float* __restrict__ tse,
    const int* __restrict__ bp, const int* __restrict__ tt,
    const float* __restrict__ cr, const float* __restrict__ tsp,
    const float* __restrict__ tg, const float* __restrict__ r7,
    const float* __restrict__ r30,
    const float* __restrict__ tx_emb, const float* __restrict__ bank_emb,
    const float* __restrict__ w1 /*[38][128]*/, const float* __restrict__ eb1,
    const float* __restrict__ w2 /*[128][64]*/, const float* __restrict__ eb2,
    float* __restrict__ eap_g /*E x 32 packed*/, int n_edges) {
    __shared__ float smem[8448];
    float* W2p = smem;            // [64 k2][64 j]
    float* Fp = smem + 4096;      // [64][20]
    float* W1p = smem + 5376;     // [20 k2][128 j]
    float* Hp = smem + 4096;      // [64][68] (overlays Fp+W1p)
    int tid = threadIdx.x;
    int t0 = blockIdx.x * 64;

#pragma unroll
    for (int i = 0; i < 16; i++) {
        int idx = tid + 256 * i;
        int k2 = idx >> 6, j = idx & 63;
        W2p[idx] = pk(w2[(2 * k2) * 64 + j], w2[(2 * k2 + 1) * 64 + j]);
    }
#pragma unroll
    for (int i = 0; i < 10; i++) {
        int idx = tid + 256 * i;
        int k2 = idx >> 7, j = idx & 127;
        float a = (2 * k2 < 38) ? w1[(2 * k2) * 128 + j] : 0.f;
        float b = (2 * k2 + 1 < 38) ? w1[(2 * k2 + 1) * 128 + j] : 0.f;
        W1p[idx] = pk(a, b);
    }
    {
        int el = tid & 63, g = tid >> 6;
        int e = t0 + el;
        bool ok = e < n_edges;
        float* Fr = Fp + el * 20;
        if (g == 0) {
            Fr[0] = ok ? pk(la[e], cr[e]) : 0.f;
            Fr[1] = ok ? pk(tsp[e], tg[e]) : 0.f;
            Fr[2] = ok ? pk(r7[e], r30[e]) : 0.f;
            Fr[19] = 0.f;
        } else if (g == 1) {
            float4 a = make_float4(0, 0, 0, 0), b = a;
            if (ok) { a = ((const float4*)(tse + (long)e * 8))[0];
                      b = ((const float4*)(tse + (long)e * 8))[1]; }
            Fr[3] = pk(a.x, a.y); Fr[4] = pk(a.z, a.w);
            Fr[5] = pk(b.x, b.y); Fr[6] = pk(b.z, b.w);
        } else if (g == 2) {
            float4 a = make_float4(0, 0, 0, 0), b = a;
            if (ok) { int txi = tt[e];
                      a = ((const float4*)(tx_emb + (long)txi * 8))[0];
                      b = ((const float4*)(tx_emb + (long)txi * 8))[1]; }
            Fr[7] = pk(a.x, a.y); Fr[8] = pk(a.z, a.w);
            Fr[9] = pk(b.x, b.y); Fr[10] = pk(b.z, b.w);
        } else {
            float4 a = make_float4(0, 0, 0, 0), b = a, c = a, d = a;
            if (ok) {
                int bk0 = bp[e * 2 + 0], bk1 = bp[e * 2 + 1];
                a = ((const float4*)(bank_emb + (long)bk0 * 8))[0];
                b = ((const float4*)(bank_emb + (long)bk0 * 8))[1];
                c = ((const float4*)(bank_emb + (long)bk1 * 8))[0];
                d = ((const float4*)(bank_emb + (long)bk1 * 8))[1];
            }
            Fr[11] = pk(a.x, a.y); Fr[12] = pk(a.z, a.w);
            Fr[13] = pk(b.x, b.y); Fr[14] = pk(b.z, b.w);
            Fr[15] = pk(c.x, c.y); Fr[16] = pk(c.z, c.w);
            Fr[17] = pk(d.x, d.y); Fr[18] = pk(d.z, d.w);
        }
    }
    __syncthreads();

    // GEMM1 (K2=20)
    int jg1 = tid & 31, eg1 = tid >> 5;
    int j1 = jg1 * 4;
    float acc1[8][4];
#pragma unroll
    for (int el = 0; el < 8; el++)
#pragma unroll
        for (int jj = 0; jj < 4; jj++) acc1[el][jj] = 0.f;
    for (int kq = 0; kq < 5; kq++) {
        float4 wv[4];
#pragma unroll
        for (int kk = 0; kk < 4; kk++)
            wv[kk] = *(const float4*)&W1p[(kq * 4 + kk) * 128 + j1];
#pragma unroll
        for (int el = 0; el < 8; el++) {
            float4 av = *(const float4*)&Fp[(eg1 * 8 + el) * 20 + kq * 4];
            const float* a = (const float*)&av;
#pragma unroll
            for (int jj = 0; jj < 4; jj++) {
                float t = acc1[el][jj];
                t = dot2f(a[0], ((const float*)&wv[0])[jj], t);
                t = dot2f(a[1], ((const float*)&wv[1])[jj], t);
                t = dot2f(a[2], ((const float*)&wv[2])[jj], t);
                t = dot2f(a[3], ((const float*)&wv[3])[jj], t);
                acc1[el][jj] = t;
            }
        }
    }
    __syncthreads();

    {
        float4 bv = *(const float4*)(eb1 + j1);
#pragma unroll
        for (int el = 0; el < 8; el++) {
            int row = eg1 * 8 + el;
            float x0 = fmaxf(acc1[el][0] + bv.x, 0.f);
            float x1 = fmaxf(acc1[el][1] + bv.y, 0.f);
            float x2 = fmaxf(acc1[el][2] + bv.z, 0.f);
            float x3 = fmaxf(acc1[el][3] + bv.w, 0.f);
            int c = (tid & 31) * 2;
            Hp[row * 68 + c] = pk(x0, x1);
            Hp[row * 68 + c + 1] = pk(x2, x3);
        }
    }
    __syncthreads();

    // GEMM2 (K2=64) -> packed f16 ea
    {
        int jg = tid & 15, eg = tid >> 4;
        int j0 = jg * 4;
        float acc[4][4];
#pragma unroll
        for (int el = 0; el < 4; el++)
#pragma unroll
            for (int jj = 0; jj < 4; jj++) acc[el][jj] = 0.f;
        for (int kq = 0; kq < 16; kq++) {
            float4 wv[4];
#pragma unroll
            for (int kk = 0; kk < 4; kk++)
                wv[kk] = *(const float4*)&W2p[(kq * 4 + kk) * 64 + j0];
#pragma unroll
            for (int el = 0; el < 4; el++) {
                float4 av = *(const float4*)&Hp[(eg * 4 + el) * 68 + kq * 4];
                const float* a = (const float*)&av;
#pragma unroll
                for (int jj = 0; jj < 4; jj++) {
                    float t = acc[el][jj];
                    t = dot2f(a[0], ((const float*)&wv[0])[jj], t);
                    t = dot2f(a[1], ((const float*)&wv[1])[jj], t);
                    t = dot2f(a[2], ((const float*)&wv[2])[jj], t);
                    t = dot2f(a[3], ((const float*)&wv[3])[jj], t);
                    acc[el][jj] = t;
                }
            }
        }
        float4 bv = *(const float4*)(eb2 + j0);
#pragma unroll
        for (int el = 0; el < 4; el++) {
            int e = t0 + eg * 4 + el;
            if (e >= n_edges) continue;
            float2 o;
            o.x = pk(acc[el][0] + bv.x, acc[el][1] + bv.y);
            o.y = pk(acc[el][2] + bv.z, acc[el][3] + bv.w);
            *((float2*)(eap_g + (long)e * 32 + (j0 >> 1))) = o;
        }
    }
}

// ---------------- generic node-level GEMM (fp32; optional packed-f16 output) -----------
template <int K1, int K2, int JC, bool RELU, bool DIV2, bool PACKOUT>
__global__ __launch_bounds__(256) void k_node_gemm(
    const float* __restrict__ in1, int ld1,
    const float* __restrict__ in2, int ld2,
    const int* __restrict__ degi,
    const float* __restrict__ W, int ldw,
    const float* __restrict__ bias,
    float* __restrict__ out, int ldo, int nrows) {
    int n = blockIdx.x * blockDim.x + threadIdx.x;
    if (n >= nrows) return;
    int j0 = blockIdx.y * JC;
    float acc[JC];
#pragma unroll
    for (int j = 0; j < JC; j++) acc[j] = bias ? bias[j0 + j] : 0.f;
    const float* r1 = in1 + (long)n * ld1;
    for (int k = 0; k < K1; k++) {
        float v = r1[k];
        const float* wr = W + (long)k * ldw + j0;
#pragma unroll
        for (int j = 0; j < JC; j++) acc[j] = fmaf(v, wr[j], acc[j]);
    }
    if constexpr (K2 > 0) {
        float dinv = 1.f;
        if constexpr (DIV2) dinv = 1.f / ((float)degi[n] + 1e-6f);
        const float* r2 = in2 + (long)n * ld2;
        for (int k = 0; k < K2; k++) {
            float v = r2[k] * dinv;
            const float* wr = W + (long)(K1 + k) * ldw + j0;
#pragma unroll
            for (int j = 0; j < JC; j++) acc[j] = fmaf(v, wr[j], acc[j]);
        }
    }
    if constexpr (PACKOUT) {
        float* orow = out + (long)n * ldo + (j0 >> 1);
#pragma unroll
        for (int j2 = 0; j2 < JC / 2; j2++) {
            float a = acc[2 * j2], b = acc[2 * j2 + 1];
            if (RELU) { a = fmaxf(a, 0.f); b = fmaxf(b, 0.f); }
            orow[j2] = pk(a, b);
        }
    } else {
        float* orow = out + (long)n * ldo + j0;
#pragma unroll
        for (int j = 0; j < JC; j++) {
            float v = acc[j];
            if (RELU) v = fmaxf(v, 0.f);
            orow[j] = v;
        }
    }
}

// ---------------- fused msg GEMM (f16-dot2, packed ea input) + segmented sum -----------
__global__ __launch_bounds__(256) void k_msg_seg(
    const float* __restrict__ P, const float* __restrict__ eap_g /*E x 32 packed*/,
    const float* __restrict__ W /*[64][128]*/, const float* __restrict__ bias,
    const int* __restrict__ src, const int* __restrict__ dst,
    const int* __restrict__ eid,
    float* __restrict__ s, int n_edges) {
    __shared__ float smem[8192];
    float* eap = smem;            // [64][32]
    float* Wp = smem + 2048;      // [32][128]
    float* M = smem;              // [64][128] overlays
    __shared__ int sn_s[64];
    __shared__ int es_s[64];
    __shared__ int nid_s[64];
    __shared__ int bound_s[2];
    int tid = threadIdx.x;
    int t0 = blockIdx.x * 64;

    if (tid < 64) {
        int slot = t0 + tid;
        int e = (slot < n_edges) ? eid[slot] : 0;
        es_s[tid] = e;
        sn_s[tid] = src[e];
        nid_s[tid] = (slot < n_edges) ? dst[e] : -1;
    }
    if (tid == 64) bound_s[0] = (t0 > 0) ? dst[eid[t0 - 1]] : -1;
    if (tid == 65) bound_s[1] = (t0 + 64 < n_edges) ? dst[eid[t0 + 64]] : -1;
#pragma unroll
    for (int i = 0; i < 16; i++) {
        int idx = tid + 256 * i;
        int k2 = idx >> 7, j = idx & 127;
        Wp[idx] = pk(W[(2 * k2) * 128 + j], W[(2 * k2 + 1) * 128 + j]);
    }
    __syncthreads();
    // stage packed ea tile: 64 rows x 8 float4 = 512 float4
#pragma unroll
    for (int i = 0; i < 2; i++) {
        int f = tid + 256 * i;
        int el = f >> 3, c = f & 7;
        float4 v = ((const float4*)(eap_g + (long)es_s[el] * 32))[c];
        *((float4*)&eap[el * 32 + c * 4]) = v;
    }
    __syncthreads();

    int jg = tid & 31;
    int eg = tid >> 5;
    int j0 = jg * 4;
    float acc[8][4];
#pragma unroll
    for (int el = 0; el < 8; el++)
#pragma unroll
        for (int jj = 0; jj < 4; jj++) acc[el][jj] = 0.f;

    for (int kq = 0; kq < 8; kq++) {
        float4 wv[4];
#pragma unroll
        for (int kk = 0; kk < 4; kk++) wv[kk] = *(const float4*)&Wp[(kq * 4 + kk) * 128 + j0];
#pragma unroll
        for (int el = 0; el < 8; el++) {
            float4 av = *(const float4*)&eap[(eg * 8 + el) * 32 + kq * 4];
            const float* a = (const float*)&av;
#pragma unroll
            for (int jj = 0; jj < 4; jj++) {
                float t = acc[el][jj];
                t = dot2f(a[0], ((const float*)&wv[0])[jj], t);
                t = dot2f(a[1], ((const float*)&wv[1])[jj], t);
                t = dot2f(a[2], ((const float*)&wv[2])[jj], t);
                t = dot2f(a[3], ((const float*)&wv[3])[jj], t);
                acc[el][jj] = t;
            }
        }
    }
    __syncthreads();

    float4 bv = *(const float4*)(bias + j0);
#pragma unroll
    for (int el = 0; el < 8; el++) {
        int row = eg * 8 + el;
        float4 pv = *(const float4*)(P + (long)sn_s[row] * 128 + j0);
        float4 o;
        o.x = fmaxf(acc[el][0] + pv.x + bv.x, 0.f);
        o.y = fmaxf(acc[el][1] + pv.y + bv.y, 0.f);
        o.z = fmaxf(acc[el][2] + pv.z + bv.z, 0.f);
        o.w = fmaxf(acc[el][3] + pv.w + bv.w, 0.f);
        *((float4*)&M[row * 128 + j0]) = o;
    }
    __syncthreads();

    if (tid < 128) {
        int c = tid;
        int rows = min(64, n_edges - t0);
        int prev_n = bound_s[0], next_n = bound_s[1];
        int cur = nid_s[0];
        int seg_start = 0;
        float run = 0.f;
        for (int r = 0; r < rows; r++) {
            int nd = nid_s[r];
            if (nd != cur) {
                if (seg_start == 0 && cur == prev_n) atomicAdd(s + (long)cur * 128 + c, run);
                else s[(long)cur * 128 + c] = run;
                cur = nd; seg_start = r; run = 0.f;
            }
            run += M[r * 128 + c];
        }
        if ((seg_start == 0 && cur == prev_n) || cur == next_n)
            atomicAdd(s + (long)cur * 128 + c, run);
        else s[(long)cur * 128 + c] = run;
    }
}

// ---------------- edge classifier: packed-f16 gathers, f16-dot2 math -------------------
__global__ __launch_bounds__(256) void k_edge_cls(
    const float* __restrict__ nSp /*N x 32 packed*/, const float* __restrict__ nDp,
    const float* __restrict__ eap_g /*E x 32 packed*/,
    const float* __restrict__ Ctp /*[64 j][32 k2] packed*/,
    const float* __restrict__ b1, const float* __restrict__ w2, const float* __restrict__ b2,
    const int* __restrict__ src, const int* __restrict__ dst,
    const int* __restrict__ uts, const int* __restrict__ tsmax,
    float* __restrict__ logits_out, float4* __restrict__ einfo) {
    int e = blockIdx.x * blockDim.x + threadIdx.x;
    if (e >= N_EDGES) return;
    int sn = src[e], dn = dst[e];
    float base[64];
    const float4* Sp4 = (const float4*)(nSp + (long)sn * 32);
    const float4* Dp4 = (const float4*)(nDp + (long)dn * 32);
#pragma unroll
    for (int i = 0; i < 8; i++) {
        float4 sv = Sp4[i];
        float4 dv = Dp4[i];
        const float* sp = (const float*)&sv;
        const float* dp = (const float*)&dv;
#pragma unroll
        for (int q = 0; q < 4; q++) {
            float2 su = upk(sp[q]), du = upk(dp[q]);
            base[8 * i + 2 * q + 0] = su.x + du.x;
            base[8 * i + 2 * q + 1] = su.y + du.y;
        }
    }
    float ap[32];
    const float4* ar = (const float4*)(eap_g + (long)e * 32);
#pragma unroll
    for (int i = 0; i < 8; i++) {
        float4 v = ar[i];
        ap[4 * i] = v.x; ap[4 * i + 1] = v.y; ap[4 * i + 2] = v.z; ap[4 * i + 3] = v.w;
    }
    float logit = b2[0];
    for (int j = 0; j < 64; j++) {
        float t = b1[j] + base[j];
        const float* wr = Ctp + j * 32;   // wave-uniform -> scalar loads
#pragma unroll
        for (int k2 = 0; k2 < 32; k2++) t = dot2f(ap[k2], wr[k2], t);
        t = fmaxf(t, 0.f);
        logit = fmaf(t, w2[j], logit);
    }
    logits_out[e] = logit;
    float p = 1.f / (1.f + expf(-logit));
    float now = (float)(*tsmax);
    float age = fmaxf(now - (float)uts[e], 0.f);
    float decay = expf(-age / 2592000.f);
    einfo[e] = make_float4(p, decay, age, 0.f);
}

// ---------------- ts max reduction -----------------------------------------------------
__global__ void k_tsmax(const int* __restrict__ ts, int* __restrict__ out) {
    int i = blockIdx.x * blockDim.x + threadIdx.x;
    int stride = gridDim.x * blockDim.x;
    int m = 0;
    for (int t = i; t < N_EDGES; t += stride) m = max(m, ts[t]);
#pragma unroll
    for (int off = 32; off > 0; off >>= 1) m = max(m, __shfl_down(m, off));
    if ((threadIdx.x & 63) == 0) atomicMax(out, m);
}

// ---------------- per-node aggregation over incidence CSR (no atomics) -----------------
__global__ __launch_bounds__(256) void k_node_agg(
    const float4* __restrict__ einfo, const int* __restrict__ row2,
    const int* __restrict__ eid2, float* __restrict__ feat8) {
    int n = blockIdx.x * blockDim.x + threadIdx.x;
    if (n >= N_NODES) return;
    int e0 = row2[n], e1 = row2[n + 1];
    float cnt = (float)(e1 - e0);
    float sump = 0.f, maxp = 0.f, sumh = 0.f, sumpd = 0.f, sumd = 0.f;
    float sumh30 = 0.f, maxp30 = 0.f, sump30 = 0.f, suml30 = 0.f, minage = 9999.f;
    for (int idx = e0; idx < e1; idx++) {
        float4 v = einfo[eid2[idx]];
        float p = v.x, decay = v.y, age = v.z;
        float aged = age / 86400.f;
        bool high = p >= 0.7f;
        bool l30 = age <= 2592000.f;
        sump += p;
        maxp = fmaxf(maxp, p);
        sumpd += p * decay;
        sumd += decay;
        if (high) {
            sumh += 1.f;
            minage = fminf(minage, aged);
        }
        if (l30) {
            sump30 += p;
            suml30 += 1.f;
            maxp30 = fmaxf(maxp30, p);
            if (high) sumh30 += 1.f;
        }
    }
    float* f = feat8 + (long)n * 8;
    f[0] = sump / (cnt + 1e-6f);
    f[1] = maxp;
    f[2] = log1pf(sumh);
    f[3] = sumpd / (sumd + 1e-6f);
    f[4] = log1pf(sumh30);
    f[5] = maxp30;
    f[6] = sump30 / (suml30 + 1e-6f);
    f[7] = log1pf(fminf(fminf(minage, 9999.f), 90.f)) / log1pf(90.f);
}

// ---------------- node classifier ------------------------------------------------------
__global__ __launch_bounds__(256) void k_node_cls(
    const float* __restrict__ ne, const float* __restrict__ feat8,
    const float* __restrict__ w1t /*[64][72]*/, const float* __restrict__ b1,
    const float* __restrict__ gamma, const float* __restrict__ beta,
    const float* __restrict__ mean, const float* __restrict__ var,
    const float* __restrict__ w2, const float* __restrict__ b2,
    float* __restrict__ out) {
    int n = blockIdx.x * blockDim.x + threadIdx.x;
    if (n >= N_NODES) return;
    float in[72];
    const float4* nr = (const float4*)(ne + (long)n * 64);
#pragma unroll
    for (int i = 0; i < 16; i++) {
        float4 v = nr[i];
        in[4 * i] = v.x; in[4 * i + 1] = v.y; in[4 * i + 2] = v.z; in[4 * i + 3] = v.w;
    }
    const float4* fr = (const float4*)(feat8 + (long)n * 8);
    float4 f0 = fr[0], f1 = fr[1];
    in[64] = f0.x; in[65] = f0.y; in[66] = f0.z; in[67] = f0.w;
    in[68] = f1.x; in[69] = f1.y; in[70] = f1.z; in[71] = f1.w;
    float logit = b2[0];
    for (int j = 0; j < 64; j++) {
        float h = b1[j];
        const float* wr = w1t + j * 72;
#pragma unroll
        for (int k = 0; k < 72; k++) h = fmaf(in[k], wr[k], h);
        h = (h - mean[j]) * rsqrtf(var[j] + 1e-5f) * gamma[j] + beta[j];
        h = fmaxf(h, 0.f);
        logit = fmaf(h, w2[j], logit);
    }
    out[n] = logit;
}

// weight transpose: dst[j*kpad + k] = src[k*ldw + j]
__global__ void k_transpose(const float* __restrict__ src, float* __restrict__ dst,
                            int K, int J, int ldw, int kpad) {
    int i = blockIdx.x * blockDim.x + threadIdx.x;
    if (i >= K * J) return;
    int k = i / J, j = i - k * J;
    dst[j * kpad + k] = src[k * ldw + j];
}

extern "C" void kernel_launch(void* const* d_in, const int* in_sizes, int n_in,
                              void* d_out, int out_size, void* d_ws, size_t ws_size,
                              hipStream_t stream) {
    const float* x = (const float*)d_in[0];
    const int* eidx = (const int*)d_in[1];
    const int* src = eidx;
    const int* dst = eidx + N_EDGES;
    const float* la = (const float*)d_in[2];
    const float* tse = (const float*)d_in[3];
    const int* bp = (const int*)d_in[4];
    const int* tt = (const int*)d_in[5];
    const float* cr = (const float*)d_in[6];
    const float* tsp = (const float*)d_in[7];
    const float* tg = (const float*)d_in[8];
    const float* r7 = (const float*)d_in[9];
    const float* r30 = (const float*)d_in[10];
    const int* uts = (const int*)d_in[11];
    const float* tx_emb = (const float*)d_in[12];
    const float* bank_emb = (const float*)d_in[13];
    const float* ee_w1 = (const float*)d_in[14];
    const float* ee_b1 = (const float*)d_in[15];
    const float* ee_w2 = (const float*)d_in[16];
    const float* ee_b2 = (const float*)d_in[17];
    const float* msg1_w = (const float*)d_in[18];
    const float* msg1_b = (const float*)d_in[19];
    const float* upd1_w = (const float*)d_in[20];
    const float* upd1_b = (const float*)d_in[21];
    const float* msg2_w = (const float*)d_in[22];
    const float* msg2_b = (const float*)d_in[23];
    const float* upd2_w = (const float*)d_in[24];
    const float* upd2_b = (const float*)d_in[25];
    const float* ec_w1 = (const float*)d_in[26];
    const float* ec_b1 = (const float*)d_in[27];
    const float* ec_w2 = (const float*)d_in[28];
    const float* ec_b2 = (const float*)d_in[29];
    const float* nc_w1 = (const float*)d_in[30];
    const float* nc_b1 = (const float*)d_in[31];
    const float* bn_g = (const float*)d_in[32];
    const float* bn_b = (const float*)d_in[33];
    const float* bn_m = (const float*)d_in[34];
    const float* bn_v = (const float*)d_in[35];
    const float* nc_w2 = (const float*)d_in[36];
    const float* nc_b2 = (const float*)d_in[37];

    float* out_node = (float*)d_out;              // [N_NODES]
    float* out_edge = (float*)d_out + N_NODES;    // [N_EDGES]

    // workspace layout (floats) — round-6 proven footprint (ea region half-used now)
    float* ws = (float*)d_ws;
    float* eap_g = ws;                      // E*32 packed f16 (region sized E*64)
    float* P = eap_g + (long)N_EDGES * 64;  // N*128 (dead after 2nd msg_seg -> einfo)
    float* s = P + (long)N_NODES * 128;     // N*128 (dead after upd2 gemm -> eid2)
    float* h1 = s + (long)N_NODES * 128;    // N*128
    float* ne = h1 + (long)N_NODES * 128;   // N*64
    float* nSp = ne + (long)N_NODES * 64;   // N*32 packed (region N*64)
    float* nDp = nSp + (long)N_NODES * 64;  // N*32 packed (region N*64)
    float* feat8 = nDp + (long)N_NODES * 64; // N*8
    float* w1t = feat8 + (long)N_NODES * 8; // spare
    float* Ctp = w1t + 128 * 40;            // 64*32 packed (region 64*64)
    float* ncw1t = Ctp + 64 * 64;           // 64*72
    int* tsmax = (int*)(ncw1t + 64 * 72);   // 1
    int* degi = tsmax + 1;                  // N
    int* row_start = degi + N_NODES;        // N+1
    int* cursor = row_start + N_NODES + 1;  // N
    int* eid = cursor + N_NODES;            // E
    int* partials = eid + N_EDGES;          // 256
    int* deg2 = partials + 256;             // N
    int* row2 = deg2 + N_NODES;             // N+1
    int* cursor2 = row2 + N_NODES + 1;      // N
    // aliased regions:
    float4* einfo = (float4*)P;             // E float4 (8 MB < P's 25.6 MB)
    int* eid2 = (int*)s;                    // 2E ints (4 MB < s's 25.6 MB)

    const int EB = (N_EDGES + 255) / 256;    // 1954
    const int E2B = (2 * N_EDGES + 255) / 256;
    const int NB = (N_NODES + 255) / 256;    // 196
    const int MB = (N_EDGES + 63) / 64;      // 7813

    // ---- init ----
    hipMemsetAsync(tsmax, 0, 4, stream);
    hipMemsetAsync(degi, 0, (size_t)N_NODES * 4, stream);
    hipMemsetAsync(s, 0, (size_t)N_NODES * 128 * 4, stream);

    // ---- CSR1 build (by dst) ----
    k_deg_count<<<EB, 256, 0, stream>>>(dst, degi, N_EDGES);
    k_block_sums<<<NB, 256, 0, stream>>>(degi, partials, N_NODES);
    k_scan_partials<<<1, 256, 0, stream>>>(partials, NB);
    k_scan_final<<<NB, 256, 0, stream>>>(degi, partials, row_start, N_NODES);
    hipMemcpyAsync(cursor, row_start, (size_t)N_NODES * 4, hipMemcpyDeviceToDevice, stream);
    k_fill_slots<<<EB, 256, 0, stream>>>(dst, cursor, eid);

    // ---- weight prep ----
    k_pack_ct<<<8, 256, 0, stream>>>(ec_w1 + 128 * 64, Ctp);
    k_transpose<<<(72 * 64 + 255) / 256, 256, 0, stream>>>(nc_w1, ncw1t, 72, 64, 64, 72);

    // ---- edge encoder (writes packed-f16 ea) ----
    k_edge_enc_tiled<<<MB, 256, 0, stream>>>(la, tse, bp, tt, cr, tsp, tg, r7, r30,
                                             tx_emb, bank_emb, ee_w1, ee_b1, ee_w2, ee_b2,
                                             eap_g, N_EDGES);

    // ---- SAGE layer 1 ----
    k_node_gemm<128, 0, 64, false, false, false><<<dim3(NB, 2), 256, 0, stream>>>(
        x, 128, nullptr, 0, nullptr, msg1_w, 128, nullptr, P, 128, N_NODES);
    k_msg_seg<<<MB, 256, 0, stream>>>(P, eap_g, msg1_w + 128 * 128, msg1_b, src, dst, eid, s, N_EDGES);
    k_node_gemm<128, 128, 64, true, true, false><<<dim3(NB, 2), 256, 0, stream>>>(
        x, 128, s, 128, degi, upd1_w, 128, upd1_b, h1, 128, N_NODES);

    // ---- SAGE layer 2 ----
    k_node_gemm<128, 0, 64, false, false, false><<<dim3(NB, 2), 256, 0, stream>>>(
        h1, 128, nullptr, 0, nullptr, msg2_w, 128, nullptr, P, 128, N_NODES);
    hipMemsetAsync(s, 0, (size_t)N_NODES * 128 * 4, stream);
    k_msg_seg<<<MB, 256, 0, stream>>>(P, eap_g, msg2_w + 128 * 128, msg2_b, src, dst, eid, s, N_EDGES);
    k_node_gemm<128, 128, 64, true, true, false><<<dim3(NB, 1), 256, 0, stream>>>(
        h1, 128, s, 128, degi, upd2_w, 64, upd2_b, ne, 64, N_NODES);
    // s and P are now dead -> eid2 / einfo aliases safe from here on

    // ---- edge classifier prep: nS/nD packed f16 ----
    k_node_gemm<64, 0, 64, false, false, true><<<dim3(NB, 1), 256, 0, stream>>>(
        ne, 64, nullptr, 0, nullptr, ec_w1, 64, nullptr, nSp, 32, N_NODES);
    k_node_gemm<64, 0, 64, false, false, true><<<dim3(NB, 1), 256, 0, stream>>>(
        ne, 64, nullptr, 0, nullptr, ec_w1 + 64 * 64, 64, nullptr, nDp, 32, N_NODES);

    // ---- CSR2 build ----
    hipMemsetAsync(deg2, 0, (size_t)N_NODES * 4, stream);
    k_deg_count<<<E2B, 256, 0, stream>>>(eidx, deg2, 2 * N_EDGES);
    k_block_sums<<<NB, 256, 0, stream>>>(deg2, partials, N_NODES);
    k_scan_partials<<<1, 256, 0, stream>>>(partials, NB);
    k_scan_final<<<NB, 256, 0, stream>>>(deg2, partials, row2, N_NODES);
    hipMemcpyAsync(cursor2, row2, (size_t)N_NODES * 4, hipMemcpyDeviceToDevice, stream);
    k_fill_slots2<<<E2B, 256, 0, stream>>>(eidx, cursor2, eid2);

    // ---- edge classifier (+ einfo pack) ----
    k_tsmax<<<256, 256, 0, stream>>>(uts, tsmax);
    k_edge_cls<<<EB, 256, 0, stream>>>(nSp, nDp, eap_g, Ctp, ec_b1, ec_w2, ec_b2,
                                       src, dst, uts, tsmax, out_edge, einfo);

    // ---- node aggregation ----
    k_node_agg<<<NB, 256, 0, stream>>>(einfo, row2, eid2, feat8);

    // ---- node classifier ----
    k_node_cls<<<NB, 256, 0, stream>>>(ne, feat8, ncw1t, nc_b1, bn_g, bn_b, bn_m, bn_v,
                                       nc_w2, nc_b2, out_node);
}

// Round 11
// 1293.429 us; speedup vs baseline: 6.5276x; 1.0338x over previous
//
#include <hip/hip_runtime.h>
#include <math.h>

#define N_NODES 50000
#define N_EDGES 500000

// ---------- f16 pair helpers ----------
typedef _Float16 h2_t __attribute__((ext_vector_type(2)));
__device__ inline float pk(float a, float b) {
    h2_t h; h[0] = (_Float16)a; h[1] = (_Float16)b;
    float r; __builtin_memcpy(&r, &h, 4); return r;
}
__device__ inline float2 upk(float p) {
    h2_t h; __builtin_memcpy(&h, &p, 4);
    return make_float2((float)h[0], (float)h[1]);
}
__device__ inline float dot2f(float pa, float pb, float c) {
    h2_t ha, hb; __builtin_memcpy(&ha, &pa, 4); __builtin_memcpy(&hb, &pb, 4);
    return __builtin_amdgcn_fdot2(ha, hb, c, false);
}

// =================== merged CSR build (CSR1 by dst + CSR2 incidence) ====================
__global__ void k_deg_count_both(const int* __restrict__ eidx,
                                 int* __restrict__ degi, int* __restrict__ deg2) {
    int i = blockIdx.x * blockDim.x + threadIdx.x;
    if (i < N_EDGES) atomicAdd(degi + eidx[N_EDGES + i], 1);  // dst
    if (i < 2 * N_EDGES) atomicAdd(deg2 + eidx[i], 1);        // both endpoints
}

__global__ void k_block_sums2(const int* __restrict__ degi, const int* __restrict__ deg2,
                              int* __restrict__ partials, int n) {
    const int* deg = blockIdx.y ? deg2 : degi;
    int* part = partials + blockIdx.y * 256;
    __shared__ int sm[256];
    int i = blockIdx.x * 256 + threadIdx.x;
    sm[threadIdx.x] = (i < n) ? deg[i] : 0;
    __syncthreads();
    for (int s = 128; s > 0; s >>= 1) {
        if (threadIdx.x < s) sm[threadIdx.x] += sm[threadIdx.x + s];
        __syncthreads();
    }
    if (threadIdx.x == 0) part[blockIdx.x] = sm[0];
}

// two blocks: each scans its own 256-entry partials array (exclusive)
__global__ void k_scan_partials2(int* partials, int nb) {
    int* part = partials + blockIdx.x * 256;
    __shared__ int sm[256];
    int v = (threadIdx.x < nb) ? part[threadIdx.x] : 0;
    sm[threadIdx.x] = v;
    __syncthreads();
    for (int off = 1; off < 256; off <<= 1) {
        int t = (threadIdx.x >= off) ? sm[threadIdx.x - off] : 0;
        __syncthreads();
        sm[threadIdx.x] += t;
        __syncthreads();
    }
    if (threadIdx.x < nb) part[threadIdx.x] = sm[threadIdx.x] - v;
}

__global__ void k_scan_final2(const int* __restrict__ degi, const int* __restrict__ deg2,
                              const int* __restrict__ partials,
                              int* __restrict__ row_start, int* __restrict__ row2, int n) {
    const int* deg = blockIdx.y ? deg2 : degi;
    const int* part = partials + blockIdx.y * 256;
    int* row = blockIdx.y ? row2 : row_start;
    __shared__ int sm[256];
    int i = blockIdx.x * 256 + threadIdx.x;
    int v = (i < n) ? deg[i] : 0;
    sm[threadIdx.x] = v;
    __syncthreads();
    for (int off = 1; off < 256; off <<= 1) {
        int t = (threadIdx.x >= off) ? sm[threadIdx.x - off] : 0;
        __syncthreads();
        sm[threadIdx.x] += t;
        __syncthreads();
    }
    if (i < n) row[i] = part[blockIdx.x] + sm[threadIdx.x] - v;
    if (i == n - 1) row[n] = part[blockIdx.x] + sm[threadIdx.x];
}

__global__ void k_copy_cursors(const int* __restrict__ row_start, const int* __restrict__ row2,
                               int* __restrict__ cursor, int* __restrict__ cursor2) {
    int i = blockIdx.x * 256 + threadIdx.x;
    if (i < N_NODES) { cursor[i] = row_start[i]; cursor2[i] = row2[i]; }
}

__global__ void k_fill_slots_both(const int* __restrict__ eidx,
                                  int* __restrict__ cursor, int* __restrict__ cursor2,
                                  int* __restrict__ eid, int* __restrict__ eid2) {
    int i = blockIdx.x * blockDim.x + threadIdx.x;
    if (i < N_EDGES) {
        int pos = atomicAdd(cursor + eidx[N_EDGES + i], 1);
        eid[pos] = i;
    }
    if (i < 2 * N_EDGES) {
        int pos2 = atomicAdd(cursor2 + eidx[i], 1);
        eid2[pos2] = (i < N_EDGES) ? i : (i - N_EDGES);
    }
}

// ---------------- merged weight prep: pack Ct + transpose nc_w1 ------------------------
__global__ void k_prep_weights(const float* __restrict__ C /*[64 k][64 j]*/, float* __restrict__ Ctp,
                               const float* __restrict__ nc_w1 /*[72][64]*/, float* __restrict__ ncw1t) {
    int i = blockIdx.x * 256 + threadIdx.x;
    if (i < 2048) {
        int j = i >> 5, k2 = i & 31;
        Ctp[i] = pk(C[(2 * k2) * 64 + j], C[(2 * k2 + 1) * 64 + j]);
    }
    int t = i - 2048;
    if (t >= 0 && t < 72 * 64) {
        int k = t / 64, j = t - k * 64;
        ncw1t[j * 72 + k] = nc_w1[k * 64 + j];
    }
}

// ---------------- edge encoder, LDS-tiled, f16-dot2, packed-f16 ea output --------------
__global__ __launch_bounds__(256) void k_edge_enc_tiled(
    const float* __restrict__ la, const float* __restrict__ tse,
    const int* __restrict__ bp, const int* __restrict__ tt,
    const float* __restrict__ cr, const float* __restrict__ tsp,
    const float* __restrict__ tg, const float* __restrict__ r7,
    const float* __restrict__ r30,
    const float* __restrict__ tx_emb, const float* __restrict__ bank_emb,
    const float* __restrict__ w1 /*[38][128]*/, const float* __restrict__ eb1,
    const float* __restrict__ w2 /*[128][64]*/, const float* __restrict__ eb2,
    float* __restrict__ eap_g /*E x 32 packed*/, int n_edges) {
    __shared__ float smem[8448];
    float* W2p = smem;            // [64 k2][64 j]
    float* Fp = smem + 4096;      // [64][20]
    float* W1p = smem + 5376;     // [20 k2][128 j]
    float* Hp = smem + 4096;      // [64][68] (overlays Fp+W1p)
    int tid = threadIdx.x;
    int t0 = blockIdx.x * 64;

#pragma unroll
    for (int i = 0; i < 16; i++) {
        int idx = tid + 256 * i;
        int k2 = idx >> 6, j = idx & 63;
        W2p[idx] = pk(w2[(2 * k2) * 64 + j], w2[(2 * k2 + 1) * 64 + j]);
    }
#pragma unroll
    for (int i = 0; i < 10; i++) {
        int idx = tid + 256 * i;
        int k2 = idx >> 7, j = idx & 127;
        float a = (2 * k2 < 38) ? w1[(2 * k2) * 128 + j] : 0.f;
        float b = (2 * k2 + 1 < 38) ? w1[(2 * k2 + 1) * 128 + j] : 0.f;
        W1p[idx] = pk(a, b);
    }
    {
        int el = tid & 63, g = tid >> 6;
        int e = t0 + el;
        bool ok = e < n_edges;
        float* Fr = Fp + el * 20;
        if (g == 0) {
            Fr[0] = ok ? pk(la[e], cr[e]) : 0.f;
            Fr[1] = ok ? pk(tsp[e], tg[e]) : 0.f;
            Fr[2] = ok ? pk(r7[e], r30[e]) : 0.f;
            Fr[19] = 0.f;
        } else if (g == 1) {
            float4 a = make_float4(0, 0, 0, 0), b = a;
            if (ok) { a = ((const float4*)(tse + (long)e * 8))[0];
                      b = ((const float4*)(tse + (long)e * 8))[1]; }
            Fr[3] = pk(a.x, a.y); Fr[4] = pk(a.z, a.w);
            Fr[5] = pk(b.x, b.y); Fr[6] = pk(b.z, b.w);
        } else if (g == 2) {
            float4 a = make_float4(0, 0, 0, 0), b = a;
            if (ok) { int txi = tt[e];
                      a = ((const float4*)(tx_emb + (long)txi * 8))[0];
                      b = ((const float4*)(tx_emb + (long)txi * 8))[1]; }
            Fr[7] = pk(a.x, a.y); Fr[8] = pk(a.z, a.w);
            Fr[9] = pk(b.x, b.y); Fr[10] = pk(b.z, b.w);
        } else {
            float4 a = make_float4(0, 0, 0, 0), b = a, c = a, d = a;
            if (ok) {
                int bk0 = bp[e * 2 + 0], bk1 = bp[e * 2 + 1];
                a = ((const float4*)(bank_emb + (long)bk0 * 8))[0];
                b = ((const float4*)(bank_emb + (long)bk0 * 8))[1];
                c = ((const float4*)(bank_emb + (long)bk1 * 8))[0];
                d = ((const float4*)(bank_emb + (long)bk1 * 8))[1];
            }
            Fr[11] = pk(a.x, a.y); Fr[12] = pk(a.z, a.w);
            Fr[13] = pk(b.x, b.y); Fr[14] = pk(b.z, b.w);
            Fr[15] = pk(c.x, c.y); Fr[16] = pk(c.z, c.w);
            Fr[17] = pk(d.x, d.y); Fr[18] = pk(d.z, d.w);
        }
    }
    __syncthreads();

    // GEMM1 (K2=20)
    int jg1 = tid & 31, eg1 = tid >> 5;
    int j1 = jg1 * 4;
    float acc1[8][4];
#pragma unroll
    for (int el = 0; el < 8; el++)
#pragma unroll
        for (int jj = 0; jj < 4; jj++) acc1[el][jj] = 0.f;
    for (int kq = 0; kq < 5; kq++) {
        float4 wv[4];
#pragma unroll
        for (int kk = 0; kk < 4; kk++)
            wv[kk] = *(const float4*)&W1p[(kq * 4 + kk) * 128 + j1];
#pragma unroll
        for (int el = 0; el < 8; el++) {
            float4 av = *(const float4*)&Fp[(eg1 * 8 + el) * 20 + kq * 4];
            const float* a = (const float*)&av;
#pragma unroll
            for (int jj = 0; jj < 4; jj++) {
                float t = acc1[el][jj];
                t = dot2f(a[0], ((const float*)&wv[0])[jj], t);
                t = dot2f(a[1], ((const float*)&wv[1])[jj], t);
                t = dot2f(a[2], ((const float*)&wv[2])[jj], t);
                t = dot2f(a[3], ((const float*)&wv[3])[jj], t);
                acc1[el][jj] = t;
            }
        }
    }
    __syncthreads();

    {
        float4 bv = *(const float4*)(eb1 + j1);
#pragma unroll
        for (int el = 0; el < 8; el++) {
            int row = eg1 * 8 + el;
            float x0 = fmaxf(acc1[el][0] + bv.x, 0.f);
            float x1 = fmaxf(acc1[el][1] + bv.y, 0.f);
            float x2 = fmaxf(acc1[el][2] + bv.z, 0.f);
            float x3 = fmaxf(acc1[el][3] + bv.w, 0.f);
            int c = (tid & 31) * 2;
            Hp[row * 68 + c] = pk(x0, x1);
            Hp[row * 68 + c + 1] = pk(x2, x3);
        }
    }
    __syncthreads();

    // GEMM2 (K2=64) -> packed f16 ea
    {
        int jg = tid & 15, eg = tid >> 4;
        int j0 = jg * 4;
        float acc[4][4];
#pragma unroll
        for (int el = 0; el < 4; el++)
#pragma unroll
            for (int jj = 0; jj < 4; jj++) acc[el][jj] = 0.f;
        for (int kq = 0; kq < 16; kq++) {
            float4 wv[4];
#pragma unroll
            for (int kk = 0; kk < 4; kk++)
                wv[kk] = *(const float4*)&W2p[(kq * 4 + kk) * 64 + j0];
#pragma unroll
            for (int el = 0; el < 4; el++) {
                float4 av = *(const float4*)&Hp[(eg * 4 + el) * 68 + kq * 4];
                const float* a = (const float*)&av;
#pragma unroll
                for (int jj = 0; jj < 4; jj++) {
                    float t = acc[el][jj];
                    t = dot2f(a[0], ((const float*)&wv[0])[jj], t);
                    t = dot2f(a[1], ((const float*)&wv[1])[jj], t);
                    t = dot2f(a[2], ((const float*)&wv[2])[jj], t);
                    t = dot2f(a[3], ((const float*)&wv[3])[jj], t);
                    acc[el][jj] = t;
                }
            }
        }
        float4 bv = *(const float4*)(eb2 + j0);
#pragma unroll
        for (int el = 0; el < 4; el++) {
            int e = t0 + eg * 4 + el;
            if (e >= n_edges) continue;
            float2 o;
            o.x = pk(acc[el][0] + bv.x, acc[el][1] + bv.y);
            o.y = pk(acc[el][2] + bv.z, acc[el][3] + bv.w);
            *((float2*)(eap_g + (long)e * 32 + (j0 >> 1))) = o;
        }
    }
}

// ---------------- generic node-level GEMM (fp32; optional packed-f16 output) -----------
template <int K1, int K2, int JC, bool RELU, bool DIV2, bool PACKOUT>
__global__ __launch_bounds__(256) void k_node_gemm(
    const float* __restrict__ in1, int ld1,
    const float* __restrict__ in2, int ld2,
    const int* __restrict__ degi,
    const float* __restrict__ W, int ldw,
    const float* __restrict__ bias,
    float* __restrict__ out, int ldo, int nrows) {
    int n = blockIdx.x * blockDim.x + threadIdx.x;
    if (n >= nrows) return;
    int j0 = blockIdx.y * JC;
    float acc[JC];
#pragma unroll
    for (int j = 0; j < JC; j++) acc[j] = bias ? bias[j0 + j] : 0.f;
    const float* r1 = in1 + (long)n * ld1;
    for (int k = 0; k < K1; k++) {
        float v = r1[k];
        const float* wr = W + (long)k * ldw + j0;
#pragma unroll
        for (int j = 0; j < JC; j++) acc[j] = fmaf(v, wr[j], acc[j]);
    }
    if constexpr (K2 > 0) {
        float dinv = 1.f;
        if constexpr (DIV2) dinv = 1.f / ((float)degi[n] + 1e-6f);
        const float* r2 = in2 + (long)n * ld2;
        for (int k = 0; k < K2; k++) {
            float v = r2[k] * dinv;
            const float* wr = W + (long)(K1 + k) * ldw + j0;
#pragma unroll
            for (int j = 0; j < JC; j++) acc[j] = fmaf(v, wr[j], acc[j]);
        }
    }
    if constexpr (PACKOUT) {
        float* orow = out + (long)n * ldo + (j0 >> 1);
#pragma unroll
        for (int j2 = 0; j2 < JC / 2; j2++) {
            float a = acc[2 * j2], b = acc[2 * j2 + 1];
            if (RELU) { a = fmaxf(a, 0.f); b = fmaxf(b, 0.f); }
            orow[j2] = pk(a, b);
        }
    } else {
        float* orow = out + (long)n * ldo + j0;
#pragma unroll
        for (int j = 0; j < JC; j++) {
            float v = acc[j];
            if (RELU) v = fmaxf(v, 0.f);
            orow[j] = v;
        }
    }
}

// ---------------- edge-cls prep: nSp/nDp in one launch (blockIdx.y picks half) ---------
__global__ __launch_bounds__(256) void k_ec_prep(
    const float* __restrict__ ne, const float* __restrict__ ec_w1,
    float* __restrict__ nSp, float* __restrict__ nDp) {
    int n = blockIdx.x * blockDim.x + threadIdx.x;
    if (n >= N_NODES) return;
    const float* W = ec_w1 + (blockIdx.y ? 64 * 64 : 0);
    float* out = blockIdx.y ? nDp : nSp;
    float acc[64];
#pragma unroll
    for (int j = 0; j < 64; j++) acc[j] = 0.f;
    const float* r = ne + (long)n * 64;
    for (int k = 0; k < 64; k++) {
        float v = r[k];
        const float* wr = W + k * 64;
#pragma unroll
        for (int j = 0; j < 64; j++) acc[j] = fmaf(v, wr[j], acc[j]);
    }
    float* orow = out + (long)n * 32;
#pragma unroll
    for (int j2 = 0; j2 < 32; j2++) orow[j2] = pk(acc[2 * j2], acc[2 * j2 + 1]);
}

// ---------------- fused msg GEMM (f16-dot2, packed ea + packed P) + segmented sum ------
__global__ __launch_bounds__(256) void k_msg_seg(
    const float* __restrict__ Pp /*N x 64 packed*/, const float* __restrict__ eap_g,
    const float* __restrict__ W /*[64][128]*/, const float* __restrict__ bias,
    const int* __restrict__ src, const int* __restrict__ dst,
    const int* __restrict__ eid,
    float* __restrict__ s, int n_edges) {
    __shared__ float smem[8192];
    float* eap = smem;            // [64][32]
    float* Wp = smem + 2048;      // [32][128]
    float* M = smem;              // [64][128] overlays
    __shared__ int sn_s[64];
    __shared__ int es_s[64];
    __shared__ int nid_s[64];
    __shared__ int bound_s[2];
    int tid = threadIdx.x;
    int t0 = blockIdx.x * 64;

    if (tid < 64) {
        int slot = t0 + tid;
        int e = (slot < n_edges) ? eid[slot] : 0;
        es_s[tid] = e;
        sn_s[tid] = src[e];
        nid_s[tid] = (slot < n_edges) ? dst[e] : -1;
    }
    if (tid == 64) bound_s[0] = (t0 > 0) ? dst[eid[t0 - 1]] : -1;
    if (tid == 65) bound_s[1] = (t0 + 64 < n_edges) ? dst[eid[t0 + 64]] : -1;
#pragma unroll
    for (int i = 0; i < 16; i++) {
        int idx = tid + 256 * i;
        int k2 = idx >> 7, j = idx & 127;
        Wp[idx] = pk(W[(2 * k2) * 128 + j], W[(2 * k2 + 1) * 128 + j]);
    }
    __syncthreads();
#pragma unroll
    for (int i = 0; i < 2; i++) {
        int f = tid + 256 * i;
        int el = f >> 3, c = f & 7;
        float4 v = ((const float4*)(eap_g + (long)es_s[el] * 32))[c];
        *((float4*)&eap[el * 32 + c * 4]) = v;
    }
    __syncthreads();

    int jg = tid & 31;
    int eg = tid >> 5;
    int j0 = jg * 4;
    float acc[8][4];
#pragma unroll
    for (int el = 0; el < 8; el++)
#pragma unroll
        for (int jj = 0; jj < 4; jj++) acc[el][jj] = 0.f;

    for (int kq = 0; kq < 8; kq++) {
        float4 wv[4];
#pragma unroll
        for (int kk = 0; kk < 4; kk++) wv[kk] = *(const float4*)&Wp[(kq * 4 + kk) * 128 + j0];
#pragma unroll
        for (int el = 0; el < 8; el++) {
            float4 av = *(const float4*)&eap[(eg * 8 + el) * 32 + kq * 4];
            const float* a = (const float*)&av;
#pragma unroll
            for (int jj = 0; jj < 4; jj++) {
                float t = acc[el][jj];
                t = dot2f(a[0], ((const float*)&wv[0])[jj], t);
                t = dot2f(a[1], ((const float*)&wv[1])[jj], t);
                t = dot2f(a[2], ((const float*)&wv[2])[jj], t);
                t = dot2f(a[3], ((const float*)&wv[3])[jj], t);
                acc[el][jj] = t;
            }
        }
    }
    __syncthreads();

    float4 bv = *(const float4*)(bias + j0);
#pragma unroll
    for (int el = 0; el < 8; el++) {
        int row = eg * 8 + el;
        float2 pv2 = *(const float2*)(Pp + (long)sn_s[row] * 64 + (j0 >> 1));
        float2 pa = upk(pv2.x), pb = upk(pv2.y);
        float4 o;
        o.x = fmaxf(acc[el][0] + pa.x + bv.x, 0.f);
        o.y = fmaxf(acc[el][1] + pa.y + bv.y, 0.f);
        o.z = fmaxf(acc[el][2] + pb.x + bv.z, 0.f);
        o.w = fmaxf(acc[el][3] + pb.y + bv.w, 0.f);
        *((float4*)&M[row * 128 + j0]) = o;
    }
    __syncthreads();

    if (tid < 128) {
        int c = tid;
        int rows = min(64, n_edges - t0);
        int prev_n = bound_s[0], next_n = bound_s[1];
        int cur = nid_s[0];
        int seg_start = 0;
        float run = 0.f;
        for (int r = 0; r < rows; r++) {
            int nd = nid_s[r];
            if (nd != cur) {
                if (seg_start == 0 && cur == prev_n) atomicAdd(s + (long)cur * 128 + c, run);
                else s[(long)cur * 128 + c] = run;
                cur = nd; seg_start = r; run = 0.f;
            }
            run += M[r * 128 + c];
        }
        if ((seg_start == 0 && cur == prev_n) || cur == next_n)
            atomicAdd(s + (long)cur * 128 + c, run);
        else s[(long)cur * 128 + c] = run;
    }
}

// ---------------- edge classifier: packed-f16 gathers, f16-dot2 math -------------------
__global__ __launch_bounds__(256) void k_edge_cls(
    const float* __restrict__ nSp, const float* __restrict__ nDp,
    const float* __restrict__ eap_g,
    const float* __restrict__ Ctp /*[64 j][32 k2] packed*/,
    const float* __restrict__ b1, const float* __restrict__ w2, const float* __restrict__ b2,
    const int* __restrict__ src, const int* __restrict__ dst,
    const int* __restrict__ uts, const int* __restrict__ tsmax,
    float* __restrict__ logits_out, float4* __restrict__ einfo) {
    int e = blockIdx.x * blockDim.x + threadIdx.x;
    if (e >= N_EDGES) return;
    int sn = src[e], dn = dst[e];
    float base[64];
    const float4* Sp4 = (const float4*)(nSp + (long)sn * 32);
    const float4* Dp4 = (const float4*)(nDp + (long)dn * 32);
#pragma unroll
    for (int i = 0; i < 8; i++) {
        float4 sv = Sp4[i];
        float4 dv = Dp4[i];
        const float* sp = (const float*)&sv;
        const float* dp = (const float*)&dv;
#pragma unroll
        for (int q = 0; q < 4; q++) {
            float2 su = upk(sp[q]), du = upk(dp[q]);
            base[8 * i + 2 * q + 0] = su.x + du.x;
            base[8 * i + 2 * q + 1] = su.y + du.y;
        }
    }
    float ap[32];
    const float4* ar = (const float4*)(eap_g + (long)e * 32);
#pragma unroll
    for (int i = 0; i < 8; i++) {
        float4 v = ar[i];
        ap[4 * i] = v.x; ap[4 * i + 1] = v.y; ap[4 * i + 2] = v.z; ap[4 * i + 3] = v.w;
    }
    float logit = b2[0];
    for (int j = 0; j < 64; j++) {
        float t = b1[j] + base[j];
        const float* wr = Ctp + j * 32;
#pragma unroll
        for (int k2 = 0; k2 < 32; k2++) t = dot2f(ap[k2], wr[k2], t);
        t = fmaxf(t, 0.f);
        logit = fmaf(t, w2[j], logit);
    }
    logits_out[e] = logit;
    float p = 1.f / (1.f + expf(-logit));
    float now = (float)(*tsmax);
    float age = fmaxf(now - (float)uts[e], 0.f);
    float decay = expf(-age / 2592000.f);
    einfo[e] = make_float4(p, decay, age, 0.f);
}

// ---------------- ts max reduction -----------------------------------------------------
__global__ void k_tsmax(const int* __restrict__ ts, int* __restrict__ out) {
    int i = blockIdx.x * blockDim.x + threadIdx.x;
    int stride = gridDim.x * blockDim.x;
    int m = 0;
    for (int t = i; t < N_EDGES; t += stride) m = max(m, ts[t]);
#pragma unroll
    for (int off = 32; off > 0; off >>= 1) m = max(m, __shfl_down(m, off));
    if ((threadIdx.x & 63) == 0) atomicMax(out, m);
}

// ---------------- per-node aggregation over incidence CSR (no atomics) -----------------
__global__ __launch_bounds__(256) void k_node_agg(
    const float4* __restrict__ einfo, const int* __restrict__ row2,
    const int* __restrict__ eid2, float* __restrict__ feat8) {
    int n = blockIdx.x * blockDim.x + threadIdx.x;
    if (n >= N_NODES) return;
    int e0 = row2[n], e1 = row2[n + 1];
    float cnt = (float)(e1 - e0);
    float sump = 0.f, maxp = 0.f, sumh = 0.f, sumpd = 0.f, sumd = 0.f;
    float sumh30 = 0.f, maxp30 = 0.f, sump30 = 0.f, suml30 = 0.f, minage = 9999.f;
    for (int idx = e0; idx < e1; idx++) {
        float4 v = einfo[eid2[idx]];
        float p = v.x, decay = v.y, age = v.z;
        float aged = age / 86400.f;
        bool high = p >= 0.7f;
        bool l30 = age <= 2592000.f;
        sump += p;
        maxp = fmaxf(maxp, p);
        sumpd += p * decay;
        sumd += decay;
        if (high) {
            sumh += 1.f;
            minage = fminf(minage, aged);
        }
        if (l30) {
            sump30 += p;
            suml30 += 1.f;
            maxp30 = fmaxf(maxp30, p);
            if (high) sumh30 += 1.f;
        }
    }
    float* f = feat8 + (long)n * 8;
    f[0] = sump / (cnt + 1e-6f);
    f[1] = maxp;
    f[2] = log1pf(sumh);
    f[3] = sumpd / (sumd + 1e-6f);
    f[4] = log1pf(sumh30);
    f[5] = maxp30;
    f[6] = sump30 / (suml30 + 1e-6f);
    f[7] = log1pf(fminf(fminf(minage, 9999.f), 90.f)) / log1pf(90.f);
}

// ---------------- node classifier ------------------------------------------------------
__global__ __launch_bounds__(256) void k_node_cls(
    const float* __restrict__ ne, const float* __restrict__ feat8,
    const float* __restrict__ w1t /*[64][72]*/, const float* __restrict__ b1,
    const float* __restrict__ gamma, const float* __restrict__ beta,
    const float* __restrict__ mean, const float* __restrict__ var,
    const float* __restrict__ w2, const float* __restrict__ b2,
    float* __restrict__ out) {
    int n = blockIdx.x * blockDim.x + threadIdx.x;
    if (n >= N_NODES) return;
    float in[72];
    const float4* nr = (const float4*)(ne + (long)n * 64);
#pragma unroll
    for (int i = 0; i < 16; i++) {
        float4 v = nr[i];
        in[4 * i] = v.x; in[4 * i + 1] = v.y; in[4 * i + 2] = v.z; in[4 * i + 3] = v.w;
    }
    const float4* fr = (const float4*)(feat8 + (long)n * 8);
    float4 f0 = fr[0], f1 = fr[1];
    in[64] = f0.x; in[65] = f0.y; in[66] = f0.z; in[67] = f0.w;
    in[68] = f1.x; in[69] = f1.y; in[70] = f1.z; in[71] = f1.w;
    float logit = b2[0];
    for (int j = 0; j < 64; j++) {
        float h = b1[j];
        const float* wr = w1t + j * 72;
#pragma unroll
        for (int k = 0; k < 72; k++) h = fmaf(in[k], wr[k], h);
        h = (h - mean[j]) * rsqrtf(var[j] + 1e-5f) * gamma[j] + beta[j];
        h = fmaxf(h, 0.f);
        logit = fmaf(h, w2[j], logit);
    }
    out[n] = logit;
}

extern "C" void kernel_launch(void* const* d_in, const int* in_sizes, int n_in,
                              void* d_out, int out_size, void* d_ws, size_t ws_size,
                              hipStream_t stream) {
    const float* x = (const float*)d_in[0];
    const int* eidx = (const int*)d_in[1];
    const int* src = eidx;
    const int* dst = eidx + N_EDGES;
    const float* la = (const float*)d_in[2];
    const float* tse = (const float*)d_in[3];
    const int* bp = (const int*)d_in[4];
    const int* tt = (const int*)d_in[5];
    const float* cr = (const float*)d_in[6];
    const float* tsp = (const float*)d_in[7];
    const float* tg = (const float*)d_in[8];
    const float* r7 = (const float*)d_in[9];
    const float* r30 = (const float*)d_in[10];
    const int* uts = (const int*)d_in[11];
    const float* tx_emb = (const float*)d_in[12];
    const float* bank_emb = (const float*)d_in[13];
    const float* ee_w1 = (const float*)d_in[14];
    const float* ee_b1 = (const float*)d_in[15];
    const float* ee_w2 = (const float*)d_in[16];
    const float* ee_b2 = (const float*)d_in[17];
    const float* msg1_w = (const float*)d_in[18];
    const float* msg1_b = (const float*)d_in[19];
    const float* upd1_w = (const float*)d_in[20];
    const float* upd1_b = (const float*)d_in[21];
    const float* msg2_w = (const float*)d_in[22];
    const float* msg2_b = (const float*)d_in[23];
    const float* upd2_w = (const float*)d_in[24];
    const float* upd2_b = (const float*)d_in[25];
    const float* ec_w1 = (const float*)d_in[26];
    const float* ec_b1 = (const float*)d_in[27];
    const float* ec_w2 = (const float*)d_in[28];
    const float* ec_b2 = (const float*)d_in[29];
    const float* nc_w1 = (const float*)d_in[30];
    const float* nc_b1 = (const float*)d_in[31];
    const float* bn_g = (const float*)d_in[32];
    const float* bn_b = (const float*)d_in[33];
    const float* bn_m = (const float*)d_in[34];
    const float* bn_v = (const float*)d_in[35];
    const float* nc_w2 = (const float*)d_in[36];
    const float* nc_b2 = (const float*)d_in[37];

    float* out_node = (float*)d_out;              // [N_NODES]
    float* out_edge = (float*)d_out + N_NODES;    // [N_EDGES]

    // workspace layout (floats) — ~163 MB total (shrunk: packed regions, standalone eid2)
    float* ws0 = (float*)d_ws;
    float* eap_g = ws0;                          // E*32 packed f16
    float* Pp = eap_g + (long)N_EDGES * 32;      // N*64 packed (einfo alias: E*4 floats = 8 MB < 12.8 MB)
    float* s = Pp + (long)N_NODES * 64;          // N*128 fp32
    float* h1 = s + (long)N_NODES * 128;         // N*128 fp32
    float* ne = h1 + (long)N_NODES * 128;        // N*64 fp32
    float* nSp = ne + (long)N_NODES * 64;        // N*32 packed
    float* nDp = nSp + (long)N_NODES * 32;       // N*32 packed
    float* feat8 = nDp + (long)N_NODES * 32;     // N*8
    float* Ctp = feat8 + (long)N_NODES * 8;      // 64*32
    float* ncw1t = Ctp + 64 * 32;                // 64*72
    int* tsmax = (int*)(ncw1t + 64 * 72);        // 1
    int* degi = tsmax + 1;                       // N
    int* deg2 = degi + N_NODES;                  // N   (tsmax..deg2 zeroed in one memset)
    int* row_start = deg2 + N_NODES;             // N+1
    int* row2 = row_start + N_NODES + 1;         // N+1
    int* cursor = row2 + N_NODES + 1;            // N
    int* cursor2 = cursor + N_NODES;             // N
    int* eid = cursor2 + N_NODES;                // E
    int* eid2 = eid + N_EDGES;                   // 2E
    int* partials = eid2 + 2 * N_EDGES;          // 512
    float4* einfo = (float4*)Pp;                 // aliases Pp (dead after 2nd msg_seg)

    const int EB = (N_EDGES + 255) / 256;
    const int E2B = (2 * N_EDGES + 255) / 256;
    const int NB = (N_NODES + 255) / 256;        // 196
    const int MB = (N_EDGES + 63) / 64;          // 7813

    // ---- init ----
    hipMemsetAsync(tsmax, 0, (size_t)(1 + 2 * N_NODES) * 4, stream);  // tsmax+degi+deg2
    hipMemsetAsync(s, 0, (size_t)N_NODES * 128 * 4, stream);

    // ---- merged CSR1 + CSR2 build ----
    k_deg_count_both<<<E2B, 256, 0, stream>>>(eidx, degi, deg2);
    k_block_sums2<<<dim3(NB, 2), 256, 0, stream>>>(degi, deg2, partials, N_NODES);
    k_scan_partials2<<<2, 256, 0, stream>>>(partials, NB);
    k_scan_final2<<<dim3(NB, 2), 256, 0, stream>>>(degi, deg2, partials, row_start, row2, N_NODES);
    k_copy_cursors<<<NB, 256, 0, stream>>>(row_start, row2, cursor, cursor2);
    k_fill_slots_both<<<E2B, 256, 0, stream>>>(eidx, cursor, cursor2, eid, eid2);

    // ---- weight prep (pack Ct + transpose nc_w1) ----
    k_prep_weights<<<26, 256, 0, stream>>>(ec_w1 + 128 * 64, Ctp, nc_w1, ncw1t);

    // ---- edge encoder (writes packed-f16 ea) ----
    k_edge_enc_tiled<<<MB, 256, 0, stream>>>(la, tse, bp, tt, cr, tsp, tg, r7, r30,
                                             tx_emb, bank_emb, ee_w1, ee_b1, ee_w2, ee_b2,
                                             eap_g, N_EDGES);

    // ---- SAGE layer 1 (P packed f16) ----
    k_node_gemm<128, 0, 64, false, false, true><<<dim3(NB, 2), 256, 0, stream>>>(
        x, 128, nullptr, 0, nullptr, msg1_w, 128, nullptr, Pp, 64, N_NODES);
    k_msg_seg<<<MB, 256, 0, stream>>>(Pp, eap_g, msg1_w + 128 * 128, msg1_b, src, dst, eid, s, N_EDGES);
    k_node_gemm<128, 128, 64, true, true, false><<<dim3(NB, 2), 256, 0, stream>>>(
        x, 128, s, 128, degi, upd1_w, 128, upd1_b, h1, 128, N_NODES);

    // ---- SAGE layer 2 ----
    k_node_gemm<128, 0, 64, false, false, true><<<dim3(NB, 2), 256, 0, stream>>>(
        h1, 128, nullptr, 0, nullptr, msg2_w, 128, nullptr, Pp, 64, N_NODES);
    hipMemsetAsync(s, 0, (size_t)N_NODES * 128 * 4, stream);
    k_msg_seg<<<MB, 256, 0, stream>>>(Pp, eap_g, msg2_w + 128 * 128, msg2_b, src, dst, eid, s, N_EDGES);
    k_node_gemm<128, 128, 64, true, true, false><<<dim3(NB, 1), 256, 0, stream>>>(
        h1, 128, s, 128, degi, upd2_w, 64, upd2_b, ne, 64, N_NODES);
    // Pp dead from here -> einfo alias safe

    // ---- edge classifier prep: nSp/nDp in one launch ----
    k_ec_prep<<<dim3(NB, 2), 256, 0, stream>>>(ne, ec_w1, nSp, nDp);

    // ---- edge classifier (+ einfo pack) ----
    k_tsmax<<<256, 256, 0, stream>>>(uts, tsmax);
    k_edge_cls<<<EB, 256, 0, stream>>>(nSp, nDp, eap_g, Ctp, ec_b1, ec_w2, ec_b2,
                                       src, dst, uts, tsmax, out_edge, einfo);

    // ---- node aggregation ----
    k_node_agg<<<NB, 256, 0, stream>>>(einfo, row2, eid2, feat8);

    // ---- node classifier ----
    k_node_cls<<<NB, 256, 0, stream>>>(ne, feat8, ncw1t, nc_b1, bn_g, bn_b, bn_m, bn_v,
                                       nc_w2, nc_b2, out_node);
}